// Round 4
// baseline (489.059 us; speedup 1.0000x reference)
//
#include <hip/hip_runtime.h>
#include <math.h>

// Problem constants
#define Bn 256
#define Ln 256
#define Dn 128
#define Hn 2
#define En 64
#define NLn 2
#define TOPKn 5
#define NUM_TOTALn 100000
#define BLD (Bn*Ln*Dn)      // 8388608 elements per activation buffer (bf16)
#define WT_LAYER 147456     // bf16 elements of weights per layer (incl W2T)

using frag_ab = __attribute__((ext_vector_type(8))) short;   // 8 bf16
using frag_cd = __attribute__((ext_vector_type(4))) float;   // 4 f32

__device__ inline short f2bf(float f) {
    union { float f; unsigned u; } c; c.f = f;
    unsigned r = (c.u + 0x7FFFu + ((c.u >> 16) & 1u)) >> 16;   // RNE
    return (short)r;
}
__device__ inline float bf2f(short s) {
    union { unsigned u; float f; } c; c.u = ((unsigned)(unsigned short)s) << 16;
    return c.f;
}

// ---------------------------------------------------------------------------
__global__ void beacon_kernel(float* out, float v) { out[0] = v; }

// Circulant band-pass matrices G_k[t][s] = g_k[(t-s)&255], closed-form
// Dirichlet kernel.  k=0: f in [51,128] (incl Nyquist), k=1: f in [0,77]
// (incl DC).
__global__ __launch_bounds__(256) void build_G_kernel(short* __restrict__ G) {
    int k = blockIdx.x, t = blockIdx.y, s = threadIdx.x;
    int d = (t - s) & 255;
    int f1 = (k == 0) ? 51 : 1;
    int f2 = (k == 0) ? 127 : 77;
    float acc;
    if (d == 0) {
        acc = 2.0f * (float)(f2 - f1 + 1);
    } else {
        const float c = 3.14159265358979323846f / 256.0f;
        int ahi = (d * (2 * f2 + 1)) & 511;
        int alo = (d * (2 * f1 - 1)) & 511;
        acc = (sinf(c * (float)ahi) - sinf(c * (float)alo)) / sinf(c * (float)d);
    }
    acc += (k == 0) ? ((d & 1) ? -1.0f : 1.0f)   // Nyquist term cos(pi*d)
                    : 1.0f;                       // DC term
    G[((size_t)k * 256 + t) * 256 + s] = f2bf(acc * (1.0f / 256.0f));
}

// x[b,t,d] = ego[paths[b,t], d] + pos[t, d]  -> bf16
__global__ __launch_bounds__(256) void build_x_kernel(const int* __restrict__ paths,
                                                      const float* __restrict__ ego,
                                                      const float* __restrict__ pos,
                                                      short* __restrict__ x) {
    int base = (blockIdx.x * 256 + threadIdx.x) * 4;
    int d = base & 127;
    int bl = base >> 7;
    int t = bl & 255;
    float4 e = *(const float4*)(ego + (size_t)paths[bl] * Dn + d);
    float4 p = *(const float4*)(pos + t * Dn + d);
    short4 s;
    s.x = f2bf(e.x + p.x); s.y = f2bf(e.y + p.y);
    s.z = f2bf(e.z + p.z); s.w = f2bf(e.w + p.w);
    *(short4*)&x[base] = s;
}

// All 6 weight transposes in ONE kernel.  Per layer z, flat idx in [0,131072):
// [0,16384)=Wq  [16384,32768)=Wk  [32768,49152)=Wv  [49152,65536)=0.1*Wp
// [65536,98304)=F1 (K=128,N=256)  [98304,131072)=F2 (K=256,N=128)
// in f32 [z][K][N] -> out bf16 [z][N][K] * scale
__global__ __launch_bounds__(256) void wtrans_all_kernel(
        const float* __restrict__ Wq, const float* __restrict__ Wk,
        const float* __restrict__ Wv, const float* __restrict__ Wp,
        const float* __restrict__ F1, const float* __restrict__ F2,
        short* __restrict__ Wt) {
    int z = blockIdx.y;
    int idx = blockIdx.x * 256 + threadIdx.x;
    short* WtL = Wt + (size_t)z * WT_LAYER;
    if (idx < 65536) {
        int which = idx >> 14, local = idx & 16383;
        const float* src = (which == 0) ? Wq : (which == 1) ? Wk
                         : (which == 2) ? Wv : Wp;
        float scale = (which == 3) ? 0.1f : 1.0f;
        int n = local & 127, k = local >> 7;
        WtL[(which << 14) + n * 128 + k] = f2bf(scale * src[(size_t)z * 16384 + local]);
    } else if (idx < 98304) {
        int local = idx - 65536;                  // F1: [128][256]
        int n = local & 255, k = local >> 8;
        WtL[65536 + n * 128 + k] = f2bf(F1[(size_t)z * 32768 + local]);
    } else {
        int local = idx - 98304;                  // F2: [256][128]
        int n = local & 127, k = local >> 7;
        WtL[98304 + n * 256 + k] = f2bf(F2[(size_t)z * 32768 + local]);
    }
}

// ---------------------------------------------------------------------------
// General MFMA bf16 GEMM (circulant filter + W2T precompute).
// A bf16 [M][K].  BT_FAST: B bf16 [N][K]; else B bf16 [K][N] transpose-staged.
template<bool BT_FAST, bool GELU_EPI>
__global__ __launch_bounds__(256)
void mfma_gemm_kernel(const short* A, const short* Bp, short* C, const short* R,
                      int K, int lda, int ldb, int ldc, int ldr,
                      long long sA, long long sB, long long sC, long long sR,
                      long long sCsplit, float alpha, float beta) {
    int bz = blockIdx.z;
    A += (size_t)bz * sA; C += (size_t)bz * sC;
    if (R) R += (size_t)bz * sR;
    const short* Bt = Bp + (size_t)bz * sB;
    const int m0 = blockIdx.x * 128, n0 = blockIdx.y * 128;
    int n0c = n0;
    if (sCsplit) { C += (size_t)blockIdx.y * sCsplit; n0c = 0; }
    __shared__ short As[128 * 40];
    __shared__ short Bs[128 * 40];
    int tid = threadIdx.x;
    int lane = tid & 63, wave = tid >> 6;
    int wr = (wave >> 1) * 64, wc = (wave & 1) * 64;
    int l15 = lane & 15, qd = lane >> 4;

    frag_cd zero4 = {0.f, 0.f, 0.f, 0.f};
    frag_cd acc[4][4];
    #pragma unroll
    for (int i = 0; i < 4; i++)
        #pragma unroll
        for (int j = 0; j < 4; j++) acc[i][j] = zero4;

    int arow = tid >> 1, acg = (tid & 1) * 16;
    int bnrow = tid >> 1, bcg = (tid & 1) * 16;
    int bkk = tid & 31, bnb = (tid >> 5) * 16;

    int4 pa0, pa1, pb0, pb1;
    {
        const short* ap = A + (size_t)(m0 + arow) * lda + acg;
        pa0 = *(const int4*)ap; pa1 = *(const int4*)(ap + 8);
        if (BT_FAST) {
            const short* bp = Bt + (size_t)(n0 + bnrow) * ldb + bcg;
            pb0 = *(const int4*)bp; pb1 = *(const int4*)(bp + 8);
        } else {
            const short* bp = Bt + (size_t)bkk * ldb + n0 + bnb;
            pb0 = *(const int4*)bp; pb1 = *(const int4*)(bp + 8);
        }
    }

    for (int k0 = 0; k0 < K; k0 += 32) {
        __syncthreads();
        *(int4*)&As[arow * 40 + acg] = pa0;
        *(int4*)&As[arow * 40 + acg + 8] = pa1;
        if (BT_FAST) {
            *(int4*)&Bs[bnrow * 40 + bcg] = pb0;
            *(int4*)&Bs[bnrow * 40 + bcg + 8] = pb1;
        } else {
            short tmp[16];
            *(int4*)&tmp[0] = pb0; *(int4*)&tmp[8] = pb1;
            #pragma unroll
            for (int i = 0; i < 16; i++) Bs[(bnb + i) * 40 + bkk] = tmp[i];
        }
        __syncthreads();
        if (k0 + 32 < K) {
            const short* ap = A + (size_t)(m0 + arow) * lda + k0 + 32 + acg;
            pa0 = *(const int4*)ap; pa1 = *(const int4*)(ap + 8);
            if (BT_FAST) {
                const short* bp = Bt + (size_t)(n0 + bnrow) * ldb + k0 + 32 + bcg;
                pb0 = *(const int4*)bp; pb1 = *(const int4*)(bp + 8);
            } else {
                const short* bp = Bt + (size_t)(k0 + 32 + bkk) * ldb + n0 + bnb;
                pb0 = *(const int4*)bp; pb1 = *(const int4*)(bp + 8);
            }
        }
        frag_ab af[4], bf[4];
        #pragma unroll
        for (int ms = 0; ms < 4; ms++)
            af[ms] = *(frag_ab*)&As[(wr + ms * 16 + l15) * 40 + qd * 8];
        #pragma unroll
        for (int ns = 0; ns < 4; ns++)
            bf[ns] = *(frag_ab*)&Bs[(wc + ns * 16 + l15) * 40 + qd * 8];
        #pragma unroll
        for (int ms = 0; ms < 4; ms++)
            #pragma unroll
            for (int ns = 0; ns < 4; ns++)
                acc[ms][ns] = __builtin_amdgcn_mfma_f32_16x16x32_bf16(
                    bf[ns], af[ms], acc[ms][ns], 0, 0, 0);
    }
    #pragma unroll
    for (int ms = 0; ms < 4; ms++) {
        int m = m0 + wr + ms * 16 + l15;
        #pragma unroll
        for (int ns = 0; ns < 4; ns++) {
            int nb = wc + ns * 16 + qd * 4;
            float v[4];
            #pragma unroll
            for (int r = 0; r < 4; r++) v[r] = alpha * acc[ms][ns][r];
            if (R) {
                short4 r4 = *(const short4*)&R[(size_t)m * ldr + n0 + nb];
                v[0] += beta * bf2f(r4.x); v[1] += beta * bf2f(r4.y);
                v[2] += beta * bf2f(r4.z); v[3] += beta * bf2f(r4.w);
            }
            if (GELU_EPI) {
                #pragma unroll
                for (int r = 0; r < 4; r++)
                    v[r] = v[r] * 0.5f * (1.0f + erff(v[r] * 0.70710678118654752f));
            }
            short4 o;
            o.x = f2bf(v[0]); o.y = f2bf(v[1]); o.z = f2bf(v[2]); o.w = f2bf(v[3]);
            *(short4*)&C[(size_t)m * ldc + n0c + nb] = o;
        }
    }
}

static inline void mgemm(hipStream_t s, const short* A, const short* B, short* C,
                         const short* R, int M, int N, int K,
                         int lda, int ldb, int ldc, int ldr,
                         long long sA, long long sB, long long sC, long long sR,
                         int batch, float alpha, float beta, bool btFast, bool gelu,
                         long long sCsplit = 0) {
    dim3 grid(M / 128, N / 128, batch), block(256);
    if (btFast) {
        if (gelu) mfma_gemm_kernel<true, true ><<<grid, block, 0, s>>>(A, B, C, R, K, lda, ldb, ldc, ldr, sA, sB, sC, sR, sCsplit, alpha, beta);
        else      mfma_gemm_kernel<true, false><<<grid, block, 0, s>>>(A, B, C, R, K, lda, ldb, ldc, ldr, sA, sB, sC, sR, sCsplit, alpha, beta);
    } else {
        if (gelu) mfma_gemm_kernel<false, true ><<<grid, block, 0, s>>>(A, B, C, R, K, lda, ldb, ldc, ldr, sA, sB, sC, sR, sCsplit, alpha, beta);
        else      mfma_gemm_kernel<false, false><<<grid, block, 0, s>>>(A, B, C, R, K, lda, ldb, ldc, ldr, sA, sB, sC, sR, sCsplit, alpha, beta);
    }
}

// ---------------------------------------------------------------------------
// Big-tile weight GEMM: BM=256, BN=128, BK=32.  512 threads = 8 waves (4x2).
// C = A1@B1 [+ A2@B2] + R (+opt GELU).  B pre-transposed bf16 [N][K].
// MIXA: pass-0 A operand is the TOPK-delay weighted gather of A1 (= x base).
template<bool DUAL, bool GELU_EPI, bool MIXA>
__global__ __launch_bounds__(512)
void bgemm_kernel(const short* __restrict__ A1, const short* __restrict__ B1, int K1,
                  const short* __restrict__ A2, const short* __restrict__ B2, int K2,
                  short* C, const short* __restrict__ R, int ldc, int ldr,
                  long long sCsplit,
                  const float* __restrict__ tc, const int* __restrict__ delays) {
    const int m0 = blockIdx.x * 256;
    int n0c;
    if (sCsplit) { C += (size_t)blockIdx.y * sCsplit; n0c = 0; }
    else         { n0c = blockIdx.y * 128; }
    __shared__ short As[256 * 40];   // [m][k] pad 40
    __shared__ short Bs[128 * 40];   // [n][k] pad 40
    int tid = threadIdx.x;
    int lane = tid & 63, wave = tid >> 6;
    int wr = (wave & 3) * 64, wc = (wave >> 2) * 64;
    int l15 = lane & 15, qd = lane >> 4;

    float wj[TOPKn]; int dj[TOPKn];
    if (MIXA) {
        #pragma unroll
        for (int j = 0; j < TOPKn; j++) {
            wj[j] = tc[blockIdx.x * TOPKn + j];
            dj[j] = delays[j];
        }
    }

    frag_cd zero4 = {0.f, 0.f, 0.f, 0.f};
    frag_cd acc[4][4];
    #pragma unroll
    for (int i = 0; i < 4; i++)
        #pragma unroll
        for (int j = 0; j < 4; j++) acc[i][j] = zero4;

    int arow = tid >> 1, acg = (tid & 1) * 16;   // A: 32B/thread
    int brow = tid >> 2, bcg = (tid & 3) * 8;    // B: 16B/thread

    #pragma unroll
    for (int pass = 0; pass < (DUAL ? 2 : 1); pass++) {
        const short* A = pass ? A2 : A1;
        const short* Bb = (pass ? B2 : B1);
        int K = pass ? K2 : K1;
        const bool domix = MIXA && (pass == 0);
        const short* Bt = Bb + (size_t)blockIdx.y * 128 * K;
        const short* xb = A + ((size_t)m0 << 7);   // x[b] base (MIXA pass 0)
        int4 pa0, pa1, pb0;
        {
            if (!domix) {
                const short* ap = A + (size_t)(m0 + arow) * K + acg;
                pa0 = *(const int4*)ap; pa1 = *(const int4*)(ap + 8);
            }
            pb0 = *(const int4*)(Bt + (size_t)brow * K + bcg);
        }
        for (int k0 = 0; k0 < K; k0 += 32) {
            __syncthreads();
            if (domix) {
                #pragma unroll
                for (int c = 0; c < 2; c++) {
                    int col = k0 + acg + c * 8;
                    float m8[8] = {0.f, 0.f, 0.f, 0.f, 0.f, 0.f, 0.f, 0.f};
                    #pragma unroll
                    for (int j = 0; j < TOPKn; j++) {
                        frag_ab v = *(const frag_ab*)(xb + (((arow + dj[j]) & 255) << 7) + col);
                        #pragma unroll
                        for (int i = 0; i < 8; i++) m8[i] += wj[j] * bf2f(v[i]);
                    }
                    frag_ab o;
                    #pragma unroll
                    for (int i = 0; i < 8; i++) o[i] = f2bf(m8[i]);
                    *(frag_ab*)&As[arow * 40 + acg + c * 8] = o;
                }
            } else {
                *(int4*)&As[arow * 40 + acg] = pa0;
                *(int4*)&As[arow * 40 + acg + 8] = pa1;
            }
            *(int4*)&Bs[brow * 40 + bcg] = pb0;
            __syncthreads();
            if (k0 + 32 < K) {
                if (!domix) {
                    const short* ap = A + (size_t)(m0 + arow) * K + k0 + 32 + acg;
                    pa0 = *(const int4*)ap; pa1 = *(const int4*)(ap + 8);
                }
                pb0 = *(const int4*)(Bt + (size_t)brow * K + k0 + 32 + bcg);
            }
            frag_ab af[4], bf[4];
            #pragma unroll
            for (int ms = 0; ms < 4; ms++)
                af[ms] = *(frag_ab*)&As[(wr + ms * 16 + l15) * 40 + qd * 8];
            #pragma unroll
            for (int ns = 0; ns < 4; ns++)
                bf[ns] = *(frag_ab*)&Bs[(wc + ns * 16 + l15) * 40 + qd * 8];
            #pragma unroll
            for (int ms = 0; ms < 4; ms++)
                #pragma unroll
                for (int ns = 0; ns < 4; ns++)
                    acc[ms][ns] = __builtin_amdgcn_mfma_f32_16x16x32_bf16(
                        bf[ns], af[ms], acc[ms][ns], 0, 0, 0);
        }
    }
    #pragma unroll
    for (int ms = 0; ms < 4; ms++) {
        int m = m0 + wr + ms * 16 + l15;
        #pragma unroll
        for (int ns = 0; ns < 4; ns++) {
            int nb = wc + ns * 16 + qd * 4;
            float v[4];
            #pragma unroll
            for (int r = 0; r < 4; r++) v[r] = acc[ms][ns][r];
            if (R) {
                short4 r4 = *(const short4*)&R[(size_t)m * ldr + n0c + nb];
                v[0] += bf2f(r4.x); v[1] += bf2f(r4.y);
                v[2] += bf2f(r4.z); v[3] += bf2f(r4.w);
            }
            if (GELU_EPI) {
                #pragma unroll
                for (int r = 0; r < 4; r++)
                    v[r] = v[r] * 0.5f * (1.0f + erff(v[r] * 0.70710678118654752f));
            }
            short4 o;
            o.x = f2bf(v[0]); o.y = f2bf(v[1]); o.z = f2bf(v[2]); o.w = f2bf(v[3]);
            *(short4*)&C[(size_t)m * ldc + n0c + nb] = o;
        }
    }
}

// ---------------------------------------------------------------------------
// MFMA bf16 fused attention, one WG per (h, b).  512 threads = 8 waves.
// Fixed-max softmax (scores O(0.01)).  S stored DIAGONALLY (SD aliases SB,
// stride 66 -> conflict-free mv reduction).  Denominator via ones-column in
// vT (round-1 proven structure, 40.4 us / 28 MB fetch).
// R4: the ONLY change vs round-1 is masks[] LDS float array -> per-jt 64-bit
// register bitmask via __ballot (removes 16 LDS reads + 16 VALU adds per
// thread per jt).  Everything else byte-identical (rounds 2/3 showed that
// the hoisted-fragment variants inflate global traffic ~3x, likely scratch).
__global__ __launch_bounds__(512, 4) void attn_kernel(short* q,
        const short* __restrict__ kb, const short* __restrict__ vf,
        const int* __restrict__ paths, float* __restrict__ mv2) {
    int h = blockIdx.x, b = blockIdx.y;
    __shared__ short SB[256 * 72];   // phase0: q staging (stride 72); loop: SD (stride 66)
    __shared__ short ks[64 * 72];
    __shared__ short vT[80 * 72];
    __shared__ float mvpart[512];
    __shared__ unsigned long long mbits[4];
    int tid = threadIdx.x;
    int lane = tid & 63, wave = tid >> 6;
    int l15 = lane & 15, qd = lane >> 4;
    if (wave < 4) {
        unsigned long long mb = __ballot(paths[b * 256 + tid] < NUM_TOTALn);
        if (lane == 0) mbits[wave] = mb;
    }
    {
        int e0 = tid * 2;
        #pragma unroll
        for (int i = 0; i < 2; i++) {
            int e = e0 + i;
            int row = 64 + (e >> 6), col = e & 63;
            vT[row * 72 + col] = (row == 64) ? (short)0x3F80 : (short)0;
        }
    }
    short* qg = q + ((size_t)b << 15) + (size_t)h * 64;
    const short* kg = kb + ((size_t)b << 15) + (size_t)h * 64;
    const short* vg = vf + ((size_t)b << 15) + (size_t)h * 64;

    #pragma unroll
    for (int p = 0; p < 4; p++) {
        int chunk = p * 512 + tid;
        int r = chunk >> 3, cb = (chunk & 7) * 8;
        *(frag_ab*)&SB[r * 72 + cb] = *(const frag_ab*)(qg + (size_t)r * 128 + cb);
    }
    __syncthreads();
    int myrow = wave * 32;
    frag_ab aq[2][2];
    #pragma unroll
    for (int mt = 0; mt < 2; mt++)
        #pragma unroll
        for (int hf = 0; hf < 2; hf++)
            aq[mt][hf] = *(frag_ab*)&SB[(myrow + mt * 16 + l15) * 72 + hf * 32 + qd * 8];

    frag_cd zero4 = {0.f, 0.f, 0.f, 0.f};
    frag_cd oacc[2][5];
    #pragma unroll
    for (int mt = 0; mt < 2; mt++)
        #pragma unroll
        for (int et = 0; et < 5; et++) oacc[mt][et] = zero4;
    float macc = 0.0f;
    int tau = tid & 255, half = tid >> 8;

    for (int jt = 0; jt < 4; jt++) {
        __syncthreads();
        {
            int r = tid >> 3, cb = (tid & 7) * 8;
            *(frag_ab*)&ks[r * 72 + cb] =
                *(const frag_ab*)(kg + (size_t)(jt * 64 + r) * 128 + cb);
            frag_ab v8 = *(const frag_ab*)(vg + (size_t)(jt * 64 + r) * 128 + cb);
            #pragma unroll
            for (int i = 0; i < 8; i++) vT[(cb + i) * 72 + r] = v8[i];
        }
        __syncthreads();
        #pragma unroll
        for (int mt = 0; mt < 2; mt++) {
            #pragma unroll
            for (int nt = 0; nt < 4; nt++) {
                frag_ab b0 = *(frag_ab*)&ks[(nt * 16 + l15) * 72 + qd * 8];
                frag_ab b1 = *(frag_ab*)&ks[(nt * 16 + l15) * 72 + 32 + qd * 8];
                frag_cd c = zero4;
                c = __builtin_amdgcn_mfma_f32_16x16x32_bf16(aq[mt][0], b0, c, 0, 0, 0);
                c = __builtin_amdgcn_mfma_f32_16x16x32_bf16(aq[mt][1], b1, c, 0, 0, 0);
                int keyLocal = nt * 16 + l15;
                #pragma unroll
                for (int r = 0; r < 4; r++) {
                    int row = myrow + mt * 16 + qd * 4 + r;
                    int tt = (row - jt * 64 - keyLocal) & 255;
                    SB[tt * 66 + keyLocal] = f2bf(c[r] * 0.125f);
                }
            }
        }
        __syncthreads();
        {
            const int* SD32 = (const int*)&SB[tau * 66 + half * 32];
            #pragma unroll
            for (int i = 0; i < 16; i++) {
                int pk = SD32[i];
                macc += bf2f((short)(pk & 0xFFFF)) + bf2f((short)(pk >> 16));
            }
        }
        unsigned long long mk = mbits[jt];
        #pragma unroll
        for (int mt = 0; mt < 2; mt++) {
            int row = myrow + mt * 16 + l15;
            #pragma unroll
            for (int hf = 0; hf < 2; hf++) {
                int kl0 = hf * 32 + qd * 8;
                frag_ab pfrag;
                #pragma unroll
                for (int j = 0; j < 8; j++) {
                    int kl = kl0 + j;
                    int tt = (row - jt * 64 - kl) & 255;
                    float s = bf2f(SB[tt * 66 + kl]);
                    pfrag[j] = ((mk >> kl) & 1ull) ? f2bf(__expf(s)) : (short)0;
                }
                #pragma unroll
                for (int et = 0; et < 5; et++) {
                    frag_ab bv = *(frag_ab*)&vT[(et * 16 + l15) * 72 + hf * 32 + qd * 8];
                    oacc[mt][et] = __builtin_amdgcn_mfma_f32_16x16x32_bf16(pfrag, bv, oacc[mt][et], 0, 0, 0);
                }
            }
        }
    }
    __syncthreads();
    mvpart[tid] = macc;
    __syncthreads();
    if (tid < 256)
        mv2[(size_t)h * 65536 + b * 256 + tid] =
            (mvpart[tid] + mvpart[tid + 256]) * 0.0625f;
    #pragma unroll
    for (int mt = 0; mt < 2; mt++) {
        #pragma unroll
        for (int r = 0; r < 4; r++) {
            float l = oacc[mt][4][r];
            l = __shfl(l, (lane & 48));
            float inv = 1.0f / l;
            int row = myrow + mt * 16 + qd * 4 + r;
            #pragma unroll
            for (int et = 0; et < 4; et++)
                qg[(size_t)row * 128 + et * 16 + l15] = f2bf(oacc[mt][et][r] * inv);
        }
    }
}

// ---------------------------------------------------------------------------
// Fused gm-reduction + top-5 + per-b softmax.  One block, 256 threads.
// Phase 1: gm[tau] = (1/256) sum_b (mv2[0][b][tau] + mv2[1][b][tau]);
// thread tau accumulates over b (coalesced 1 KB lines across threads).
// Then 5 rounds of wave-shuffle argmax (tie -> smaller index), then per-b
// softmax over the selected weights.  Replaces gm_reduce + topk (one fewer
// launch in the serial attn->mix chain, no gm global round-trip).
__global__ __launch_bounds__(256) void gm_topk_kernel(const float* __restrict__ mv2,
                                                      int* __restrict__ delays,
                                                      float* __restrict__ tc) {
    __shared__ float vsh[4];
    __shared__ int ish[4];
    __shared__ int dsh[TOPKn];
    int tid = threadIdx.x;
    int lane = tid & 63, wave = tid >> 6;
    float acc = 0.f;
    #pragma unroll 8
    for (int b = 0; b < 256; b++)
        acc += mv2[b * 256 + tid] + mv2[65536 + b * 256 + tid];
    float v = acc * (1.0f / 256.0f);
    for (int t = 0; t < TOPKn; t++) {
        float mv_ = v; int mi = tid;
        #pragma unroll
        for (int s = 32; s > 0; s >>= 1) {
            float v2 = __shfl_xor(mv_, s); int i2 = __shfl_xor(mi, s);
            if (v2 > mv_ || (v2 == mv_ && i2 < mi)) { mv_ = v2; mi = i2; }
        }
        if (lane == 0) { vsh[wave] = mv_; ish[wave] = mi; }
        __syncthreads();
        if (tid == 0) {
            float bv = vsh[0]; int bi = ish[0];
            #pragma unroll
            for (int w = 1; w < 4; w++)
                if (vsh[w] > bv || (vsh[w] == bv && ish[w] < bi)) { bv = vsh[w]; bi = ish[w]; }
            dsh[t] = bi; delays[t] = bi;
        }
        __syncthreads();
        if (tid == dsh[t]) v = -1e30f;
    }
    __syncthreads();
    int b = tid;
    float w[TOPKn];
    float m = -1e30f;
    #pragma unroll
    for (int j = 0; j < TOPKn; j++) {
        w[j] = mv2[b * 256 + dsh[j]] + mv2[65536 + b * 256 + dsh[j]];
        m = fmaxf(m, w[j]);
    }
    float ssum = 0.0f;
    #pragma unroll
    for (int j = 0; j < TOPKn; j++) { w[j] = expf(w[j] - m); ssum += w[j]; }
    #pragma unroll
    for (int j = 0; j < TOPKn; j++) tc[b * TOPKn + j] = w[j] / ssum;
}

__global__ __launch_bounds__(256) void gather_out_kernel(const short* __restrict__ x,
                                                         const int* __restrict__ lengths,
                                                         float* __restrict__ out) {
    int idx = blockIdx.x * 256 + threadIdx.x;
    int d = idx & 127;
    int b = idx >> 7;
    out[idx] = bf2f(x[((size_t)b << 15) + (size_t)(lengths[b] - 1) * Dn + d]);
}

// ---------------------------------------------------------------------------
extern "C" void kernel_launch(void* const* d_in, const int* in_sizes, int n_in,
                              void* d_out, int out_size, void* d_ws, size_t ws_size,
                              hipStream_t stream) {
    const int* paths    = (const int*)d_in[0];
    const int* lengths  = (const int*)d_in[1];
    const float* ego    = (const float*)d_in[4];
    const float* pos    = (const float*)d_in[5];
    const float* Wq     = (const float*)d_in[6];
    const float* Wk     = (const float*)d_in[7];
    const float* Wv     = (const float*)d_in[8];
    const float* Wp     = (const float*)d_in[9];
    const float* F1     = (const float*)d_in[10];
    const float* F2     = (const float*)d_in[11];
    float* out = (float*)d_out;

    const size_t need = (size_t)5 * BLD * 2 + 131072 * 2 + 131072 * 4
                        + 256 * 4 + 1280 * 4 + 16 * 4 + (size_t)NLn * WT_LAYER * 2;
    if (ws_size < need) {
        beacon_kernel<<<dim3(1), dim3(1), 0, stream>>>(out, (float)(ws_size >> 20));
        return;
    }

    short* x    = (short*)d_ws;
    short* q    = x + (size_t)1 * BLD;   // q~ -> spat
    short* kb   = x + (size_t)2 * BLD;   // k~ -> a
    short* vf   = x + (size_t)3 * BLD;   // v~ -> h (spans vf+x5)
    short* x5   = x + (size_t)4 * BLD;   // xf -> h(hi)
    short* Gb   = x + (size_t)5 * BLD;
    float* mv   = (float*)(Gb + 131072);   // mv2: [2][256][256]
    float* tc   = mv + 131072 + 256;       // (256-slot gap: former gm)
    int* delays = (int*)(tc + 1280);
    short* Wt   = (short*)(delays + 16);

    build_G_kernel<<<dim3(2, 256), dim3(256), 0, stream>>>(Gb);
    build_x_kernel<<<dim3(BLD / 1024), dim3(256), 0, stream>>>(paths, ego, pos, x);

    // Wt per layer: [0]=Wq^T | [16384]=Wk^T | [32768]=Wv^T | [49152]=0.1*Wp^T
    //               [65536]=F1^T | [98304]=F2^T | [131072]=W2^T=0.9*(Wv@Wp)^T
    wtrans_all_kernel<<<dim3(512, NLn), dim3(256), 0, stream>>>(Wq, Wk, Wv, Wp, F1, F2, Wt);
    // W2T = 9*(0.1Wp^T)@(Wv^T slow-path) for both layers in one batched launch
    mgemm(stream, Wt + 49152, Wt + 32768, Wt + 131072, nullptr,
          128, 128, 128, 128, 128, 128, 0,
          WT_LAYER, WT_LAYER, WT_LAYER, 0, NLn,
          9.0f, 0.0f, false, false);

    for (int k = 0; k < NLn; k++) {
        const short* WtL = Wt + (size_t)k * WT_LAYER;
        // xf = G_k @ x[b] (band filter; slow-path B) -> x5
        mgemm(stream, Gb + (size_t)k * 65536, x, x5, nullptr,
              256, 128, 256, 256, 128, 128, 0,
              0, 32768, 32768, 0, 256, 1.0f, 0.0f, false, false);
        // fused projections: A=x5, B=[Wq^T;Wk^T;Wv^T], N=384 split-C (BM=256)
        bgemm_kernel<false, false, false><<<dim3(256, 3), dim3(512), 0, stream>>>(
            x5, WtL + 0, 128, nullptr, nullptr, 0, q, nullptr, 128, 0,
            (long long)BLD, nullptr, nullptr);

        attn_kernel<<<dim3(2, 256), dim3(512), 0, stream>>>(q, kb, vf, paths, mv);

        gm_topk_kernel<<<dim3(1), dim3(256), 0, stream>>>(mv, delays, tc);

        // a = mix(x)@W2' + spat@(0.1Wp') + x  -> kb   (mix fused into A-stage)
        bgemm_kernel<true, false, true><<<dim3(256, 1), dim3(512), 0, stream>>>(
            x, WtL + 131072, 128, q, WtL + 49152, 128, kb, x, 128, 128, 0,
            tc, delays);
        // h = gelu(a @ F1) -> vf..x5 span (65536 x 256)
        bgemm_kernel<false, true, false><<<dim3(256, 2), dim3(512), 0, stream>>>(
            kb, WtL + 65536, 128, nullptr, nullptr, 0, vf, nullptr, 256, 0, 0,
            nullptr, nullptr);
        // x = h @ F2  (K=256)
        bgemm_kernel<false, false, false><<<dim3(256, 1), dim3(512), 0, stream>>>(
            vf, WtL + 98304, 256, nullptr, nullptr, 0, x, nullptr, 128, 0, 0,
            nullptr, nullptr);
    }

    gather_out_kernel<<<dim3((Bn * Dn) / 256), dim3(256), 0, stream>>>(x, lengths, out);
}

// Round 5
// 398.850 us; speedup vs baseline: 1.2262x; 1.2262x over previous
//
#include <hip/hip_runtime.h>
#include <math.h>

// Problem constants
#define Bn 256
#define Ln 256
#define Dn 128
#define Hn 2
#define En 64
#define NLn 2
#define TOPKn 5
#define NUM_TOTALn 100000
#define BLD (Bn*Ln*Dn)      // 8388608 elements per activation buffer (bf16)
#define WT_LAYER 147456     // bf16 elements of weights per layer (incl W2T)

using frag_ab = __attribute__((ext_vector_type(8))) short;   // 8 bf16
using frag_cd = __attribute__((ext_vector_type(4))) float;   // 4 f32

__device__ inline short f2bf(float f) {
    union { float f; unsigned u; } c; c.f = f;
    unsigned r = (c.u + 0x7FFFu + ((c.u >> 16) & 1u)) >> 16;   // RNE
    return (short)r;
}
__device__ inline float bf2f(short s) {
    union { unsigned u; float f; } c; c.u = ((unsigned)(unsigned short)s) << 16;
    return c.f;
}

// ---------------------------------------------------------------------------
__global__ void beacon_kernel(float* out, float v) { out[0] = v; }

// Circulant band-pass matrices G_k[t][s] = g_k[(t-s)&255], closed-form
// Dirichlet kernel (replaces double-precision 77-term cosine loop + extra
// kernel).  k=0: f in [51,128] (incl Nyquist), k=1: f in [0,77] (incl DC).
// sum_{f=f1}^{f2} 2cos(2*pi*f*d/L) = [sin((2f2+1)c d) - sin((2f1-1)c d)]/sin(c d),
// c = pi/256; integer phase reduction mod 512 keeps sinf args in [0, 2pi).
__global__ __launch_bounds__(256) void build_G_kernel(short* __restrict__ G) {
    int k = blockIdx.x, t = blockIdx.y, s = threadIdx.x;
    int d = (t - s) & 255;
    int f1 = (k == 0) ? 51 : 1;
    int f2 = (k == 0) ? 127 : 77;
    float acc;
    if (d == 0) {
        acc = 2.0f * (float)(f2 - f1 + 1);
    } else {
        const float c = 3.14159265358979323846f / 256.0f;
        int ahi = (d * (2 * f2 + 1)) & 511;
        int alo = (d * (2 * f1 - 1)) & 511;
        acc = (sinf(c * (float)ahi) - sinf(c * (float)alo)) / sinf(c * (float)d);
    }
    acc += (k == 0) ? ((d & 1) ? -1.0f : 1.0f)   // Nyquist term cos(pi*d)
                    : 1.0f;                       // DC term
    G[((size_t)k * 256 + t) * 256 + s] = f2bf(acc * (1.0f / 256.0f));
}

// x[b,t,d] = ego[paths[b,t], d] + pos[t, d]  -> bf16
__global__ __launch_bounds__(256) void build_x_kernel(const int* __restrict__ paths,
                                                      const float* __restrict__ ego,
                                                      const float* __restrict__ pos,
                                                      short* __restrict__ x) {
    int base = (blockIdx.x * 256 + threadIdx.x) * 4;
    int d = base & 127;
    int bl = base >> 7;
    int t = bl & 255;
    float4 e = *(const float4*)(ego + (size_t)paths[bl] * Dn + d);
    float4 p = *(const float4*)(pos + t * Dn + d);
    short4 s;
    s.x = f2bf(e.x + p.x); s.y = f2bf(e.y + p.y);
    s.z = f2bf(e.z + p.z); s.w = f2bf(e.w + p.w);
    *(short4*)&x[base] = s;
}

// All 6 weight transposes in ONE kernel.  Per layer z, flat idx in [0,131072):
// [0,16384)=Wq  [16384,32768)=Wk  [32768,49152)=Wv  [49152,65536)=0.1*Wp
// [65536,98304)=F1 (K=128,N=256)  [98304,131072)=F2 (K=256,N=128)
// in f32 [z][K][N] -> out bf16 [z][N][K] * scale
__global__ __launch_bounds__(256) void wtrans_all_kernel(
        const float* __restrict__ Wq, const float* __restrict__ Wk,
        const float* __restrict__ Wv, const float* __restrict__ Wp,
        const float* __restrict__ F1, const float* __restrict__ F2,
        short* __restrict__ Wt) {
    int z = blockIdx.y;
    int idx = blockIdx.x * 256 + threadIdx.x;
    short* WtL = Wt + (size_t)z * WT_LAYER;
    if (idx < 65536) {
        int which = idx >> 14, local = idx & 16383;
        const float* src = (which == 0) ? Wq : (which == 1) ? Wk
                         : (which == 2) ? Wv : Wp;
        float scale = (which == 3) ? 0.1f : 1.0f;
        int n = local & 127, k = local >> 7;
        WtL[(which << 14) + n * 128 + k] = f2bf(scale * src[(size_t)z * 16384 + local]);
    } else if (idx < 98304) {
        int local = idx - 65536;                  // F1: [128][256]
        int n = local & 255, k = local >> 8;
        WtL[65536 + n * 128 + k] = f2bf(F1[(size_t)z * 32768 + local]);
    } else {
        int local = idx - 98304;                  // F2: [256][128]
        int n = local & 127, k = local >> 7;
        WtL[98304 + n * 256 + k] = f2bf(F2[(size_t)z * 32768 + local]);
    }
}

// ---------------------------------------------------------------------------
// General MFMA bf16 GEMM (circulant filter + W2T precompute).
// A bf16 [M][K].  BT_FAST: B bf16 [N][K]; else B bf16 [K][N] transpose-staged.
// Operand-swapped MFMA -> coalesced short4 epilogue; register prefetch.
template<bool BT_FAST, bool GELU_EPI>
__global__ __launch_bounds__(256)
void mfma_gemm_kernel(const short* A, const short* Bp, short* C, const short* R,
                      int K, int lda, int ldb, int ldc, int ldr,
                      long long sA, long long sB, long long sC, long long sR,
                      long long sCsplit, float alpha, float beta) {
    int bz = blockIdx.z;
    A += (size_t)bz * sA; C += (size_t)bz * sC;
    if (R) R += (size_t)bz * sR;
    const short* Bt = Bp + (size_t)bz * sB;
    const int m0 = blockIdx.x * 128, n0 = blockIdx.y * 128;
    int n0c = n0;
    if (sCsplit) { C += (size_t)blockIdx.y * sCsplit; n0c = 0; }
    __shared__ short As[128 * 40];
    __shared__ short Bs[128 * 40];
    int tid = threadIdx.x;
    int lane = tid & 63, wave = tid >> 6;
    int wr = (wave >> 1) * 64, wc = (wave & 1) * 64;
    int l15 = lane & 15, qd = lane >> 4;

    frag_cd zero4 = {0.f, 0.f, 0.f, 0.f};
    frag_cd acc[4][4];
    #pragma unroll
    for (int i = 0; i < 4; i++)
        #pragma unroll
        for (int j = 0; j < 4; j++) acc[i][j] = zero4;

    int arow = tid >> 1, acg = (tid & 1) * 16;
    int bnrow = tid >> 1, bcg = (tid & 1) * 16;
    int bkk = tid & 31, bnb = (tid >> 5) * 16;

    int4 pa0, pa1, pb0, pb1;
    {
        const short* ap = A + (size_t)(m0 + arow) * lda + acg;
        pa0 = *(const int4*)ap; pa1 = *(const int4*)(ap + 8);
        if (BT_FAST) {
            const short* bp = Bt + (size_t)(n0 + bnrow) * ldb + bcg;
            pb0 = *(const int4*)bp; pb1 = *(const int4*)(bp + 8);
        } else {
            const short* bp = Bt + (size_t)bkk * ldb + n0 + bnb;
            pb0 = *(const int4*)bp; pb1 = *(const int4*)(bp + 8);
        }
    }

    for (int k0 = 0; k0 < K; k0 += 32) {
        __syncthreads();
        *(int4*)&As[arow * 40 + acg] = pa0;
        *(int4*)&As[arow * 40 + acg + 8] = pa1;
        if (BT_FAST) {
            *(int4*)&Bs[bnrow * 40 + bcg] = pb0;
            *(int4*)&Bs[bnrow * 40 + bcg + 8] = pb1;
        } else {
            short tmp[16];
            *(int4*)&tmp[0] = pb0; *(int4*)&tmp[8] = pb1;
            #pragma unroll
            for (int i = 0; i < 16; i++) Bs[(bnb + i) * 40 + bkk] = tmp[i];
        }
        __syncthreads();
        if (k0 + 32 < K) {
            const short* ap = A + (size_t)(m0 + arow) * lda + k0 + 32 + acg;
            pa0 = *(const int4*)ap; pa1 = *(const int4*)(ap + 8);
            if (BT_FAST) {
                const short* bp = Bt + (size_t)(n0 + bnrow) * ldb + k0 + 32 + bcg;
                pb0 = *(const int4*)bp; pb1 = *(const int4*)(bp + 8);
            } else {
                const short* bp = Bt + (size_t)(k0 + 32 + bkk) * ldb + n0 + bnb;
                pb0 = *(const int4*)bp; pb1 = *(const int4*)(bp + 8);
            }
        }
        frag_ab af[4], bf[4];
        #pragma unroll
        for (int ms = 0; ms < 4; ms++)
            af[ms] = *(frag_ab*)&As[(wr + ms * 16 + l15) * 40 + qd * 8];
        #pragma unroll
        for (int ns = 0; ns < 4; ns++)
            bf[ns] = *(frag_ab*)&Bs[(wc + ns * 16 + l15) * 40 + qd * 8];
        #pragma unroll
        for (int ms = 0; ms < 4; ms++)
            #pragma unroll
            for (int ns = 0; ns < 4; ns++)
                acc[ms][ns] = __builtin_amdgcn_mfma_f32_16x16x32_bf16(
                    bf[ns], af[ms], acc[ms][ns], 0, 0, 0);
    }
    #pragma unroll
    for (int ms = 0; ms < 4; ms++) {
        int m = m0 + wr + ms * 16 + l15;
        #pragma unroll
        for (int ns = 0; ns < 4; ns++) {
            int nb = wc + ns * 16 + qd * 4;
            float v[4];
            #pragma unroll
            for (int r = 0; r < 4; r++) v[r] = alpha * acc[ms][ns][r];
            if (R) {
                short4 r4 = *(const short4*)&R[(size_t)m * ldr + n0 + nb];
                v[0] += beta * bf2f(r4.x); v[1] += beta * bf2f(r4.y);
                v[2] += beta * bf2f(r4.z); v[3] += beta * bf2f(r4.w);
            }
            if (GELU_EPI) {
                #pragma unroll
                for (int r = 0; r < 4; r++)
                    v[r] = v[r] * 0.5f * (1.0f + erff(v[r] * 0.70710678118654752f));
            }
            short4 o;
            o.x = f2bf(v[0]); o.y = f2bf(v[1]); o.z = f2bf(v[2]); o.w = f2bf(v[3]);
            *(short4*)&C[(size_t)m * ldc + n0c + nb] = o;
        }
    }
}

static inline void mgemm(hipStream_t s, const short* A, const short* B, short* C,
                         const short* R, int M, int N, int K,
                         int lda, int ldb, int ldc, int ldr,
                         long long sA, long long sB, long long sC, long long sR,
                         int batch, float alpha, float beta, bool btFast, bool gelu,
                         long long sCsplit = 0) {
    dim3 grid(M / 128, N / 128, batch), block(256);
    if (btFast) {
        if (gelu) mfma_gemm_kernel<true, true ><<<grid, block, 0, s>>>(A, B, C, R, K, lda, ldb, ldc, ldr, sA, sB, sC, sR, sCsplit, alpha, beta);
        else      mfma_gemm_kernel<true, false><<<grid, block, 0, s>>>(A, B, C, R, K, lda, ldb, ldc, ldr, sA, sB, sC, sR, sCsplit, alpha, beta);
    } else {
        if (gelu) mfma_gemm_kernel<false, true ><<<grid, block, 0, s>>>(A, B, C, R, K, lda, ldb, ldc, ldr, sA, sB, sC, sR, sCsplit, alpha, beta);
        else      mfma_gemm_kernel<false, false><<<grid, block, 0, s>>>(A, B, C, R, K, lda, ldb, ldc, ldr, sA, sB, sC, sR, sCsplit, alpha, beta);
    }
}

// ---------------------------------------------------------------------------
// Big-tile weight GEMM: BM=256, BN=128, BK=32.  512 threads = 8 waves (4x2).
// C = A1@B1 [+ A2@B2] + R (+opt GELU).  A row stride == K (contiguous).
// B pre-transposed bf16 [N][K]; per-grid.y chunk: B += y*128*K.
// sCsplit != 0: C += y*sCsplit, C cols 0..127 (split outputs); else cols y*128.
// MIXA: pass-0 A operand is the TOPK-delay weighted gather of A1 (= x base);
// each 256-row block is exactly one batch b, so tc[b]/delays load once.
template<bool DUAL, bool GELU_EPI, bool MIXA>
__global__ __launch_bounds__(512)
void bgemm_kernel(const short* __restrict__ A1, const short* __restrict__ B1, int K1,
                  const short* __restrict__ A2, const short* __restrict__ B2, int K2,
                  short* C, const short* __restrict__ R, int ldc, int ldr,
                  long long sCsplit,
                  const float* __restrict__ tc, const int* __restrict__ delays) {
    const int m0 = blockIdx.x * 256;
    int n0c;
    if (sCsplit) { C += (size_t)blockIdx.y * sCsplit; n0c = 0; }
    else         { n0c = blockIdx.y * 128; }
    __shared__ short As[256 * 40];   // [m][k] pad 40
    __shared__ short Bs[128 * 40];   // [n][k] pad 40
    int tid = threadIdx.x;
    int lane = tid & 63, wave = tid >> 6;
    int wr = (wave & 3) * 64, wc = (wave >> 2) * 64;
    int l15 = lane & 15, qd = lane >> 4;

    float wj[TOPKn]; int dj[TOPKn];
    if (MIXA) {
        #pragma unroll
        for (int j = 0; j < TOPKn; j++) {
            wj[j] = tc[blockIdx.x * TOPKn + j];
            dj[j] = delays[j];
        }
    }

    frag_cd zero4 = {0.f, 0.f, 0.f, 0.f};
    frag_cd acc[4][4];
    #pragma unroll
    for (int i = 0; i < 4; i++)
        #pragma unroll
        for (int j = 0; j < 4; j++) acc[i][j] = zero4;

    int arow = tid >> 1, acg = (tid & 1) * 16;   // A: 32B/thread
    int brow = tid >> 2, bcg = (tid & 3) * 8;    // B: 16B/thread

    #pragma unroll
    for (int pass = 0; pass < (DUAL ? 2 : 1); pass++) {
        const short* A = pass ? A2 : A1;
        const short* Bb = (pass ? B2 : B1);
        int K = pass ? K2 : K1;
        const bool domix = MIXA && (pass == 0);
        const short* Bt = Bb + (size_t)blockIdx.y * 128 * K;
        const short* xb = A + ((size_t)m0 << 7);   // x[b] base (MIXA pass 0)
        int4 pa0, pa1, pb0;
        {
            if (!domix) {
                const short* ap = A + (size_t)(m0 + arow) * K + acg;
                pa0 = *(const int4*)ap; pa1 = *(const int4*)(ap + 8);
            }
            pb0 = *(const int4*)(Bt + (size_t)brow * K + bcg);
        }
        for (int k0 = 0; k0 < K; k0 += 32) {
            __syncthreads();
            if (domix) {
                #pragma unroll
                for (int c = 0; c < 2; c++) {
                    int col = k0 + acg + c * 8;
                    float m8[8] = {0.f, 0.f, 0.f, 0.f, 0.f, 0.f, 0.f, 0.f};
                    #pragma unroll
                    for (int j = 0; j < TOPKn; j++) {
                        frag_ab v = *(const frag_ab*)(xb + (((arow + dj[j]) & 255) << 7) + col);
                        #pragma unroll
                        for (int i = 0; i < 8; i++) m8[i] += wj[j] * bf2f(v[i]);
                    }
                    frag_ab o;
                    #pragma unroll
                    for (int i = 0; i < 8; i++) o[i] = f2bf(m8[i]);
                    *(frag_ab*)&As[arow * 40 + acg + c * 8] = o;
                }
            } else {
                *(int4*)&As[arow * 40 + acg] = pa0;
                *(int4*)&As[arow * 40 + acg + 8] = pa1;
            }
            *(int4*)&Bs[brow * 40 + bcg] = pb0;
            __syncthreads();
            if (k0 + 32 < K) {
                if (!domix) {
                    const short* ap = A + (size_t)(m0 + arow) * K + k0 + 32 + acg;
                    pa0 = *(const int4*)ap; pa1 = *(const int4*)(ap + 8);
                }
                pb0 = *(const int4*)(Bt + (size_t)brow * K + k0 + 32 + bcg);
            }
            frag_ab af[4], bf[4];
            #pragma unroll
            for (int ms = 0; ms < 4; ms++)
                af[ms] = *(frag_ab*)&As[(wr + ms * 16 + l15) * 40 + qd * 8];
            #pragma unroll
            for (int ns = 0; ns < 4; ns++)
                bf[ns] = *(frag_ab*)&Bs[(wc + ns * 16 + l15) * 40 + qd * 8];
            #pragma unroll
            for (int ms = 0; ms < 4; ms++)
                #pragma unroll
                for (int ns = 0; ns < 4; ns++)
                    acc[ms][ns] = __builtin_amdgcn_mfma_f32_16x16x32_bf16(
                        bf[ns], af[ms], acc[ms][ns], 0, 0, 0);
        }
    }
    #pragma unroll
    for (int ms = 0; ms < 4; ms++) {
        int m = m0 + wr + ms * 16 + l15;
        #pragma unroll
        for (int ns = 0; ns < 4; ns++) {
            int nb = wc + ns * 16 + qd * 4;
            float v[4];
            #pragma unroll
            for (int r = 0; r < 4; r++) v[r] = acc[ms][ns][r];
            if (R) {
                short4 r4 = *(const short4*)&R[(size_t)m * ldr + n0c + nb];
                v[0] += bf2f(r4.x); v[1] += bf2f(r4.y);
                v[2] += bf2f(r4.z); v[3] += bf2f(r4.w);
            }
            if (GELU_EPI) {
                #pragma unroll
                for (int r = 0; r < 4; r++)
                    v[r] = v[r] * 0.5f * (1.0f + erff(v[r] * 0.70710678118654752f));
            }
            short4 o;
            o.x = f2bf(v[0]); o.y = f2bf(v[1]); o.z = f2bf(v[2]); o.w = f2bf(v[3]);
            *(short4*)&C[(size_t)m * ldc + n0c + nb] = o;
        }
    }
}

// ---------------------------------------------------------------------------
// MFMA bf16 fused attention, one WG per (h, b).  512 threads = 8 waves.
// Fixed-max softmax (scores O(0.01)).  S stored DIAGONALLY (SD[tau][keyLocal],
// stride 66 -> conflict-free mv reduction).  Denominator via ones-column in vT.
// Correlation partials: plain store to mv2[h][b][tau] (no atomics / no zero).
// NOTE (R4 lesson): ballot-bitmask + ternary pfrag variants inflate FETCH
// 28->88..126 MB (3 independent A/Bs) -- keep the masks[] LDS float path.
__global__ __launch_bounds__(512, 4) void attn_kernel(short* q,
        const short* __restrict__ kb, const short* __restrict__ vf,
        const int* __restrict__ paths, float* __restrict__ mv2) {
    int h = blockIdx.x, b = blockIdx.y;
    __shared__ short SB[256 * 72];   // phase0: q staging (stride 72); loop: SD (stride 66)
    __shared__ short ks[64 * 72];
    __shared__ short vT[80 * 72];
    __shared__ float masks[256];
    __shared__ float mvpart[512];
    int tid = threadIdx.x;
    int lane = tid & 63, wave = tid >> 6;
    int l15 = lane & 15, qd = lane >> 4;
    if (tid < 256) masks[tid] = (paths[b * 256 + tid] < NUM_TOTALn) ? 0.0f : -10000.0f;
    {
        int e0 = tid * 2;
        #pragma unroll
        for (int i = 0; i < 2; i++) {
            int e = e0 + i;
            int row = 64 + (e >> 6), col = e & 63;
            vT[row * 72 + col] = (row == 64) ? (short)0x3F80 : (short)0;
        }
    }
    short* qg = q + ((size_t)b << 15) + (size_t)h * 64;
    const short* kg = kb + ((size_t)b << 15) + (size_t)h * 64;
    const short* vg = vf + ((size_t)b << 15) + (size_t)h * 64;

    #pragma unroll
    for (int p = 0; p < 4; p++) {
        int chunk = p * 512 + tid;
        int r = chunk >> 3, cb = (chunk & 7) * 8;
        *(frag_ab*)&SB[r * 72 + cb] = *(const frag_ab*)(qg + (size_t)r * 128 + cb);
    }
    __syncthreads();
    int myrow = wave * 32;
    frag_ab aq[2][2];
    #pragma unroll
    for (int mt = 0; mt < 2; mt++)
        #pragma unroll
        for (int hf = 0; hf < 2; hf++)
            aq[mt][hf] = *(frag_ab*)&SB[(myrow + mt * 16 + l15) * 72 + hf * 32 + qd * 8];

    frag_cd zero4 = {0.f, 0.f, 0.f, 0.f};
    frag_cd oacc[2][5];
    #pragma unroll
    for (int mt = 0; mt < 2; mt++)
        #pragma unroll
        for (int et = 0; et < 5; et++) oacc[mt][et] = zero4;
    float macc = 0.0f;
    int tau = tid & 255, half = tid >> 8;

    for (int jt = 0; jt < 4; jt++) {
        __syncthreads();
        {
            int r = tid >> 3, cb = (tid & 7) * 8;
            *(frag_ab*)&ks[r * 72 + cb] =
                *(const frag_ab*)(kg + (size_t)(jt * 64 + r) * 128 + cb);
            frag_ab v8 = *(const frag_ab*)(vg + (size_t)(jt * 64 + r) * 128 + cb);
            #pragma unroll
            for (int i = 0; i < 8; i++) vT[(cb + i) * 72 + r] = v8[i];
        }
        __syncthreads();
        #pragma unroll
        for (int mt = 0; mt < 2; mt++) {
            #pragma unroll
            for (int nt = 0; nt < 4; nt++) {
                frag_ab b0 = *(frag_ab*)&ks[(nt * 16 + l15) * 72 + qd * 8];
                frag_ab b1 = *(frag_ab*)&ks[(nt * 16 + l15) * 72 + 32 + qd * 8];
                frag_cd c = zero4;
                c = __builtin_amdgcn_mfma_f32_16x16x32_bf16(aq[mt][0], b0, c, 0, 0, 0);
                c = __builtin_amdgcn_mfma_f32_16x16x32_bf16(aq[mt][1], b1, c, 0, 0, 0);
                int keyLocal = nt * 16 + l15;
                #pragma unroll
                for (int r = 0; r < 4; r++) {
                    int row = myrow + mt * 16 + qd * 4 + r;
                    int tt = (row - jt * 64 - keyLocal) & 255;
                    SB[tt * 66 + keyLocal] = f2bf(c[r] * 0.125f);
                }
            }
        }
        __syncthreads();
        {
            const int* SD32 = (const int*)&SB[tau * 66 + half * 32];
            #pragma unroll
            for (int i = 0; i < 16; i++) {
                int pk = SD32[i];
                macc += bf2f((short)(pk & 0xFFFF)) + bf2f((short)(pk >> 16));
            }
        }
        #pragma unroll
        for (int mt = 0; mt < 2; mt++) {
            int row = myrow + mt * 16 + l15;
            #pragma unroll
            for (int hf = 0; hf < 2; hf++) {
                int kl0 = hf * 32 + qd * 8;
                frag_ab pfrag;
                #pragma unroll
                for (int j = 0; j < 8; j++) {
                    int kl = kl0 + j;
                    int tt = (row - jt * 64 - kl) & 255;
                    float s = bf2f(SB[tt * 66 + kl]);
                    pfrag[j] = f2bf(__expf(s + masks[jt * 64 + kl]));
                }
                #pragma unroll
                for (int et = 0; et < 5; et++) {
                    frag_ab bv = *(frag_ab*)&vT[(et * 16 + l15) * 72 + hf * 32 + qd * 8];
                    oacc[mt][et] = __builtin_amdgcn_mfma_f32_16x16x32_bf16(pfrag, bv, oacc[mt][et], 0, 0, 0);
                }
            }
        }
    }
    __syncthreads();
    mvpart[tid] = macc;
    __syncthreads();
    if (tid < 256)
        mv2[(size_t)h * 65536 + b * 256 + tid] =
            (mvpart[tid] + mvpart[tid + 256]) * 0.0625f;
    #pragma unroll
    for (int mt = 0; mt < 2; mt++) {
        #pragma unroll
        for (int r = 0; r < 4; r++) {
            float l = oacc[mt][4][r];
            l = __shfl(l, (lane & 48));
            float inv = 1.0f / l;
            int row = myrow + mt * 16 + qd * 4 + r;
            #pragma unroll
            for (int et = 0; et < 4; et++)
                qg[(size_t)row * 128 + et * 16 + l15] = f2bf(oacc[mt][et][r] * inv);
        }
    }
}

// ---------------------------------------------------------------------------
__global__ __launch_bounds__(256) void gm_reduce_kernel(const float* __restrict__ mv2,
                                                        float* __restrict__ gm) {
    int tau = blockIdx.x;
    int b = threadIdx.x;
    __shared__ float red[256];
    red[b] = mv2[b * 256 + tau] + mv2[65536 + b * 256 + tau];
    __syncthreads();
    for (int s = 128; s > 0; s >>= 1) { if (b < s) red[b] += red[b + s]; __syncthreads(); }
    if (b == 0) gm[tau] = red[0] * (1.0f / 256.0f);
}

// Single block.  5 rounds of wave-shuffle argmax (tie -> smaller index) over
// 256 values (4 waves), then per-b softmax over the selected weights.
__global__ __launch_bounds__(256) void topk_softmax_kernel(const float* __restrict__ gm,
                                                           const float* __restrict__ mv2,
                                                           int* __restrict__ delays,
                                                           float* __restrict__ tc) {
    __shared__ float vsh[4];
    __shared__ int ish[4];
    __shared__ int dsh[TOPKn];
    int tid = threadIdx.x;
    int lane = tid & 63, wave = tid >> 6;
    float v = gm[tid];
    for (int t = 0; t < TOPKn; t++) {
        float mv_ = v; int mi = tid;
        #pragma unroll
        for (int s = 32; s > 0; s >>= 1) {
            float v2 = __shfl_xor(mv_, s); int i2 = __shfl_xor(mi, s);
            if (v2 > mv_ || (v2 == mv_ && i2 < mi)) { mv_ = v2; mi = i2; }
        }
        if (lane == 0) { vsh[wave] = mv_; ish[wave] = mi; }
        __syncthreads();
        if (tid == 0) {
            float bv = vsh[0]; int bi = ish[0];
            #pragma unroll
            for (int w = 1; w < 4; w++)
                if (vsh[w] > bv || (vsh[w] == bv && ish[w] < bi)) { bv = vsh[w]; bi = ish[w]; }
            dsh[t] = bi; delays[t] = bi;
        }
        __syncthreads();
        if (tid == dsh[t]) v = -1e30f;
    }
    __syncthreads();
    int b = tid;
    float w[TOPKn];
    float m = -1e30f;
    #pragma unroll
    for (int j = 0; j < TOPKn; j++) {
        w[j] = mv2[b * 256 + dsh[j]] + mv2[65536 + b * 256 + dsh[j]];
        m = fmaxf(m, w[j]);
    }
    float ssum = 0.0f;
    #pragma unroll
    for (int j = 0; j < TOPKn; j++) { w[j] = expf(w[j] - m); ssum += w[j]; }
    #pragma unroll
    for (int j = 0; j < TOPKn; j++) tc[b * TOPKn + j] = w[j] / ssum;
}

__global__ __launch_bounds__(256) void gather_out_kernel(const short* __restrict__ x,
                                                         const int* __restrict__ lengths,
                                                         float* __restrict__ out) {
    int idx = blockIdx.x * 256 + threadIdx.x;
    int d = idx & 127;
    int b = idx >> 7;
    out[idx] = bf2f(x[((size_t)b << 15) + (size_t)(lengths[b] - 1) * Dn + d]);
}

// ---------------------------------------------------------------------------
extern "C" void kernel_launch(void* const* d_in, const int* in_sizes, int n_in,
                              void* d_out, int out_size, void* d_ws, size_t ws_size,
                              hipStream_t stream) {
    const int* paths    = (const int*)d_in[0];
    const int* lengths  = (const int*)d_in[1];
    const float* ego    = (const float*)d_in[4];
    const float* pos    = (const float*)d_in[5];
    const float* Wq     = (const float*)d_in[6];
    const float* Wk     = (const float*)d_in[7];
    const float* Wv     = (const float*)d_in[8];
    const float* Wp     = (const float*)d_in[9];
    const float* F1     = (const float*)d_in[10];
    const float* F2     = (const float*)d_in[11];
    float* out = (float*)d_out;

    const size_t need = (size_t)5 * BLD * 2 + 131072 * 2 + 131072 * 4
                        + 256 * 4 + 1280 * 4 + 16 * 4 + (size_t)NLn * WT_LAYER * 2;
    if (ws_size < need) {
        beacon_kernel<<<dim3(1), dim3(1), 0, stream>>>(out, (float)(ws_size >> 20));
        return;
    }

    short* x    = (short*)d_ws;
    short* q    = x + (size_t)1 * BLD;   // q~ -> spat
    short* kb   = x + (size_t)2 * BLD;   // k~ -> a
    short* vf   = x + (size_t)3 * BLD;   // v~ -> h (spans vf+x5)
    short* x5   = x + (size_t)4 * BLD;   // xf -> h(hi)
    short* Gb   = x + (size_t)5 * BLD;
    float* mv   = (float*)(Gb + 131072);   // mv2: [2][256][256]
    float* gm   = mv + 131072;
    float* tc   = gm + 256;
    int* delays = (int*)(tc + 1280);
    short* Wt   = (short*)(delays + 16);

    build_G_kernel<<<dim3(2, 256), dim3(256), 0, stream>>>(Gb);
    build_x_kernel<<<dim3(BLD / 1024), dim3(256), 0, stream>>>(paths, ego, pos, x);

    // Wt per layer: [0]=Wq^T | [16384]=Wk^T | [32768]=Wv^T | [49152]=0.1*Wp^T
    //               [65536]=F1^T | [98304]=F2^T | [131072]=W2^T=0.9*(Wv@Wp)^T
    wtrans_all_kernel<<<dim3(512, NLn), dim3(256), 0, stream>>>(Wq, Wk, Wv, Wp, F1, F2, Wt);
    // W2T = 9*(0.1Wp^T)@(Wv^T slow-path) for both layers in one batched launch
    mgemm(stream, Wt + 49152, Wt + 32768, Wt + 131072, nullptr,
          128, 128, 128, 128, 128, 128, 0,
          WT_LAYER, WT_LAYER, WT_LAYER, 0, NLn,
          9.0f, 0.0f, false, false);

    for (int k = 0; k < NLn; k++) {
        const short* WtL = Wt + (size_t)k * WT_LAYER;
        // xf = G_k @ x[b] (band filter; slow-path B) -> x5
        mgemm(stream, Gb + (size_t)k * 65536, x, x5, nullptr,
              256, 128, 256, 256, 128, 128, 0,
              0, 32768, 32768, 0, 256, 1.0f, 0.0f, false, false);
        // fused projections: A=x5, B=[Wq^T;Wk^T;Wv^T], N=384 split-C (BM=256)
        bgemm_kernel<false, false, false><<<dim3(256, 3), dim3(512), 0, stream>>>(
            x5, WtL + 0, 128, nullptr, nullptr, 0, q, nullptr, 128, 0,
            (long long)BLD, nullptr, nullptr);

        attn_kernel<<<dim3(2, 256), dim3(512), 0, stream>>>(q, kb, vf, paths, mv);

        gm_reduce_kernel<<<dim3(256), dim3(256), 0, stream>>>(mv, gm);
        topk_softmax_kernel<<<dim3(1), dim3(256), 0, stream>>>(gm, mv, delays, tc);

        // a = mix(x)@W2' + spat@(0.1Wp') + x  -> kb   (mix fused into A-stage)
        bgemm_kernel<true, false, true><<<dim3(256, 1), dim3(512), 0, stream>>>(
            x, WtL + 131072, 128, q, WtL + 49152, 128, kb, x, 128, 128, 0,
            tc, delays);
        // h = gelu(a @ F1) -> vf..x5 span (65536 x 256)
        bgemm_kernel<false, true, false><<<dim3(256, 2), dim3(512), 0, stream>>>(
            kb, WtL + 65536, 128, nullptr, nullptr, 0, vf, nullptr, 256, 0, 0,
            nullptr, nullptr);
        // x = h @ F2  (K=256)
        bgemm_kernel<false, false, false><<<dim3(256, 1), dim3(512), 0, stream>>>(
            vf, WtL + 98304, 256, nullptr, nullptr, 0, x, nullptr, 128, 0, 0,
            nullptr, nullptr);
    }

    gather_out_kernel<<<dim3((Bn * Dn) / 256), dim3(256), 0, stream>>>(x, lengths, out);
}

// Round 6
// 392.483 us; speedup vs baseline: 1.2461x; 1.0162x over previous
//
#include <hip/hip_runtime.h>
#include <math.h>

// Problem constants
#define Bn 256
#define Ln 256
#define Dn 128
#define Hn 2
#define En 64
#define NLn 2
#define TOPKn 5
#define NUM_TOTALn 100000
#define BLD (Bn*Ln*Dn)      // 8388608 elements per activation buffer (bf16)
#define WT_LAYER 147456     // bf16 elements of weights per layer (incl W2T)

using frag_ab = __attribute__((ext_vector_type(8))) short;   // 8 bf16
using frag_cd = __attribute__((ext_vector_type(4))) float;   // 4 f32

__device__ inline short f2bf(float f) {
    union { float f; unsigned u; } c; c.f = f;
    unsigned r = (c.u + 0x7FFFu + ((c.u >> 16) & 1u)) >> 16;   // RNE
    return (short)r;
}
__device__ inline float bf2f(short s) {
    union { unsigned u; float f; } c; c.u = ((unsigned)(unsigned short)s) << 16;
    return c.f;
}

// ---------------------------------------------------------------------------
__global__ void beacon_kernel(float* out, float v) { out[0] = v; }

// Circulant band-pass matrices G_k[t][s] = g_k[(t-s)&255], closed-form
// Dirichlet kernel.  k=0: f in [51,128] (incl Nyquist), k=1: f in [0,77]
// (incl DC).
__global__ __launch_bounds__(256) void build_G_kernel(short* __restrict__ G) {
    int k = blockIdx.x, t = blockIdx.y, s = threadIdx.x;
    int d = (t - s) & 255;
    int f1 = (k == 0) ? 51 : 1;
    int f2 = (k == 0) ? 127 : 77;
    float acc;
    if (d == 0) {
        acc = 2.0f * (float)(f2 - f1 + 1);
    } else {
        const float c = 3.14159265358979323846f / 256.0f;
        int ahi = (d * (2 * f2 + 1)) & 511;
        int alo = (d * (2 * f1 - 1)) & 511;
        acc = (sinf(c * (float)ahi) - sinf(c * (float)alo)) / sinf(c * (float)d);
    }
    acc += (k == 0) ? ((d & 1) ? -1.0f : 1.0f)   // Nyquist term cos(pi*d)
                    : 1.0f;                       // DC term
    G[((size_t)k * 256 + t) * 256 + s] = f2bf(acc * (1.0f / 256.0f));
}

// x[b,t,d] = ego[paths[b,t], d] + pos[t, d]  -> bf16
__global__ __launch_bounds__(256) void build_x_kernel(const int* __restrict__ paths,
                                                      const float* __restrict__ ego,
                                                      const float* __restrict__ pos,
                                                      short* __restrict__ x) {
    int base = (blockIdx.x * 256 + threadIdx.x) * 4;
    int d = base & 127;
    int bl = base >> 7;
    int t = bl & 255;
    float4 e = *(const float4*)(ego + (size_t)paths[bl] * Dn + d);
    float4 p = *(const float4*)(pos + t * Dn + d);
    short4 s;
    s.x = f2bf(e.x + p.x); s.y = f2bf(e.y + p.y);
    s.z = f2bf(e.z + p.z); s.w = f2bf(e.w + p.w);
    *(short4*)&x[base] = s;
}

// All 6 weight transposes in ONE kernel.  Per layer z, flat idx in [0,131072):
// [0,16384)=Wq  [16384,32768)=Wk  [32768,49152)=Wv  [49152,65536)=0.1*Wp
// [65536,98304)=F1 (K=128,N=256)  [98304,131072)=F2 (K=256,N=128)
// in f32 [z][K][N] -> out bf16 [z][N][K] * scale
__global__ __launch_bounds__(256) void wtrans_all_kernel(
        const float* __restrict__ Wq, const float* __restrict__ Wk,
        const float* __restrict__ Wv, const float* __restrict__ Wp,
        const float* __restrict__ F1, const float* __restrict__ F2,
        short* __restrict__ Wt) {
    int z = blockIdx.y;
    int idx = blockIdx.x * 256 + threadIdx.x;
    short* WtL = Wt + (size_t)z * WT_LAYER;
    if (idx < 65536) {
        int which = idx >> 14, local = idx & 16383;
        const float* src = (which == 0) ? Wq : (which == 1) ? Wk
                         : (which == 2) ? Wv : Wp;
        float scale = (which == 3) ? 0.1f : 1.0f;
        int n = local & 127, k = local >> 7;
        WtL[(which << 14) + n * 128 + k] = f2bf(scale * src[(size_t)z * 16384 + local]);
    } else if (idx < 98304) {
        int local = idx - 65536;                  // F1: [128][256]
        int n = local & 255, k = local >> 8;
        WtL[65536 + n * 128 + k] = f2bf(F1[(size_t)z * 32768 + local]);
    } else {
        int local = idx - 98304;                  // F2: [256][128]
        int n = local & 127, k = local >> 7;
        WtL[98304 + n * 256 + k] = f2bf(F2[(size_t)z * 32768 + local]);
    }
}

// ---------------------------------------------------------------------------
// General MFMA bf16 GEMM (circulant filter + W2T precompute).
// A bf16 [M][K].  BT_FAST: B bf16 [N][K]; else B bf16 [K][N] transpose-staged.
// Operand-swapped MFMA -> coalesced short4 epilogue; register prefetch.
template<bool BT_FAST, bool GELU_EPI>
__global__ __launch_bounds__(256)
void mfma_gemm_kernel(const short* A, const short* Bp, short* C, const short* R,
                      int K, int lda, int ldb, int ldc, int ldr,
                      long long sA, long long sB, long long sC, long long sR,
                      long long sCsplit, float alpha, float beta) {
    int bz = blockIdx.z;
    A += (size_t)bz * sA; C += (size_t)bz * sC;
    if (R) R += (size_t)bz * sR;
    const short* Bt = Bp + (size_t)bz * sB;
    const int m0 = blockIdx.x * 128, n0 = blockIdx.y * 128;
    int n0c = n0;
    if (sCsplit) { C += (size_t)blockIdx.y * sCsplit; n0c = 0; }
    __shared__ short As[128 * 40];
    __shared__ short Bs[128 * 40];
    int tid = threadIdx.x;
    int lane = tid & 63, wave = tid >> 6;
    int wr = (wave >> 1) * 64, wc = (wave & 1) * 64;
    int l15 = lane & 15, qd = lane >> 4;

    frag_cd zero4 = {0.f, 0.f, 0.f, 0.f};
    frag_cd acc[4][4];
    #pragma unroll
    for (int i = 0; i < 4; i++)
        #pragma unroll
        for (int j = 0; j < 4; j++) acc[i][j] = zero4;

    int arow = tid >> 1, acg = (tid & 1) * 16;
    int bnrow = tid >> 1, bcg = (tid & 1) * 16;
    int bkk = tid & 31, bnb = (tid >> 5) * 16;

    int4 pa0, pa1, pb0, pb1;
    {
        const short* ap = A + (size_t)(m0 + arow) * lda + acg;
        pa0 = *(const int4*)ap; pa1 = *(const int4*)(ap + 8);
        if (BT_FAST) {
            const short* bp = Bt + (size_t)(n0 + bnrow) * ldb + bcg;
            pb0 = *(const int4*)bp; pb1 = *(const int4*)(bp + 8);
        } else {
            const short* bp = Bt + (size_t)bkk * ldb + n0 + bnb;
            pb0 = *(const int4*)bp; pb1 = *(const int4*)(bp + 8);
        }
    }

    for (int k0 = 0; k0 < K; k0 += 32) {
        __syncthreads();
        *(int4*)&As[arow * 40 + acg] = pa0;
        *(int4*)&As[arow * 40 + acg + 8] = pa1;
        if (BT_FAST) {
            *(int4*)&Bs[bnrow * 40 + bcg] = pb0;
            *(int4*)&Bs[bnrow * 40 + bcg + 8] = pb1;
        } else {
            short tmp[16];
            *(int4*)&tmp[0] = pb0; *(int4*)&tmp[8] = pb1;
            #pragma unroll
            for (int i = 0; i < 16; i++) Bs[(bnb + i) * 40 + bkk] = tmp[i];
        }
        __syncthreads();
        if (k0 + 32 < K) {
            const short* ap = A + (size_t)(m0 + arow) * lda + k0 + 32 + acg;
            pa0 = *(const int4*)ap; pa1 = *(const int4*)(ap + 8);
            if (BT_FAST) {
                const short* bp = Bt + (size_t)(n0 + bnrow) * ldb + k0 + 32 + bcg;
                pb0 = *(const int4*)bp; pb1 = *(const int4*)(bp + 8);
            } else {
                const short* bp = Bt + (size_t)(k0 + 32 + bkk) * ldb + n0 + bnb;
                pb0 = *(const int4*)bp; pb1 = *(const int4*)(bp + 8);
            }
        }
        frag_ab af[4], bf[4];
        #pragma unroll
        for (int ms = 0; ms < 4; ms++)
            af[ms] = *(frag_ab*)&As[(wr + ms * 16 + l15) * 40 + qd * 8];
        #pragma unroll
        for (int ns = 0; ns < 4; ns++)
            bf[ns] = *(frag_ab*)&Bs[(wc + ns * 16 + l15) * 40 + qd * 8];
        #pragma unroll
        for (int ms = 0; ms < 4; ms++)
            #pragma unroll
            for (int ns = 0; ns < 4; ns++)
                acc[ms][ns] = __builtin_amdgcn_mfma_f32_16x16x32_bf16(
                    bf[ns], af[ms], acc[ms][ns], 0, 0, 0);
    }
    #pragma unroll
    for (int ms = 0; ms < 4; ms++) {
        int m = m0 + wr + ms * 16 + l15;
        #pragma unroll
        for (int ns = 0; ns < 4; ns++) {
            int nb = wc + ns * 16 + qd * 4;
            float v[4];
            #pragma unroll
            for (int r = 0; r < 4; r++) v[r] = alpha * acc[ms][ns][r];
            if (R) {
                short4 r4 = *(const short4*)&R[(size_t)m * ldr + n0 + nb];
                v[0] += beta * bf2f(r4.x); v[1] += beta * bf2f(r4.y);
                v[2] += beta * bf2f(r4.z); v[3] += beta * bf2f(r4.w);
            }
            if (GELU_EPI) {
                #pragma unroll
                for (int r = 0; r < 4; r++)
                    v[r] = v[r] * 0.5f * (1.0f + erff(v[r] * 0.70710678118654752f));
            }
            short4 o;
            o.x = f2bf(v[0]); o.y = f2bf(v[1]); o.z = f2bf(v[2]); o.w = f2bf(v[3]);
            *(short4*)&C[(size_t)m * ldc + n0c + nb] = o;
        }
    }
}

static inline void mgemm(hipStream_t s, const short* A, const short* B, short* C,
                         const short* R, int M, int N, int K,
                         int lda, int ldb, int ldc, int ldr,
                         long long sA, long long sB, long long sC, long long sR,
                         int batch, float alpha, float beta, bool btFast, bool gelu,
                         long long sCsplit = 0) {
    dim3 grid(M / 128, N / 128, batch), block(256);
    if (btFast) {
        if (gelu) mfma_gemm_kernel<true, true ><<<grid, block, 0, s>>>(A, B, C, R, K, lda, ldb, ldc, ldr, sA, sB, sC, sR, sCsplit, alpha, beta);
        else      mfma_gemm_kernel<true, false><<<grid, block, 0, s>>>(A, B, C, R, K, lda, ldb, ldc, ldr, sA, sB, sC, sR, sCsplit, alpha, beta);
    } else {
        if (gelu) mfma_gemm_kernel<false, true ><<<grid, block, 0, s>>>(A, B, C, R, K, lda, ldb, ldc, ldr, sA, sB, sC, sR, sCsplit, alpha, beta);
        else      mfma_gemm_kernel<false, false><<<grid, block, 0, s>>>(A, B, C, R, K, lda, ldb, ldc, ldr, sA, sB, sC, sR, sCsplit, alpha, beta);
    }
}

// ---------------------------------------------------------------------------
// Big-tile weight GEMM: BM=256, BN=128, BK=32.  512 threads = 8 waves (4x2).
// C = A1@B1 [+ A2@B2] + R (+opt GELU).  A row stride == K (contiguous).
// B pre-transposed bf16 [N][K]; per-grid.y chunk: B += y*128*K.
// sCsplit != 0: C += y*sCsplit, C cols 0..127 (split outputs); else cols y*128.
// MIXA: pass-0 A operand is the TOPK-delay weighted gather of A1 (= x base);
// each 256-row block is exactly one batch b, so tc[b]/delays load once.
template<bool DUAL, bool GELU_EPI, bool MIXA>
__global__ __launch_bounds__(512)
void bgemm_kernel(const short* __restrict__ A1, const short* __restrict__ B1, int K1,
                  const short* __restrict__ A2, const short* __restrict__ B2, int K2,
                  short* C, const short* __restrict__ R, int ldc, int ldr,
                  long long sCsplit,
                  const float* __restrict__ tc, const int* __restrict__ delays) {
    const int m0 = blockIdx.x * 256;
    int n0c;
    if (sCsplit) { C += (size_t)blockIdx.y * sCsplit; n0c = 0; }
    else         { n0c = blockIdx.y * 128; }
    __shared__ short As[256 * 40];   // [m][k] pad 40
    __shared__ short Bs[128 * 40];   // [n][k] pad 40
    int tid = threadIdx.x;
    int lane = tid & 63, wave = tid >> 6;
    int wr = (wave & 3) * 64, wc = (wave >> 2) * 64;
    int l15 = lane & 15, qd = lane >> 4;

    float wj[TOPKn]; int dj[TOPKn];
    if (MIXA) {
        #pragma unroll
        for (int j = 0; j < TOPKn; j++) {
            wj[j] = tc[blockIdx.x * TOPKn + j];
            dj[j] = delays[j];
        }
    }

    frag_cd zero4 = {0.f, 0.f, 0.f, 0.f};
    frag_cd acc[4][4];
    #pragma unroll
    for (int i = 0; i < 4; i++)
        #pragma unroll
        for (int j = 0; j < 4; j++) acc[i][j] = zero4;

    int arow = tid >> 1, acg = (tid & 1) * 16;   // A: 32B/thread
    int brow = tid >> 2, bcg = (tid & 3) * 8;    // B: 16B/thread

    #pragma unroll
    for (int pass = 0; pass < (DUAL ? 2 : 1); pass++) {
        const short* A = pass ? A2 : A1;
        const short* Bb = (pass ? B2 : B1);
        int K = pass ? K2 : K1;
        const bool domix = MIXA && (pass == 0);
        const short* Bt = Bb + (size_t)blockIdx.y * 128 * K;
        const short* xb = A + ((size_t)m0 << 7);   // x[b] base (MIXA pass 0)
        int4 pa0, pa1, pb0;
        {
            if (!domix) {
                const short* ap = A + (size_t)(m0 + arow) * K + acg;
                pa0 = *(const int4*)ap; pa1 = *(const int4*)(ap + 8);
            }
            pb0 = *(const int4*)(Bt + (size_t)brow * K + bcg);
        }
        for (int k0 = 0; k0 < K; k0 += 32) {
            __syncthreads();
            if (domix) {
                #pragma unroll
                for (int c = 0; c < 2; c++) {
                    int col = k0 + acg + c * 8;
                    float m8[8] = {0.f, 0.f, 0.f, 0.f, 0.f, 0.f, 0.f, 0.f};
                    #pragma unroll
                    for (int j = 0; j < TOPKn; j++) {
                        frag_ab v = *(const frag_ab*)(xb + (((arow + dj[j]) & 255) << 7) + col);
                        #pragma unroll
                        for (int i = 0; i < 8; i++) m8[i] += wj[j] * bf2f(v[i]);
                    }
                    frag_ab o;
                    #pragma unroll
                    for (int i = 0; i < 8; i++) o[i] = f2bf(m8[i]);
                    *(frag_ab*)&As[arow * 40 + acg + c * 8] = o;
                }
            } else {
                *(int4*)&As[arow * 40 + acg] = pa0;
                *(int4*)&As[arow * 40 + acg + 8] = pa1;
            }
            *(int4*)&Bs[brow * 40 + bcg] = pb0;
            __syncthreads();
            if (k0 + 32 < K) {
                if (!domix) {
                    const short* ap = A + (size_t)(m0 + arow) * K + k0 + 32 + acg;
                    pa0 = *(const int4*)ap; pa1 = *(const int4*)(ap + 8);
                }
                pb0 = *(const int4*)(Bt + (size_t)brow * K + k0 + 32 + bcg);
            }
            frag_ab af[4], bf[4];
            #pragma unroll
            for (int ms = 0; ms < 4; ms++)
                af[ms] = *(frag_ab*)&As[(wr + ms * 16 + l15) * 40 + qd * 8];
            #pragma unroll
            for (int ns = 0; ns < 4; ns++)
                bf[ns] = *(frag_ab*)&Bs[(wc + ns * 16 + l15) * 40 + qd * 8];
            #pragma unroll
            for (int ms = 0; ms < 4; ms++)
                #pragma unroll
                for (int ns = 0; ns < 4; ns++)
                    acc[ms][ns] = __builtin_amdgcn_mfma_f32_16x16x32_bf16(
                        bf[ns], af[ms], acc[ms][ns], 0, 0, 0);
        }
    }
    #pragma unroll
    for (int ms = 0; ms < 4; ms++) {
        int m = m0 + wr + ms * 16 + l15;
        #pragma unroll
        for (int ns = 0; ns < 4; ns++) {
            int nb = wc + ns * 16 + qd * 4;
            float v[4];
            #pragma unroll
            for (int r = 0; r < 4; r++) v[r] = acc[ms][ns][r];
            if (R) {
                short4 r4 = *(const short4*)&R[(size_t)m * ldr + n0c + nb];
                v[0] += bf2f(r4.x); v[1] += bf2f(r4.y);
                v[2] += bf2f(r4.z); v[3] += bf2f(r4.w);
            }
            if (GELU_EPI) {
                #pragma unroll
                for (int r = 0; r < 4; r++)
                    v[r] = v[r] * 0.5f * (1.0f + erff(v[r] * 0.70710678118654752f));
            }
            short4 o;
            o.x = f2bf(v[0]); o.y = f2bf(v[1]); o.z = f2bf(v[2]); o.w = f2bf(v[3]);
            *(short4*)&C[(size_t)m * ldc + n0c + nb] = o;
        }
    }
}

// ---------------------------------------------------------------------------
// MFMA bf16 fused attention, one WG per (h, b).  512 threads = 8 waves.
// Fixed-max softmax (scores O(0.01)).  S stored DIAGONALLY (SD[tau][keyLocal],
// stride 66 -> conflict-free mv reduction).  Denominator via ones-column in vT.
// NOTE (R4 lesson): ballot-bitmask + ternary pfrag variants inflate FETCH
// 28->88..126 MB (3 independent A/Bs) -- keep the masks[] LDS float path.
// R6: vT kv-axis XOR-swizzled at 16B blocks (phys blk = (kv>>3) ^ ((e>>3)&7)).
// Fixes the 16-way bank conflict on the transpose write (stride 72 = 36 dw
// == 4 mod 32 made banks independent of the cb lane index); bv read applies
// the same involution and stays one aligned ds_read_b128.  Ones/zero rows
// 64..79 are row-constant -> init unchanged.  Everything else byte-identical.
__global__ __launch_bounds__(512, 4) void attn_kernel(short* q,
        const short* __restrict__ kb, const short* __restrict__ vf,
        const int* __restrict__ paths, float* __restrict__ mv2) {
    int h = blockIdx.x, b = blockIdx.y;
    __shared__ short SB[256 * 72];   // phase0: q staging (stride 72); loop: SD (stride 66)
    __shared__ short ks[64 * 72];
    __shared__ short vT[80 * 72];
    __shared__ float masks[256];
    __shared__ float mvpart[512];
    int tid = threadIdx.x;
    int lane = tid & 63, wave = tid >> 6;
    int l15 = lane & 15, qd = lane >> 4;
    if (tid < 256) masks[tid] = (paths[b * 256 + tid] < NUM_TOTALn) ? 0.0f : -10000.0f;
    {
        int e0 = tid * 2;
        #pragma unroll
        for (int i = 0; i < 2; i++) {
            int e = e0 + i;
            int row = 64 + (e >> 6), col = e & 63;
            vT[row * 72 + col] = (row == 64) ? (short)0x3F80 : (short)0;
        }
    }
    short* qg = q + ((size_t)b << 15) + (size_t)h * 64;
    const short* kg = kb + ((size_t)b << 15) + (size_t)h * 64;
    const short* vg = vf + ((size_t)b << 15) + (size_t)h * 64;

    #pragma unroll
    for (int p = 0; p < 4; p++) {
        int chunk = p * 512 + tid;
        int r = chunk >> 3, cb = (chunk & 7) * 8;
        *(frag_ab*)&SB[r * 72 + cb] = *(const frag_ab*)(qg + (size_t)r * 128 + cb);
    }
    __syncthreads();
    int myrow = wave * 32;
    frag_ab aq[2][2];
    #pragma unroll
    for (int mt = 0; mt < 2; mt++)
        #pragma unroll
        for (int hf = 0; hf < 2; hf++)
            aq[mt][hf] = *(frag_ab*)&SB[(myrow + mt * 16 + l15) * 72 + hf * 32 + qd * 8];

    frag_cd zero4 = {0.f, 0.f, 0.f, 0.f};
    frag_cd oacc[2][5];
    #pragma unroll
    for (int mt = 0; mt < 2; mt++)
        #pragma unroll
        for (int et = 0; et < 5; et++) oacc[mt][et] = zero4;
    float macc = 0.0f;
    int tau = tid & 255, half = tid >> 8;

    for (int jt = 0; jt < 4; jt++) {
        __syncthreads();
        {
            int r = tid >> 3, cb = (tid & 7) * 8;
            *(frag_ab*)&ks[r * 72 + cb] =
                *(const frag_ab*)(kg + (size_t)(jt * 64 + r) * 128 + cb);
            frag_ab v8 = *(const frag_ab*)(vg + (size_t)(jt * 64 + r) * 128 + cb);
            // vT swizzled write: e = cb+i, phys block = (r>>3) ^ ((e>>3)&7);
            // e>>3 == cb>>3 (cb multiple of 8, i<8) -> per-thread constant.
            int swz = (((r >> 3) ^ (cb >> 3)) << 3) + (r & 7);
            #pragma unroll
            for (int i = 0; i < 8; i++) vT[(cb + i) * 72 + swz] = v8[i];
        }
        __syncthreads();
        #pragma unroll
        for (int mt = 0; mt < 2; mt++) {
            #pragma unroll
            for (int nt = 0; nt < 4; nt++) {
                frag_ab b0 = *(frag_ab*)&ks[(nt * 16 + l15) * 72 + qd * 8];
                frag_ab b1 = *(frag_ab*)&ks[(nt * 16 + l15) * 72 + 32 + qd * 8];
                frag_cd c = zero4;
                c = __builtin_amdgcn_mfma_f32_16x16x32_bf16(aq[mt][0], b0, c, 0, 0, 0);
                c = __builtin_amdgcn_mfma_f32_16x16x32_bf16(aq[mt][1], b1, c, 0, 0, 0);
                int keyLocal = nt * 16 + l15;
                #pragma unroll
                for (int r = 0; r < 4; r++) {
                    int row = myrow + mt * 16 + qd * 4 + r;
                    int tt = (row - jt * 64 - keyLocal) & 255;
                    SB[tt * 66 + keyLocal] = f2bf(c[r] * 0.125f);
                }
            }
        }
        __syncthreads();
        {
            const int* SD32 = (const int*)&SB[tau * 66 + half * 32];
            #pragma unroll
            for (int i = 0; i < 16; i++) {
                int pk = SD32[i];
                macc += bf2f((short)(pk & 0xFFFF)) + bf2f((short)(pk >> 16));
            }
        }
        #pragma unroll
        for (int mt = 0; mt < 2; mt++) {
            int row = myrow + mt * 16 + l15;
            #pragma unroll
            for (int hf = 0; hf < 2; hf++) {
                int kl0 = hf * 32 + qd * 8;
                frag_ab pfrag;
                #pragma unroll
                for (int j = 0; j < 8; j++) {
                    int kl = kl0 + j;
                    int tt = (row - jt * 64 - kl) & 255;
                    float s = bf2f(SB[tt * 66 + kl]);
                    pfrag[j] = f2bf(__expf(s + masks[jt * 64 + kl]));
                }
                #pragma unroll
                for (int et = 0; et < 5; et++) {
                    // swizzled bv read: e = et*16+l15; phys blk = (hf*4+qd) ^ ((e>>3)&7)
                    int e = et * 16 + l15;
                    int blk = (hf * 4 + qd) ^ ((e >> 3) & 7);
                    frag_ab bv = *(frag_ab*)&vT[e * 72 + (blk << 3)];
                    oacc[mt][et] = __builtin_amdgcn_mfma_f32_16x16x32_bf16(pfrag, bv, oacc[mt][et], 0, 0, 0);
                }
            }
        }
    }
    __syncthreads();
    mvpart[tid] = macc;
    __syncthreads();
    if (tid < 256)
        mv2[(size_t)h * 65536 + b * 256 + tid] =
            (mvpart[tid] + mvpart[tid + 256]) * 0.0625f;
    #pragma unroll
    for (int mt = 0; mt < 2; mt++) {
        #pragma unroll
        for (int r = 0; r < 4; r++) {
            float l = oacc[mt][4][r];
            l = __shfl(l, (lane & 48));
            float inv = 1.0f / l;
            int row = myrow + mt * 16 + qd * 4 + r;
            #pragma unroll
            for (int et = 0; et < 4; et++)
                qg[(size_t)row * 128 + et * 16 + l15] = f2bf(oacc[mt][et][r] * inv);
        }
    }
}

// ---------------------------------------------------------------------------
__global__ __launch_bounds__(256) void gm_reduce_kernel(const float* __restrict__ mv2,
                                                        float* __restrict__ gm) {
    int tau = blockIdx.x;
    int b = threadIdx.x;
    __shared__ float red[256];
    red[b] = mv2[b * 256 + tau] + mv2[65536 + b * 256 + tau];
    __syncthreads();
    for (int s = 128; s > 0; s >>= 1) { if (b < s) red[b] += red[b + s]; __syncthreads(); }
    if (b == 0) gm[tau] = red[0] * (1.0f / 256.0f);
}

// Single block.  5 rounds of wave-shuffle argmax (tie -> smaller index) over
// 256 values (4 waves), then per-b softmax over the selected weights.
__global__ __launch_bounds__(256) void topk_softmax_kernel(const float* __restrict__ gm,
                                                           const float* __restrict__ mv2,
                                                           int* __restrict__ delays,
                                                           float* __restrict__ tc) {
    __shared__ float vsh[4];
    __shared__ int ish[4];
    __shared__ int dsh[TOPKn];
    int tid = threadIdx.x;
    int lane = tid & 63, wave = tid >> 6;
    float v = gm[tid];
    for (int t = 0; t < TOPKn; t++) {
        float mv_ = v; int mi = tid;
        #pragma unroll
        for (int s = 32; s > 0; s >>= 1) {
            float v2 = __shfl_xor(mv_, s); int i2 = __shfl_xor(mi, s);
            if (v2 > mv_ || (v2 == mv_ && i2 < mi)) { mv_ = v2; mi = i2; }
        }
        if (lane == 0) { vsh[wave] = mv_; ish[wave] = mi; }
        __syncthreads();
        if (tid == 0) {
            float bv = vsh[0]; int bi = ish[0];
            #pragma unroll
            for (int w = 1; w < 4; w++)
                if (vsh[w] > bv || (vsh[w] == bv && ish[w] < bi)) { bv = vsh[w]; bi = ish[w]; }
            dsh[t] = bi; delays[t] = bi;
        }
        __syncthreads();
        if (tid == dsh[t]) v = -1e30f;
    }
    __syncthreads();
    int b = tid;
    float w[TOPKn];
    float m = -1e30f;
    #pragma unroll
    for (int j = 0; j < TOPKn; j++) {
        w[j] = mv2[b * 256 + dsh[j]] + mv2[65536 + b * 256 + dsh[j]];
        m = fmaxf(m, w[j]);
    }
    float ssum = 0.0f;
    #pragma unroll
    for (int j = 0; j < TOPKn; j++) { w[j] = expf(w[j] - m); ssum += w[j]; }
    #pragma unroll
    for (int j = 0; j < TOPKn; j++) tc[b * TOPKn + j] = w[j] / ssum;
}

__global__ __launch_bounds__(256) void gather_out_kernel(const short* __restrict__ x,
                                                         const int* __restrict__ lengths,
                                                         float* __restrict__ out) {
    int idx = blockIdx.x * 256 + threadIdx.x;
    int d = idx & 127;
    int b = idx >> 7;
    out[idx] = bf2f(x[((size_t)b << 15) + (size_t)(lengths[b] - 1) * Dn + d]);
}

// ---------------------------------------------------------------------------
extern "C" void kernel_launch(void* const* d_in, const int* in_sizes, int n_in,
                              void* d_out, int out_size, void* d_ws, size_t ws_size,
                              hipStream_t stream) {
    const int* paths    = (const int*)d_in[0];
    const int* lengths  = (const int*)d_in[1];
    const float* ego    = (const float*)d_in[4];
    const float* pos    = (const float*)d_in[5];
    const float* Wq     = (const float*)d_in[6];
    const float* Wk     = (const float*)d_in[7];
    const float* Wv     = (const float*)d_in[8];
    const float* Wp     = (const float*)d_in[9];
    const float* F1     = (const float*)d_in[10];
    const float* F2     = (const float*)d_in[11];
    float* out = (float*)d_out;

    const size_t need = (size_t)5 * BLD * 2 + 131072 * 2 + 131072 * 4
                        + 256 * 4 + 1280 * 4 + 16 * 4 + (size_t)NLn * WT_LAYER * 2;
    if (ws_size < need) {
        beacon_kernel<<<dim3(1), dim3(1), 0, stream>>>(out, (float)(ws_size >> 20));
        return;
    }

    short* x    = (short*)d_ws;
    short* q    = x + (size_t)1 * BLD;   // q~ -> spat
    short* kb   = x + (size_t)2 * BLD;   // k~ -> a
    short* vf   = x + (size_t)3 * BLD;   // v~ -> h (spans vf+x5)
    short* x5   = x + (size_t)4 * BLD;   // xf -> h(hi)
    short* Gb   = x + (size_t)5 * BLD;
    float* mv   = (float*)(Gb + 131072);   // mv2: [2][256][256]
    float* gm   = mv + 131072;
    float* tc   = gm + 256;
    int* delays = (int*)(tc + 1280);
    short* Wt   = (short*)(delays + 16);

    build_G_kernel<<<dim3(2, 256), dim3(256), 0, stream>>>(Gb);
    build_x_kernel<<<dim3(BLD / 1024), dim3(256), 0, stream>>>(paths, ego, pos, x);

    // Wt per layer: [0]=Wq^T | [16384]=Wk^T | [32768]=Wv^T | [49152]=0.1*Wp^T
    //               [65536]=F1^T | [98304]=F2^T | [131072]=W2^T=0.9*(Wv@Wp)^T
    wtrans_all_kernel<<<dim3(512, NLn), dim3(256), 0, stream>>>(Wq, Wk, Wv, Wp, F1, F2, Wt);
    // W2T = 9*(0.1Wp^T)@(Wv^T slow-path) for both layers in one batched launch
    mgemm(stream, Wt + 49152, Wt + 32768, Wt + 131072, nullptr,
          128, 128, 128, 128, 128, 128, 0,
          WT_LAYER, WT_LAYER, WT_LAYER, 0, NLn,
          9.0f, 0.0f, false, false);

    for (int k = 0; k < NLn; k++) {
        const short* WtL = Wt + (size_t)k * WT_LAYER;
        // xf = G_k @ x[b] (band filter; slow-path B) -> x5
        mgemm(stream, Gb + (size_t)k * 65536, x, x5, nullptr,
              256, 128, 256, 256, 128, 128, 0,
              0, 32768, 32768, 0, 256, 1.0f, 0.0f, false, false);
        // fused projections: A=x5, B=[Wq^T;Wk^T;Wv^T], N=384 split-C (BM=256)
        bgemm_kernel<false, false, false><<<dim3(256, 3), dim3(512), 0, stream>>>(
            x5, WtL + 0, 128, nullptr, nullptr, 0, q, nullptr, 128, 0,
            (long long)BLD, nullptr, nullptr);

        attn_kernel<<<dim3(2, 256), dim3(512), 0, stream>>>(q, kb, vf, paths, mv);

        gm_reduce_kernel<<<dim3(256), dim3(256), 0, stream>>>(mv, gm);
        topk_softmax_kernel<<<dim3(1), dim3(256), 0, stream>>>(gm, mv, delays, tc);

        // a = mix(x)@W2' + spat@(0.1Wp') + x  -> kb   (mix fused into A-stage)
        bgemm_kernel<true, false, true><<<dim3(256, 1), dim3(512), 0, stream>>>(
            x, WtL + 131072, 128, q, WtL + 49152, 128, kb, x, 128, 128, 0,
            tc, delays);
        // h = gelu(a @ F1) -> vf..x5 span (65536 x 256)
        bgemm_kernel<false, true, false><<<dim3(256, 2), dim3(512), 0, stream>>>(
            kb, WtL + 65536, 128, nullptr, nullptr, 0, vf, nullptr, 256, 0, 0,
            nullptr, nullptr);
        // x = h @ F2  (K=256)
        bgemm_kernel<false, false, false><<<dim3(256, 1), dim3(512), 0, stream>>>(
            vf, WtL + 98304, 256, nullptr, nullptr, 0, x, nullptr, 128, 0, 0,
            nullptr, nullptr);
    }

    gather_out_kernel<<<dim3((Bn * Dn) / 256), dim3(256), 0, stream>>>(x, lengths, out);
}

// Round 7
// 378.372 us; speedup vs baseline: 1.2925x; 1.0373x over previous
//
#include <hip/hip_runtime.h>
#include <math.h>

// Problem constants
#define Bn 256
#define Ln 256
#define Dn 128
#define Hn 2
#define En 64
#define NLn 2
#define TOPKn 5
#define NUM_TOTALn 100000
#define BLD (Bn*Ln*Dn)      // 8388608 elements per activation buffer (bf16)
#define WT_LAYER 147456     // bf16 elements of weights per layer (incl W2T)

using frag_ab = __attribute__((ext_vector_type(8))) short;   // 8 bf16
using frag_cd = __attribute__((ext_vector_type(4))) float;   // 4 f32

__device__ inline short f2bf(float f) {
    union { float f; unsigned u; } c; c.f = f;
    unsigned r = (c.u + 0x7FFFu + ((c.u >> 16) & 1u)) >> 16;   // RNE
    return (short)r;
}
__device__ inline float bf2f(short s) {
    union { unsigned u; float f; } c; c.u = ((unsigned)(unsigned short)s) << 16;
    return c.f;
}

// ---------------------------------------------------------------------------
__global__ void beacon_kernel(float* out, float v) { out[0] = v; }

// Circulant band-pass matrices G_k[t][s] = g_k[(t-s)&255], closed-form
// Dirichlet kernel.  k=0: f in [51,128] (incl Nyquist), k=1: f in [0,77]
// (incl DC).
__global__ __launch_bounds__(256) void build_G_kernel(short* __restrict__ G) {
    int k = blockIdx.x, t = blockIdx.y, s = threadIdx.x;
    int d = (t - s) & 255;
    int f1 = (k == 0) ? 51 : 1;
    int f2 = (k == 0) ? 127 : 77;
    float acc;
    if (d == 0) {
        acc = 2.0f * (float)(f2 - f1 + 1);
    } else {
        const float c = 3.14159265358979323846f / 256.0f;
        int ahi = (d * (2 * f2 + 1)) & 511;
        int alo = (d * (2 * f1 - 1)) & 511;
        acc = (sinf(c * (float)ahi) - sinf(c * (float)alo)) / sinf(c * (float)d);
    }
    acc += (k == 0) ? ((d & 1) ? -1.0f : 1.0f)   // Nyquist term cos(pi*d)
                    : 1.0f;                       // DC term
    G[((size_t)k * 256 + t) * 256 + s] = f2bf(acc * (1.0f / 256.0f));
}

// x[b,t,d] = ego[paths[b,t], d] + pos[t, d]  -> bf16
__global__ __launch_bounds__(256) void build_x_kernel(const int* __restrict__ paths,
                                                      const float* __restrict__ ego,
                                                      const float* __restrict__ pos,
                                                      short* __restrict__ x) {
    int base = (blockIdx.x * 256 + threadIdx.x) * 4;
    int d = base & 127;
    int bl = base >> 7;
    int t = bl & 255;
    float4 e = *(const float4*)(ego + (size_t)paths[bl] * Dn + d);
    float4 p = *(const float4*)(pos + t * Dn + d);
    short4 s;
    s.x = f2bf(e.x + p.x); s.y = f2bf(e.y + p.y);
    s.z = f2bf(e.z + p.z); s.w = f2bf(e.w + p.w);
    *(short4*)&x[base] = s;
}

// All 6 weight transposes in ONE kernel.  Per layer z, flat idx in [0,131072):
// [0,16384)=Wq  [16384,32768)=Wk  [32768,49152)=Wv  [49152,65536)=0.1*Wp
// [65536,98304)=F1 (K=128,N=256)  [98304,131072)=F2 (K=256,N=128)
// in f32 [z][K][N] -> out bf16 [z][N][K] * scale
__global__ __launch_bounds__(256) void wtrans_all_kernel(
        const float* __restrict__ Wq, const float* __restrict__ Wk,
        const float* __restrict__ Wv, const float* __restrict__ Wp,
        const float* __restrict__ F1, const float* __restrict__ F2,
        short* __restrict__ Wt) {
    int z = blockIdx.y;
    int idx = blockIdx.x * 256 + threadIdx.x;
    short* WtL = Wt + (size_t)z * WT_LAYER;
    if (idx < 65536) {
        int which = idx >> 14, local = idx & 16383;
        const float* src = (which == 0) ? Wq : (which == 1) ? Wk
                         : (which == 2) ? Wv : Wp;
        float scale = (which == 3) ? 0.1f : 1.0f;
        int n = local & 127, k = local >> 7;
        WtL[(which << 14) + n * 128 + k] = f2bf(scale * src[(size_t)z * 16384 + local]);
    } else if (idx < 98304) {
        int local = idx - 65536;                  // F1: [128][256]
        int n = local & 255, k = local >> 8;
        WtL[65536 + n * 128 + k] = f2bf(F1[(size_t)z * 32768 + local]);
    } else {
        int local = idx - 98304;                  // F2: [256][128]
        int n = local & 127, k = local >> 7;
        WtL[98304 + n * 256 + k] = f2bf(F2[(size_t)z * 32768 + local]);
    }
}

// ---------------------------------------------------------------------------
// General MFMA bf16 GEMM (W2T precompute only now).
// A bf16 [M][K].  BT_FAST: B bf16 [N][K]; else B bf16 [K][N] transpose-staged.
template<bool BT_FAST, bool GELU_EPI>
__global__ __launch_bounds__(256)
void mfma_gemm_kernel(const short* A, const short* Bp, short* C, const short* R,
                      int K, int lda, int ldb, int ldc, int ldr,
                      long long sA, long long sB, long long sC, long long sR,
                      long long sCsplit, float alpha, float beta) {
    int bz = blockIdx.z;
    A += (size_t)bz * sA; C += (size_t)bz * sC;
    if (R) R += (size_t)bz * sR;
    const short* Bt = Bp + (size_t)bz * sB;
    const int m0 = blockIdx.x * 128, n0 = blockIdx.y * 128;
    int n0c = n0;
    if (sCsplit) { C += (size_t)blockIdx.y * sCsplit; n0c = 0; }
    __shared__ short As[128 * 40];
    __shared__ short Bs[128 * 40];
    int tid = threadIdx.x;
    int lane = tid & 63, wave = tid >> 6;
    int wr = (wave >> 1) * 64, wc = (wave & 1) * 64;
    int l15 = lane & 15, qd = lane >> 4;

    frag_cd zero4 = {0.f, 0.f, 0.f, 0.f};
    frag_cd acc[4][4];
    #pragma unroll
    for (int i = 0; i < 4; i++)
        #pragma unroll
        for (int j = 0; j < 4; j++) acc[i][j] = zero4;

    int arow = tid >> 1, acg = (tid & 1) * 16;
    int bnrow = tid >> 1, bcg = (tid & 1) * 16;
    int bkk = tid & 31, bnb = (tid >> 5) * 16;

    int4 pa0, pa1, pb0, pb1;
    {
        const short* ap = A + (size_t)(m0 + arow) * lda + acg;
        pa0 = *(const int4*)ap; pa1 = *(const int4*)(ap + 8);
        if (BT_FAST) {
            const short* bp = Bt + (size_t)(n0 + bnrow) * ldb + bcg;
            pb0 = *(const int4*)bp; pb1 = *(const int4*)(bp + 8);
        } else {
            const short* bp = Bt + (size_t)bkk * ldb + n0 + bnb;
            pb0 = *(const int4*)bp; pb1 = *(const int4*)(bp + 8);
        }
    }

    for (int k0 = 0; k0 < K; k0 += 32) {
        __syncthreads();
        *(int4*)&As[arow * 40 + acg] = pa0;
        *(int4*)&As[arow * 40 + acg + 8] = pa1;
        if (BT_FAST) {
            *(int4*)&Bs[bnrow * 40 + bcg] = pb0;
            *(int4*)&Bs[bnrow * 40 + bcg + 8] = pb1;
        } else {
            short tmp[16];
            *(int4*)&tmp[0] = pb0; *(int4*)&tmp[8] = pb1;
            #pragma unroll
            for (int i = 0; i < 16; i++) Bs[(bnb + i) * 40 + bkk] = tmp[i];
        }
        __syncthreads();
        if (k0 + 32 < K) {
            const short* ap = A + (size_t)(m0 + arow) * lda + k0 + 32 + acg;
            pa0 = *(const int4*)ap; pa1 = *(const int4*)(ap + 8);
            if (BT_FAST) {
                const short* bp = Bt + (size_t)(n0 + bnrow) * ldb + k0 + 32 + bcg;
                pb0 = *(const int4*)bp; pb1 = *(const int4*)(bp + 8);
            } else {
                const short* bp = Bt + (size_t)(k0 + 32 + bkk) * ldb + n0 + bnb;
                pb0 = *(const int4*)bp; pb1 = *(const int4*)(bp + 8);
            }
        }
        frag_ab af[4], bf[4];
        #pragma unroll
        for (int ms = 0; ms < 4; ms++)
            af[ms] = *(frag_ab*)&As[(wr + ms * 16 + l15) * 40 + qd * 8];
        #pragma unroll
        for (int ns = 0; ns < 4; ns++)
            bf[ns] = *(frag_ab*)&Bs[(wc + ns * 16 + l15) * 40 + qd * 8];
        #pragma unroll
        for (int ms = 0; ms < 4; ms++)
            #pragma unroll
            for (int ns = 0; ns < 4; ns++)
                acc[ms][ns] = __builtin_amdgcn_mfma_f32_16x16x32_bf16(
                    bf[ns], af[ms], acc[ms][ns], 0, 0, 0);
    }
    #pragma unroll
    for (int ms = 0; ms < 4; ms++) {
        int m = m0 + wr + ms * 16 + l15;
        #pragma unroll
        for (int ns = 0; ns < 4; ns++) {
            int nb = wc + ns * 16 + qd * 4;
            float v[4];
            #pragma unroll
            for (int r = 0; r < 4; r++) v[r] = alpha * acc[ms][ns][r];
            if (R) {
                short4 r4 = *(const short4*)&R[(size_t)m * ldr + n0 + nb];
                v[0] += beta * bf2f(r4.x); v[1] += beta * bf2f(r4.y);
                v[2] += beta * bf2f(r4.z); v[3] += beta * bf2f(r4.w);
            }
            if (GELU_EPI) {
                #pragma unroll
                for (int r = 0; r < 4; r++)
                    v[r] = v[r] * 0.5f * (1.0f + erff(v[r] * 0.70710678118654752f));
            }
            short4 o;
            o.x = f2bf(v[0]); o.y = f2bf(v[1]); o.z = f2bf(v[2]); o.w = f2bf(v[3]);
            *(short4*)&C[(size_t)m * ldc + n0c + nb] = o;
        }
    }
}

static inline void mgemm(hipStream_t s, const short* A, const short* B, short* C,
                         const short* R, int M, int N, int K,
                         int lda, int ldb, int ldc, int ldr,
                         long long sA, long long sB, long long sC, long long sR,
                         int batch, float alpha, float beta, bool btFast, bool gelu,
                         long long sCsplit = 0) {
    dim3 grid(M / 128, N / 128, batch), block(256);
    if (btFast) {
        if (gelu) mfma_gemm_kernel<true, true ><<<grid, block, 0, s>>>(A, B, C, R, K, lda, ldb, ldc, ldr, sA, sB, sC, sR, sCsplit, alpha, beta);
        else      mfma_gemm_kernel<true, false><<<grid, block, 0, s>>>(A, B, C, R, K, lda, ldb, ldc, ldr, sA, sB, sC, sR, sCsplit, alpha, beta);
    } else {
        if (gelu) mfma_gemm_kernel<false, true ><<<grid, block, 0, s>>>(A, B, C, R, K, lda, ldb, ldc, ldr, sA, sB, sC, sR, sCsplit, alpha, beta);
        else      mfma_gemm_kernel<false, false><<<grid, block, 0, s>>>(A, B, C, R, K, lda, ldb, ldc, ldr, sA, sB, sC, sR, sCsplit, alpha, beta);
    }
}

// ---------------------------------------------------------------------------
// Fused band-filter + QKV projections.  One WG per batch b (grid 256, 1/CU),
// 512 threads = 8 waves (4x2).
// Phase 1: xf = G_k @ x[b]  (256x128, K=256; x[b] is [s][d] -> slow-path
//          transpose staging, exactly the old filter mgemm pattern) -> LDS
//          (stride 136: 68 dw == 4 mod 32 -> rows bank-spread).
// Phase 2: for y in {q,k,v}: C_y[b] = xf @ Wy^T (K=128, BT_FAST staging,
//          A read straight from LDS xf -> no re-staging, no global round-trip).
// Saves: x5 write+read (33 MB/layer) + 1 launch/layer.  All global access
// patterns inherited verbatim from the proven kernels.
__global__ __launch_bounds__(512)
void filtproj_kernel(const short* __restrict__ G, const short* __restrict__ x,
                     const short* __restrict__ W, short* __restrict__ q) {
    int b = blockIdx.x;
    __shared__ short As[256 * 40];
    __shared__ short Bs[128 * 40];
    __shared__ short xf[256 * 136];
    int tid = threadIdx.x;
    int lane = tid & 63, wave = tid >> 6;
    int wr = (wave & 3) * 64, wc = (wave >> 2) * 64;
    int l15 = lane & 15, qd = lane >> 4;
    const short* xb = x + ((size_t)b << 15);

    frag_cd zero4 = {0.f, 0.f, 0.f, 0.f};
    frag_cd acc[4][4];
    #pragma unroll
    for (int i = 0; i < 4; i++)
        #pragma unroll
        for (int j = 0; j < 4; j++) acc[i][j] = zero4;

    int arow = tid >> 1, acg = (tid & 1) * 16;   // A: 32B/thread (256x32 tile)
    int bkk = tid & 31, bnb = (tid >> 5) * 16;   // B slow-path (tid<256 only)

    // ---- phase 1: xf = G @ x[b] ----
    int4 pa0, pa1, pb0, pb1;
    {
        const short* ap = G + (size_t)arow * 256 + acg;
        pa0 = *(const int4*)ap; pa1 = *(const int4*)(ap + 8);
        if (tid < 256) {
            const short* bp = xb + (size_t)bkk * 128 + bnb;
            pb0 = *(const int4*)bp; pb1 = *(const int4*)(bp + 8);
        }
    }
    for (int k0 = 0; k0 < 256; k0 += 32) {
        __syncthreads();
        *(int4*)&As[arow * 40 + acg] = pa0;
        *(int4*)&As[arow * 40 + acg + 8] = pa1;
        if (tid < 256) {
            short tmp[16];
            *(int4*)&tmp[0] = pb0; *(int4*)&tmp[8] = pb1;
            #pragma unroll
            for (int i = 0; i < 16; i++) Bs[(bnb + i) * 40 + bkk] = tmp[i];
        }
        __syncthreads();
        if (k0 + 32 < 256) {
            const short* ap = G + (size_t)arow * 256 + k0 + 32 + acg;
            pa0 = *(const int4*)ap; pa1 = *(const int4*)(ap + 8);
            if (tid < 256) {
                const short* bp = xb + (size_t)(k0 + 32 + bkk) * 128 + bnb;
                pb0 = *(const int4*)bp; pb1 = *(const int4*)(bp + 8);
            }
        }
        frag_ab af[4], bf[4];
        #pragma unroll
        for (int ms = 0; ms < 4; ms++)
            af[ms] = *(frag_ab*)&As[(wr + ms * 16 + l15) * 40 + qd * 8];
        #pragma unroll
        for (int ns = 0; ns < 4; ns++)
            bf[ns] = *(frag_ab*)&Bs[(wc + ns * 16 + l15) * 40 + qd * 8];
        #pragma unroll
        for (int ms = 0; ms < 4; ms++)
            #pragma unroll
            for (int ns = 0; ns < 4; ns++)
                acc[ms][ns] = __builtin_amdgcn_mfma_f32_16x16x32_bf16(
                    bf[ns], af[ms], acc[ms][ns], 0, 0, 0);
    }
    // epilogue -> LDS xf (same f2bf rounding as the old global store)
    #pragma unroll
    for (int ms = 0; ms < 4; ms++) {
        int m = wr + ms * 16 + l15;
        #pragma unroll
        for (int ns = 0; ns < 4; ns++) {
            int nb = wc + ns * 16 + qd * 4;
            short4 o;
            o.x = f2bf(acc[ms][ns][0]); o.y = f2bf(acc[ms][ns][1]);
            o.z = f2bf(acc[ms][ns][2]); o.w = f2bf(acc[ms][ns][3]);
            *(short4*)&xf[m * 136 + nb] = o;
        }
    }

    // ---- phase 2: C_y[b] = xf @ Wy^T, y = 0..2 ----
    int brow = tid >> 2, bcg = (tid & 3) * 8;    // B: 16B/thread (128x32 tile)
    #pragma unroll 1
    for (int y = 0; y < 3; y++) {
        const short* Bt = W + y * 16384;
        #pragma unroll
        for (int i = 0; i < 4; i++)
            #pragma unroll
            for (int j = 0; j < 4; j++) acc[i][j] = zero4;
        int4 pb = *(const int4*)(Bt + (size_t)brow * 128 + bcg);
        for (int k0 = 0; k0 < 128; k0 += 32) {
            __syncthreads();
            *(int4*)&Bs[brow * 40 + bcg] = pb;
            __syncthreads();
            if (k0 + 32 < 128)
                pb = *(const int4*)(Bt + (size_t)brow * 128 + k0 + 32 + bcg);
            frag_ab af[4], bf[4];
            #pragma unroll
            for (int ms = 0; ms < 4; ms++)
                af[ms] = *(frag_ab*)&xf[(wr + ms * 16 + l15) * 136 + k0 + qd * 8];
            #pragma unroll
            for (int ns = 0; ns < 4; ns++)
                bf[ns] = *(frag_ab*)&Bs[(wc + ns * 16 + l15) * 40 + qd * 8];
            #pragma unroll
            for (int ms = 0; ms < 4; ms++)
                #pragma unroll
                for (int ns = 0; ns < 4; ns++)
                    acc[ms][ns] = __builtin_amdgcn_mfma_f32_16x16x32_bf16(
                        bf[ns], af[ms], acc[ms][ns], 0, 0, 0);
        }
        short* Cy = q + (size_t)y * BLD + ((size_t)b << 15);
        #pragma unroll
        for (int ms = 0; ms < 4; ms++) {
            int m = wr + ms * 16 + l15;
            #pragma unroll
            for (int ns = 0; ns < 4; ns++) {
                int nb = wc + ns * 16 + qd * 4;
                short4 o;
                o.x = f2bf(acc[ms][ns][0]); o.y = f2bf(acc[ms][ns][1]);
                o.z = f2bf(acc[ms][ns][2]); o.w = f2bf(acc[ms][ns][3]);
                *(short4*)&Cy[(size_t)m * 128 + nb] = o;
            }
        }
    }
}

// ---------------------------------------------------------------------------
// Big-tile weight GEMM: BM=256, BN=128, BK=32.  512 threads = 8 waves (4x2).
// C = A1@B1 [+ A2@B2] + R (+opt GELU).  B pre-transposed bf16 [N][K].
// MIXA: pass-0 A operand is the TOPK-delay weighted gather of A1 (= x base).
template<bool DUAL, bool GELU_EPI, bool MIXA>
__global__ __launch_bounds__(512)
void bgemm_kernel(const short* __restrict__ A1, const short* __restrict__ B1, int K1,
                  const short* __restrict__ A2, const short* __restrict__ B2, int K2,
                  short* C, const short* __restrict__ R, int ldc, int ldr,
                  long long sCsplit,
                  const float* __restrict__ tc, const int* __restrict__ delays) {
    const int m0 = blockIdx.x * 256;
    int n0c;
    if (sCsplit) { C += (size_t)blockIdx.y * sCsplit; n0c = 0; }
    else         { n0c = blockIdx.y * 128; }
    __shared__ short As[256 * 40];   // [m][k] pad 40
    __shared__ short Bs[128 * 40];   // [n][k] pad 40
    int tid = threadIdx.x;
    int lane = tid & 63, wave = tid >> 6;
    int wr = (wave & 3) * 64, wc = (wave >> 2) * 64;
    int l15 = lane & 15, qd = lane >> 4;

    float wj[TOPKn]; int dj[TOPKn];
    if (MIXA) {
        #pragma unroll
        for (int j = 0; j < TOPKn; j++) {
            wj[j] = tc[blockIdx.x * TOPKn + j];
            dj[j] = delays[j];
        }
    }

    frag_cd zero4 = {0.f, 0.f, 0.f, 0.f};
    frag_cd acc[4][4];
    #pragma unroll
    for (int i = 0; i < 4; i++)
        #pragma unroll
        for (int j = 0; j < 4; j++) acc[i][j] = zero4;

    int arow = tid >> 1, acg = (tid & 1) * 16;   // A: 32B/thread
    int brow = tid >> 2, bcg = (tid & 3) * 8;    // B: 16B/thread

    #pragma unroll
    for (int pass = 0; pass < (DUAL ? 2 : 1); pass++) {
        const short* A = pass ? A2 : A1;
        const short* Bb = (pass ? B2 : B1);
        int K = pass ? K2 : K1;
        const bool domix = MIXA && (pass == 0);
        const short* Bt = Bb + (size_t)blockIdx.y * 128 * K;
        const short* xb = A + ((size_t)m0 << 7);   // x[b] base (MIXA pass 0)
        int4 pa0, pa1, pb0;
        {
            if (!domix) {
                const short* ap = A + (size_t)(m0 + arow) * K + acg;
                pa0 = *(const int4*)ap; pa1 = *(const int4*)(ap + 8);
            }
            pb0 = *(const int4*)(Bt + (size_t)brow * K + bcg);
        }
        for (int k0 = 0; k0 < K; k0 += 32) {
            __syncthreads();
            if (domix) {
                #pragma unroll
                for (int c = 0; c < 2; c++) {
                    int col = k0 + acg + c * 8;
                    float m8[8] = {0.f, 0.f, 0.f, 0.f, 0.f, 0.f, 0.f, 0.f};
                    #pragma unroll
                    for (int j = 0; j < TOPKn; j++) {
                        frag_ab v = *(const frag_ab*)(xb + (((arow + dj[j]) & 255) << 7) + col);
                        #pragma unroll
                        for (int i = 0; i < 8; i++) m8[i] += wj[j] * bf2f(v[i]);
                    }
                    frag_ab o;
                    #pragma unroll
                    for (int i = 0; i < 8; i++) o[i] = f2bf(m8[i]);
                    *(frag_ab*)&As[arow * 40 + acg + c * 8] = o;
                }
            } else {
                *(int4*)&As[arow * 40 + acg] = pa0;
                *(int4*)&As[arow * 40 + acg + 8] = pa1;
            }
            *(int4*)&Bs[brow * 40 + bcg] = pb0;
            __syncthreads();
            if (k0 + 32 < K) {
                if (!domix) {
                    const short* ap = A + (size_t)(m0 + arow) * K + k0 + 32 + acg;
                    pa0 = *(const int4*)ap; pa1 = *(const int4*)(ap + 8);
                }
                pb0 = *(const int4*)(Bt + (size_t)brow * K + k0 + 32 + bcg);
            }
            frag_ab af[4], bf[4];
            #pragma unroll
            for (int ms = 0; ms < 4; ms++)
                af[ms] = *(frag_ab*)&As[(wr + ms * 16 + l15) * 40 + qd * 8];
            #pragma unroll
            for (int ns = 0; ns < 4; ns++)
                bf[ns] = *(frag_ab*)&Bs[(wc + ns * 16 + l15) * 40 + qd * 8];
            #pragma unroll
            for (int ms = 0; ms < 4; ms++)
                #pragma unroll
                for (int ns = 0; ns < 4; ns++)
                    acc[ms][ns] = __builtin_amdgcn_mfma_f32_16x16x32_bf16(
                        bf[ns], af[ms], acc[ms][ns], 0, 0, 0);
        }
    }
    #pragma unroll
    for (int ms = 0; ms < 4; ms++) {
        int m = m0 + wr + ms * 16 + l15;
        #pragma unroll
        for (int ns = 0; ns < 4; ns++) {
            int nb = wc + ns * 16 + qd * 4;
            float v[4];
            #pragma unroll
            for (int r = 0; r < 4; r++) v[r] = acc[ms][ns][r];
            if (R) {
                short4 r4 = *(const short4*)&R[(size_t)m * ldr + n0c + nb];
                v[0] += bf2f(r4.x); v[1] += bf2f(r4.y);
                v[2] += bf2f(r4.z); v[3] += bf2f(r4.w);
            }
            if (GELU_EPI) {
                #pragma unroll
                for (int r = 0; r < 4; r++)
                    v[r] = v[r] * 0.5f * (1.0f + erff(v[r] * 0.70710678118654752f));
            }
            short4 o;
            o.x = f2bf(v[0]); o.y = f2bf(v[1]); o.z = f2bf(v[2]); o.w = f2bf(v[3]);
            *(short4*)&C[(size_t)m * ldc + n0c + nb] = o;
        }
    }
}

// ---------------------------------------------------------------------------
// MFMA bf16 fused attention, one WG per (h, b).  512 threads = 8 waves.
// Fixed-max softmax (scores O(0.01)).  S stored DIAGONALLY (SD[tau][keyLocal],
// stride 66 -> conflict-free mv reduction).  Denominator via ones-column in vT.
// NOTE (R4 lesson): ballot-bitmask + ternary pfrag variants inflate FETCH
// 28->88..126 MB (3 independent A/Bs) -- keep the masks[] LDS float path.
// R6: vT kv-axis XOR-swizzled at 16B blocks (fixed the 16-way transpose-write
// bank conflict; verified -6.4 us).
__global__ __launch_bounds__(512, 4) void attn_kernel(short* q,
        const short* __restrict__ kb, const short* __restrict__ vf,
        const int* __restrict__ paths, float* __restrict__ mv2) {
    int h = blockIdx.x, b = blockIdx.y;
    __shared__ short SB[256 * 72];   // phase0: q staging (stride 72); loop: SD (stride 66)
    __shared__ short ks[64 * 72];
    __shared__ short vT[80 * 72];
    __shared__ float masks[256];
    __shared__ float mvpart[512];
    int tid = threadIdx.x;
    int lane = tid & 63, wave = tid >> 6;
    int l15 = lane & 15, qd = lane >> 4;
    if (tid < 256) masks[tid] = (paths[b * 256 + tid] < NUM_TOTALn) ? 0.0f : -10000.0f;
    {
        int e0 = tid * 2;
        #pragma unroll
        for (int i = 0; i < 2; i++) {
            int e = e0 + i;
            int row = 64 + (e >> 6), col = e & 63;
            vT[row * 72 + col] = (row == 64) ? (short)0x3F80 : (short)0;
        }
    }
    short* qg = q + ((size_t)b << 15) + (size_t)h * 64;
    const short* kg = kb + ((size_t)b << 15) + (size_t)h * 64;
    const short* vg = vf + ((size_t)b << 15) + (size_t)h * 64;

    #pragma unroll
    for (int p = 0; p < 4; p++) {
        int chunk = p * 512 + tid;
        int r = chunk >> 3, cb = (chunk & 7) * 8;
        *(frag_ab*)&SB[r * 72 + cb] = *(const frag_ab*)(qg + (size_t)r * 128 + cb);
    }
    __syncthreads();
    int myrow = wave * 32;
    frag_ab aq[2][2];
    #pragma unroll
    for (int mt = 0; mt < 2; mt++)
        #pragma unroll
        for (int hf = 0; hf < 2; hf++)
            aq[mt][hf] = *(frag_ab*)&SB[(myrow + mt * 16 + l15) * 72 + hf * 32 + qd * 8];

    frag_cd zero4 = {0.f, 0.f, 0.f, 0.f};
    frag_cd oacc[2][5];
    #pragma unroll
    for (int mt = 0; mt < 2; mt++)
        #pragma unroll
        for (int et = 0; et < 5; et++) oacc[mt][et] = zero4;
    float macc = 0.0f;
    int tau = tid & 255, half = tid >> 8;

    for (int jt = 0; jt < 4; jt++) {
        __syncthreads();
        {
            int r = tid >> 3, cb = (tid & 7) * 8;
            *(frag_ab*)&ks[r * 72 + cb] =
                *(const frag_ab*)(kg + (size_t)(jt * 64 + r) * 128 + cb);
            frag_ab v8 = *(const frag_ab*)(vg + (size_t)(jt * 64 + r) * 128 + cb);
            // vT swizzled write: e = cb+i, phys block = (r>>3) ^ ((e>>3)&7);
            // e>>3 == cb>>3 (cb multiple of 8, i<8) -> per-thread constant.
            int swz = (((r >> 3) ^ (cb >> 3)) << 3) + (r & 7);
            #pragma unroll
            for (int i = 0; i < 8; i++) vT[(cb + i) * 72 + swz] = v8[i];
        }
        __syncthreads();
        #pragma unroll
        for (int mt = 0; mt < 2; mt++) {
            #pragma unroll
            for (int nt = 0; nt < 4; nt++) {
                frag_ab b0 = *(frag_ab*)&ks[(nt * 16 + l15) * 72 + qd * 8];
                frag_ab b1 = *(frag_ab*)&ks[(nt * 16 + l15) * 72 + 32 + qd * 8];
                frag_cd c = zero4;
                c = __builtin_amdgcn_mfma_f32_16x16x32_bf16(aq[mt][0], b0, c, 0, 0, 0);
                c = __builtin_amdgcn_mfma_f32_16x16x32_bf16(aq[mt][1], b1, c, 0, 0, 0);
                int keyLocal = nt * 16 + l15;
                #pragma unroll
                for (int r = 0; r < 4; r++) {
                    int row = myrow + mt * 16 + qd * 4 + r;
                    int tt = (row - jt * 64 - keyLocal) & 255;
                    SB[tt * 66 + keyLocal] = f2bf(c[r] * 0.125f);
                }
            }
        }
        __syncthreads();
        {
            const int* SD32 = (const int*)&SB[tau * 66 + half * 32];
            #pragma unroll
            for (int i = 0; i < 16; i++) {
                int pk = SD32[i];
                macc += bf2f((short)(pk & 0xFFFF)) + bf2f((short)(pk >> 16));
            }
        }
        #pragma unroll
        for (int mt = 0; mt < 2; mt++) {
            int row = myrow + mt * 16 + l15;
            #pragma unroll
            for (int hf = 0; hf < 2; hf++) {
                int kl0 = hf * 32 + qd * 8;
                frag_ab pfrag;
                #pragma unroll
                for (int j = 0; j < 8; j++) {
                    int kl = kl0 + j;
                    int tt = (row - jt * 64 - kl) & 255;
                    float s = bf2f(SB[tt * 66 + kl]);
                    pfrag[j] = f2bf(__expf(s + masks[jt * 64 + kl]));
                }
                #pragma unroll
                for (int et = 0; et < 5; et++) {
                    // swizzled bv read: e = et*16+l15; phys blk = (hf*4+qd) ^ ((e>>3)&7)
                    int e = et * 16 + l15;
                    int blk = (hf * 4 + qd) ^ ((e >> 3) & 7);
                    frag_ab bv = *(frag_ab*)&vT[e * 72 + (blk << 3)];
                    oacc[mt][et] = __builtin_amdgcn_mfma_f32_16x16x32_bf16(pfrag, bv, oacc[mt][et], 0, 0, 0);
                }
            }
        }
    }
    __syncthreads();
    mvpart[tid] = macc;
    __syncthreads();
    if (tid < 256)
        mv2[(size_t)h * 65536 + b * 256 + tid] =
            (mvpart[tid] + mvpart[tid + 256]) * 0.0625f;
    #pragma unroll
    for (int mt = 0; mt < 2; mt++) {
        #pragma unroll
        for (int r = 0; r < 4; r++) {
            float l = oacc[mt][4][r];
            l = __shfl(l, (lane & 48));
            float inv = 1.0f / l;
            int row = myrow + mt * 16 + qd * 4 + r;
            #pragma unroll
            for (int et = 0; et < 4; et++)
                qg[(size_t)row * 128 + et * 16 + l15] = f2bf(oacc[mt][et][r] * inv);
        }
    }
}

// ---------------------------------------------------------------------------
__global__ __launch_bounds__(256) void gm_reduce_kernel(const float* __restrict__ mv2,
                                                        float* __restrict__ gm) {
    int tau = blockIdx.x;
    int b = threadIdx.x;
    __shared__ float red[256];
    red[b] = mv2[b * 256 + tau] + mv2[65536 + b * 256 + tau];
    __syncthreads();
    for (int s = 128; s > 0; s >>= 1) { if (b < s) red[b] += red[b + s]; __syncthreads(); }
    if (b == 0) gm[tau] = red[0] * (1.0f / 256.0f);
}

// Single block.  5 rounds of wave-shuffle argmax (tie -> smaller index) over
// 256 values (4 waves), then per-b softmax over the selected weights.
__global__ __launch_bounds__(256) void topk_softmax_kernel(const float* __restrict__ gm,
                                                           const float* __restrict__ mv2,
                                                           int* __restrict__ delays,
                                                           float* __restrict__ tc) {
    __shared__ float vsh[4];
    __shared__ int ish[4];
    __shared__ int dsh[TOPKn];
    int tid = threadIdx.x;
    int lane = tid & 63, wave = tid >> 6;
    float v = gm[tid];
    for (int t = 0; t < TOPKn; t++) {
        float mv_ = v; int mi = tid;
        #pragma unroll
        for (int s = 32; s > 0; s >>= 1) {
            float v2 = __shfl_xor(mv_, s); int i2 = __shfl_xor(mi, s);
            if (v2 > mv_ || (v2 == mv_ && i2 < mi)) { mv_ = v2; mi = i2; }
        }
        if (lane == 0) { vsh[wave] = mv_; ish[wave] = mi; }
        __syncthreads();
        if (tid == 0) {
            float bv = vsh[0]; int bi = ish[0];
            #pragma unroll
            for (int w = 1; w < 4; w++)
                if (vsh[w] > bv || (vsh[w] == bv && ish[w] < bi)) { bv = vsh[w]; bi = ish[w]; }
            dsh[t] = bi; delays[t] = bi;
        }
        __syncthreads();
        if (tid == dsh[t]) v = -1e30f;
    }
    __syncthreads();
    int b = tid;
    float w[TOPKn];
    float m = -1e30f;
    #pragma unroll
    for (int j = 0; j < TOPKn; j++) {
        w[j] = mv2[b * 256 + dsh[j]] + mv2[65536 + b * 256 + dsh[j]];
        m = fmaxf(m, w[j]);
    }
    float ssum = 0.0f;
    #pragma unroll
    for (int j = 0; j < TOPKn; j++) { w[j] = expf(w[j] - m); ssum += w[j]; }
    #pragma unroll
    for (int j = 0; j < TOPKn; j++) tc[b * TOPKn + j] = w[j] / ssum;
}

__global__ __launch_bounds__(256) void gather_out_kernel(const short* __restrict__ x,
                                                         const int* __restrict__ lengths,
                                                         float* __restrict__ out) {
    int idx = blockIdx.x * 256 + threadIdx.x;
    int d = idx & 127;
    int b = idx >> 7;
    out[idx] = bf2f(x[((size_t)b << 15) + (size_t)(lengths[b] - 1) * Dn + d]);
}

// ---------------------------------------------------------------------------
extern "C" void kernel_launch(void* const* d_in, const int* in_sizes, int n_in,
                              void* d_out, int out_size, void* d_ws, size_t ws_size,
                              hipStream_t stream) {
    const int* paths    = (const int*)d_in[0];
    const int* lengths  = (const int*)d_in[1];
    const float* ego    = (const float*)d_in[4];
    const float* pos    = (const float*)d_in[5];
    const float* Wq     = (const float*)d_in[6];
    const float* Wk     = (const float*)d_in[7];
    const float* Wv     = (const float*)d_in[8];
    const float* Wp     = (const float*)d_in[9];
    const float* F1     = (const float*)d_in[10];
    const float* F2     = (const float*)d_in[11];
    float* out = (float*)d_out;

    const size_t need = (size_t)5 * BLD * 2 + 131072 * 2 + 131072 * 4
                        + 256 * 4 + 1280 * 4 + 16 * 4 + (size_t)NLn * WT_LAYER * 2;
    if (ws_size < need) {
        beacon_kernel<<<dim3(1), dim3(1), 0, stream>>>(out, (float)(ws_size >> 20));
        return;
    }

    short* x    = (short*)d_ws;
    short* q    = x + (size_t)1 * BLD;   // q~ -> spat
    short* kb   = x + (size_t)2 * BLD;   // k~ -> a
    short* vf   = x + (size_t)3 * BLD;   // v~ -> h (spans vf+x5)
    short* x5   = x + (size_t)4 * BLD;   // h(hi)
    short* Gb   = x + (size_t)5 * BLD;
    float* mv   = (float*)(Gb + 131072);   // mv2: [2][256][256]
    float* gm   = mv + 131072;
    float* tc   = gm + 256;
    int* delays = (int*)(tc + 1280);
    short* Wt   = (short*)(delays + 16);

    build_G_kernel<<<dim3(2, 256), dim3(256), 0, stream>>>(Gb);
    build_x_kernel<<<dim3(BLD / 1024), dim3(256), 0, stream>>>(paths, ego, pos, x);

    // Wt per layer: [0]=Wq^T | [16384]=Wk^T | [32768]=Wv^T | [49152]=0.1*Wp^T
    //               [65536]=F1^T | [98304]=F2^T | [131072]=W2^T=0.9*(Wv@Wp)^T
    wtrans_all_kernel<<<dim3(512, NLn), dim3(256), 0, stream>>>(Wq, Wk, Wv, Wp, F1, F2, Wt);
    // W2T = 9*(0.1Wp^T)@(Wv^T slow-path) for both layers in one batched launch
    mgemm(stream, Wt + 49152, Wt + 32768, Wt + 131072, nullptr,
          128, 128, 128, 128, 128, 128, 0,
          WT_LAYER, WT_LAYER, WT_LAYER, 0, NLn,
          9.0f, 0.0f, false, false);

    for (int k = 0; k < NLn; k++) {
        const short* WtL = Wt + (size_t)k * WT_LAYER;
        // fused: xf = G_k @ x[b] (LDS) -> {q,k,v} projections, one WG per b
        filtproj_kernel<<<dim3(256), dim3(512), 0, stream>>>(
            Gb + (size_t)k * 65536, x, WtL, q);

        attn_kernel<<<dim3(2, 256), dim3(512), 0, stream>>>(q, kb, vf, paths, mv);

        gm_reduce_kernel<<<dim3(256), dim3(256), 0, stream>>>(mv, gm);
        topk_softmax_kernel<<<dim3(1), dim3(256), 0, stream>>>(gm, mv, delays, tc);

        // a = mix(x)@W2' + spat@(0.1Wp') + x  -> kb   (mix fused into A-stage)
        bgemm_kernel<true, false, true><<<dim3(256, 1), dim3(512), 0, stream>>>(
            x, WtL + 131072, 128, q, WtL + 49152, 128, kb, x, 128, 128, 0,
            tc, delays);
        // h = gelu(a @ F1) -> vf..x5 span (65536 x 256)
        bgemm_kernel<false, true, false><<<dim3(256, 2), dim3(512), 0, stream>>>(
            kb, WtL + 65536, 128, nullptr, nullptr, 0, vf, nullptr, 256, 0, 0,
            nullptr, nullptr);
        // x = h @ F2  (K=256)
        bgemm_kernel<false, false, false><<<dim3(256, 1), dim3(512), 0, stream>>>(
            vf, WtL + 98304, 256, nullptr, nullptr, 0, x, nullptr, 128, 0, 0,
            nullptr, nullptr);
    }

    gather_out_kernel<<<dim3((Bn * Dn) / 256), dim3(256), 0, stream>>>(x, lengths, out);
}

// Round 8
// 360.283 us; speedup vs baseline: 1.3574x; 1.0502x over previous
//
#include <hip/hip_runtime.h>
#include <math.h>

// Problem constants
#define Bn 256
#define Ln 256
#define Dn 128
#define Hn 2
#define En 64
#define NLn 2
#define TOPKn 5
#define NUM_TOTALn 100000
#define BLD (Bn*Ln*Dn)      // 8388608 elements per activation buffer (bf16)
#define WT_LAYER 147456     // bf16 elements of weights per layer (incl W2T)

using frag_ab = __attribute__((ext_vector_type(8))) short;   // 8 bf16
using frag_cd = __attribute__((ext_vector_type(4))) float;   // 4 f32

__device__ inline short f2bf(float f) {
    union { float f; unsigned u; } c; c.f = f;
    unsigned r = (c.u + 0x7FFFu + ((c.u >> 16) & 1u)) >> 16;   // RNE
    return (short)r;
}
__device__ inline float bf2f(short s) {
    union { unsigned u; float f; } c; c.u = ((unsigned)(unsigned short)s) << 16;
    return c.f;
}

// ---------------------------------------------------------------------------
__global__ void beacon_kernel(float* out, float v) { out[0] = v; }

// Circulant band-pass matrices G_k[t][s] = g_k[(t-s)&255], closed-form
// Dirichlet kernel.  k=0: f in [51,128] (incl Nyquist), k=1: f in [0,77]
// (incl DC).
__global__ __launch_bounds__(256) void build_G_kernel(short* __restrict__ G) {
    int k = blockIdx.x, t = blockIdx.y, s = threadIdx.x;
    int d = (t - s) & 255;
    int f1 = (k == 0) ? 51 : 1;
    int f2 = (k == 0) ? 127 : 77;
    float acc;
    if (d == 0) {
        acc = 2.0f * (float)(f2 - f1 + 1);
    } else {
        const float c = 3.14159265358979323846f / 256.0f;
        int ahi = (d * (2 * f2 + 1)) & 511;
        int alo = (d * (2 * f1 - 1)) & 511;
        acc = (sinf(c * (float)ahi) - sinf(c * (float)alo)) / sinf(c * (float)d);
    }
    acc += (k == 0) ? ((d & 1) ? -1.0f : 1.0f)   // Nyquist term cos(pi*d)
                    : 1.0f;                       // DC term
    G[((size_t)k * 256 + t) * 256 + s] = f2bf(acc * (1.0f / 256.0f));
}

// x[b,t,d] = ego[paths[b,t], d] + pos[t, d]  -> bf16
__global__ __launch_bounds__(256) void build_x_kernel(const int* __restrict__ paths,
                                                      const float* __restrict__ ego,
                                                      const float* __restrict__ pos,
                                                      short* __restrict__ x) {
    int base = (blockIdx.x * 256 + threadIdx.x) * 4;
    int d = base & 127;
    int bl = base >> 7;
    int t = bl & 255;
    float4 e = *(const float4*)(ego + (size_t)paths[bl] * Dn + d);
    float4 p = *(const float4*)(pos + t * Dn + d);
    short4 s;
    s.x = f2bf(e.x + p.x); s.y = f2bf(e.y + p.y);
    s.z = f2bf(e.z + p.z); s.w = f2bf(e.w + p.w);
    *(short4*)&x[base] = s;
}

// All 6 weight transposes in ONE kernel.  Per layer z, flat idx in [0,131072):
// [0,16384)=Wq  [16384,32768)=Wk  [32768,49152)=Wv  [49152,65536)=0.1*Wp
// [65536,98304)=F1 (K=128,N=256)  [98304,131072)=F2 (K=256,N=128)
// in f32 [z][K][N] -> out bf16 [z][N][K] * scale
__global__ __launch_bounds__(256) void wtrans_all_kernel(
        const float* __restrict__ Wq, const float* __restrict__ Wk,
        const float* __restrict__ Wv, const float* __restrict__ Wp,
        const float* __restrict__ F1, const float* __restrict__ F2,
        short* __restrict__ Wt) {
    int z = blockIdx.y;
    int idx = blockIdx.x * 256 + threadIdx.x;
    short* WtL = Wt + (size_t)z * WT_LAYER;
    if (idx < 65536) {
        int which = idx >> 14, local = idx & 16383;
        const float* src = (which == 0) ? Wq : (which == 1) ? Wk
                         : (which == 2) ? Wv : Wp;
        float scale = (which == 3) ? 0.1f : 1.0f;
        int n = local & 127, k = local >> 7;
        WtL[(which << 14) + n * 128 + k] = f2bf(scale * src[(size_t)z * 16384 + local]);
    } else if (idx < 98304) {
        int local = idx - 65536;                  // F1: [128][256]
        int n = local & 255, k = local >> 8;
        WtL[65536 + n * 128 + k] = f2bf(F1[(size_t)z * 32768 + local]);
    } else {
        int local = idx - 98304;                  // F2: [256][128]
        int n = local & 127, k = local >> 7;
        WtL[98304 + n * 256 + k] = f2bf(F2[(size_t)z * 32768 + local]);
    }
}

// ---------------------------------------------------------------------------
// General MFMA bf16 GEMM (W2T precompute only now).
// A bf16 [M][K].  BT_FAST: B bf16 [N][K]; else B bf16 [K][N] transpose-staged.
template<bool BT_FAST, bool GELU_EPI>
__global__ __launch_bounds__(256)
void mfma_gemm_kernel(const short* A, const short* Bp, short* C, const short* R,
                      int K, int lda, int ldb, int ldc, int ldr,
                      long long sA, long long sB, long long sC, long long sR,
                      long long sCsplit, float alpha, float beta) {
    int bz = blockIdx.z;
    A += (size_t)bz * sA; C += (size_t)bz * sC;
    if (R) R += (size_t)bz * sR;
    const short* Bt = Bp + (size_t)bz * sB;
    const int m0 = blockIdx.x * 128, n0 = blockIdx.y * 128;
    int n0c = n0;
    if (sCsplit) { C += (size_t)blockIdx.y * sCsplit; n0c = 0; }
    __shared__ short As[128 * 40];
    __shared__ short Bs[128 * 40];
    int tid = threadIdx.x;
    int lane = tid & 63, wave = tid >> 6;
    int wr = (wave >> 1) * 64, wc = (wave & 1) * 64;
    int l15 = lane & 15, qd = lane >> 4;

    frag_cd zero4 = {0.f, 0.f, 0.f, 0.f};
    frag_cd acc[4][4];
    #pragma unroll
    for (int i = 0; i < 4; i++)
        #pragma unroll
        for (int j = 0; j < 4; j++) acc[i][j] = zero4;

    int arow = tid >> 1, acg = (tid & 1) * 16;
    int bnrow = tid >> 1, bcg = (tid & 1) * 16;
    int bkk = tid & 31, bnb = (tid >> 5) * 16;

    int4 pa0, pa1, pb0, pb1;
    {
        const short* ap = A + (size_t)(m0 + arow) * lda + acg;
        pa0 = *(const int4*)ap; pa1 = *(const int4*)(ap + 8);
        if (BT_FAST) {
            const short* bp = Bt + (size_t)(n0 + bnrow) * ldb + bcg;
            pb0 = *(const int4*)bp; pb1 = *(const int4*)(bp + 8);
        } else {
            const short* bp = Bt + (size_t)bkk * ldb + n0 + bnb;
            pb0 = *(const int4*)bp; pb1 = *(const int4*)(bp + 8);
        }
    }

    for (int k0 = 0; k0 < K; k0 += 32) {
        __syncthreads();
        *(int4*)&As[arow * 40 + acg] = pa0;
        *(int4*)&As[arow * 40 + acg + 8] = pa1;
        if (BT_FAST) {
            *(int4*)&Bs[bnrow * 40 + bcg] = pb0;
            *(int4*)&Bs[bnrow * 40 + bcg + 8] = pb1;
        } else {
            short tmp[16];
            *(int4*)&tmp[0] = pb0; *(int4*)&tmp[8] = pb1;
            #pragma unroll
            for (int i = 0; i < 16; i++) Bs[(bnb + i) * 40 + bkk] = tmp[i];
        }
        __syncthreads();
        if (k0 + 32 < K) {
            const short* ap = A + (size_t)(m0 + arow) * lda + k0 + 32 + acg;
            pa0 = *(const int4*)ap; pa1 = *(const int4*)(ap + 8);
            if (BT_FAST) {
                const short* bp = Bt + (size_t)(n0 + bnrow) * ldb + k0 + 32 + bcg;
                pb0 = *(const int4*)bp; pb1 = *(const int4*)(bp + 8);
            } else {
                const short* bp = Bt + (size_t)(k0 + 32 + bkk) * ldb + n0 + bnb;
                pb0 = *(const int4*)bp; pb1 = *(const int4*)(bp + 8);
            }
        }
        frag_ab af[4], bf[4];
        #pragma unroll
        for (int ms = 0; ms < 4; ms++)
            af[ms] = *(frag_ab*)&As[(wr + ms * 16 + l15) * 40 + qd * 8];
        #pragma unroll
        for (int ns = 0; ns < 4; ns++)
            bf[ns] = *(frag_ab*)&Bs[(wc + ns * 16 + l15) * 40 + qd * 8];
        #pragma unroll
        for (int ms = 0; ms < 4; ms++)
            #pragma unroll
            for (int ns = 0; ns < 4; ns++)
                acc[ms][ns] = __builtin_amdgcn_mfma_f32_16x16x32_bf16(
                    bf[ns], af[ms], acc[ms][ns], 0, 0, 0);
    }
    #pragma unroll
    for (int ms = 0; ms < 4; ms++) {
        int m = m0 + wr + ms * 16 + l15;
        #pragma unroll
        for (int ns = 0; ns < 4; ns++) {
            int nb = wc + ns * 16 + qd * 4;
            float v[4];
            #pragma unroll
            for (int r = 0; r < 4; r++) v[r] = alpha * acc[ms][ns][r];
            if (R) {
                short4 r4 = *(const short4*)&R[(size_t)m * ldr + n0 + nb];
                v[0] += beta * bf2f(r4.x); v[1] += beta * bf2f(r4.y);
                v[2] += beta * bf2f(r4.z); v[3] += beta * bf2f(r4.w);
            }
            if (GELU_EPI) {
                #pragma unroll
                for (int r = 0; r < 4; r++)
                    v[r] = v[r] * 0.5f * (1.0f + erff(v[r] * 0.70710678118654752f));
            }
            short4 o;
            o.x = f2bf(v[0]); o.y = f2bf(v[1]); o.z = f2bf(v[2]); o.w = f2bf(v[3]);
            *(short4*)&C[(size_t)m * ldc + n0c + nb] = o;
        }
    }
}

static inline void mgemm(hipStream_t s, const short* A, const short* B, short* C,
                         const short* R, int M, int N, int K,
                         int lda, int ldb, int ldc, int ldr,
                         long long sA, long long sB, long long sC, long long sR,
                         int batch, float alpha, float beta, bool btFast, bool gelu,
                         long long sCsplit = 0) {
    dim3 grid(M / 128, N / 128, batch), block(256);
    if (btFast) {
        if (gelu) mfma_gemm_kernel<true, true ><<<grid, block, 0, s>>>(A, B, C, R, K, lda, ldb, ldc, ldr, sA, sB, sC, sR, sCsplit, alpha, beta);
        else      mfma_gemm_kernel<true, false><<<grid, block, 0, s>>>(A, B, C, R, K, lda, ldb, ldc, ldr, sA, sB, sC, sR, sCsplit, alpha, beta);
    } else {
        if (gelu) mfma_gemm_kernel<false, true ><<<grid, block, 0, s>>>(A, B, C, R, K, lda, ldb, ldc, ldr, sA, sB, sC, sR, sCsplit, alpha, beta);
        else      mfma_gemm_kernel<false, false><<<grid, block, 0, s>>>(A, B, C, R, K, lda, ldb, ldc, ldr, sA, sB, sC, sR, sCsplit, alpha, beta);
    }
}

// ---------------------------------------------------------------------------
// Fused band-filter + QKV projections.  One WG per batch b (grid 256, 1/CU),
// 512 threads = 8 waves (4x2).  (R7 win: -14 us, x5 round-trip eliminated.)
__global__ __launch_bounds__(512)
void filtproj_kernel(const short* __restrict__ G, const short* __restrict__ x,
                     const short* __restrict__ W, short* __restrict__ q) {
    int b = blockIdx.x;
    __shared__ short As[256 * 40];
    __shared__ short Bs[128 * 40];
    __shared__ short xf[256 * 136];
    int tid = threadIdx.x;
    int lane = tid & 63, wave = tid >> 6;
    int wr = (wave & 3) * 64, wc = (wave >> 2) * 64;
    int l15 = lane & 15, qd = lane >> 4;
    const short* xb = x + ((size_t)b << 15);

    frag_cd zero4 = {0.f, 0.f, 0.f, 0.f};
    frag_cd acc[4][4];
    #pragma unroll
    for (int i = 0; i < 4; i++)
        #pragma unroll
        for (int j = 0; j < 4; j++) acc[i][j] = zero4;

    int arow = tid >> 1, acg = (tid & 1) * 16;   // A: 32B/thread (256x32 tile)
    int bkk = tid & 31, bnb = (tid >> 5) * 16;   // B slow-path (tid<256 only)

    // ---- phase 1: xf = G @ x[b] ----
    int4 pa0, pa1, pb0, pb1;
    {
        const short* ap = G + (size_t)arow * 256 + acg;
        pa0 = *(const int4*)ap; pa1 = *(const int4*)(ap + 8);
        if (tid < 256) {
            const short* bp = xb + (size_t)bkk * 128 + bnb;
            pb0 = *(const int4*)bp; pb1 = *(const int4*)(bp + 8);
        }
    }
    for (int k0 = 0; k0 < 256; k0 += 32) {
        __syncthreads();
        *(int4*)&As[arow * 40 + acg] = pa0;
        *(int4*)&As[arow * 40 + acg + 8] = pa1;
        if (tid < 256) {
            short tmp[16];
            *(int4*)&tmp[0] = pb0; *(int4*)&tmp[8] = pb1;
            #pragma unroll
            for (int i = 0; i < 16; i++) Bs[(bnb + i) * 40 + bkk] = tmp[i];
        }
        __syncthreads();
        if (k0 + 32 < 256) {
            const short* ap = G + (size_t)arow * 256 + k0 + 32 + acg;
            pa0 = *(const int4*)ap; pa1 = *(const int4*)(ap + 8);
            if (tid < 256) {
                const short* bp = xb + (size_t)(k0 + 32 + bkk) * 128 + bnb;
                pb0 = *(const int4*)bp; pb1 = *(const int4*)(bp + 8);
            }
        }
        frag_ab af[4], bf[4];
        #pragma unroll
        for (int ms = 0; ms < 4; ms++)
            af[ms] = *(frag_ab*)&As[(wr + ms * 16 + l15) * 40 + qd * 8];
        #pragma unroll
        for (int ns = 0; ns < 4; ns++)
            bf[ns] = *(frag_ab*)&Bs[(wc + ns * 16 + l15) * 40 + qd * 8];
        #pragma unroll
        for (int ms = 0; ms < 4; ms++)
            #pragma unroll
            for (int ns = 0; ns < 4; ns++)
                acc[ms][ns] = __builtin_amdgcn_mfma_f32_16x16x32_bf16(
                    bf[ns], af[ms], acc[ms][ns], 0, 0, 0);
    }
    // epilogue -> LDS xf (same f2bf rounding as the old global store)
    #pragma unroll
    for (int ms = 0; ms < 4; ms++) {
        int m = wr + ms * 16 + l15;
        #pragma unroll
        for (int ns = 0; ns < 4; ns++) {
            int nb = wc + ns * 16 + qd * 4;
            short4 o;
            o.x = f2bf(acc[ms][ns][0]); o.y = f2bf(acc[ms][ns][1]);
            o.z = f2bf(acc[ms][ns][2]); o.w = f2bf(acc[ms][ns][3]);
            *(short4*)&xf[m * 136 + nb] = o;
        }
    }

    // ---- phase 2: C_y[b] = xf @ Wy^T, y = 0..2 ----
    int brow = tid >> 2, bcg = (tid & 3) * 8;    // B: 16B/thread (128x32 tile)
    #pragma unroll 1
    for (int y = 0; y < 3; y++) {
        const short* Bt = W + y * 16384;
        #pragma unroll
        for (int i = 0; i < 4; i++)
            #pragma unroll
            for (int j = 0; j < 4; j++) acc[i][j] = zero4;
        int4 pb = *(const int4*)(Bt + (size_t)brow * 128 + bcg);
        for (int k0 = 0; k0 < 128; k0 += 32) {
            __syncthreads();
            *(int4*)&Bs[brow * 40 + bcg] = pb;
            __syncthreads();
            if (k0 + 32 < 128)
                pb = *(const int4*)(Bt + (size_t)brow * 128 + k0 + 32 + bcg);
            frag_ab af[4], bf[4];
            #pragma unroll
            for (int ms = 0; ms < 4; ms++)
                af[ms] = *(frag_ab*)&xf[(wr + ms * 16 + l15) * 136 + k0 + qd * 8];
            #pragma unroll
            for (int ns = 0; ns < 4; ns++)
                bf[ns] = *(frag_ab*)&Bs[(wc + ns * 16 + l15) * 40 + qd * 8];
            #pragma unroll
            for (int ms = 0; ms < 4; ms++)
                #pragma unroll
                for (int ns = 0; ns < 4; ns++)
                    acc[ms][ns] = __builtin_amdgcn_mfma_f32_16x16x32_bf16(
                        bf[ns], af[ms], acc[ms][ns], 0, 0, 0);
        }
        short* Cy = q + (size_t)y * BLD + ((size_t)b << 15);
        #pragma unroll
        for (int ms = 0; ms < 4; ms++) {
            int m = wr + ms * 16 + l15;
            #pragma unroll
            for (int ns = 0; ns < 4; ns++) {
                int nb = wc + ns * 16 + qd * 4;
                short4 o;
                o.x = f2bf(acc[ms][ns][0]); o.y = f2bf(acc[ms][ns][1]);
                o.z = f2bf(acc[ms][ns][2]); o.w = f2bf(acc[ms][ns][3]);
                *(short4*)&Cy[(size_t)m * 128 + nb] = o;
            }
        }
    }
}

// ---------------------------------------------------------------------------
// Fused FFN: x[b] = gelu(a[b] @ F1) @ F2, one WG per batch b (grid 256),
// 512 threads = 8 waves (4x2).  a[b] staged to LDS once (coalesced); h kept
// entirely in LDS (stride 132: 66 dw == 2 mod 32 -> conflict-free b128 reads).
// K=256 of the F2 GEMM split into two 128 halves, each computed right after
// its gelu(h) half -- identical accumulation order to the old two-kernel
// path (h f2bf-rounded to bf16 exactly as the old global store), so numerics
// are unchanged.  Saves the 33 MB/layer h round-trip + 1 launch.
__global__ __launch_bounds__(512)
void ffn_kernel(const short* __restrict__ a, const short* __restrict__ W,
                short* __restrict__ x) {
    int b = blockIdx.x;
    __shared__ short aL[256 * 132];   // a[b] (67.6 KB)
    __shared__ short hA[256 * 132];   // gelu half (67.6 KB)
    __shared__ short Bs[128 * 36];    // weight tile (9 KB); total 141 KB LDS
    int tid = threadIdx.x;
    int lane = tid & 63, wave = tid >> 6;
    int wr = (wave & 3) * 64, wc = (wave >> 2) * 64;
    int l15 = lane & 15, qd = lane >> 4;
    const short* ab = a + ((size_t)b << 15);
    const short* F1T = W + 65536;     // [256][128]
    const short* F2T = W + 98304;     // [128][256]

    // stage a[b] -> aL (coalesced 16B per thread, 8 rounds)
    #pragma unroll
    for (int p = 0; p < 8; p++) {
        int chunk = p * 512 + tid;
        int r = chunk >> 4, cb = (chunk & 15) * 8;
        *(frag_ab*)&aL[r * 132 + cb] = *(const frag_ab*)(ab + (size_t)r * 128 + cb);
    }

    frag_cd zero4 = {0.f, 0.f, 0.f, 0.f};
    frag_cd xacc[4][4];
    #pragma unroll
    for (int i = 0; i < 4; i++)
        #pragma unroll
        for (int j = 0; j < 4; j++) xacc[i][j] = zero4;

    int brow = tid >> 2, bcg = (tid & 3) * 8;    // B: 16B/thread (128x32 tile)

    #pragma unroll 1
    for (int half = 0; half < 2; half++) {
        // ---- phase 1: hA = gelu(a[b] @ F1T[half*128 .. +128]) ----
        const short* B1 = F1T + (size_t)(half * 128) * 128;
        frag_cd acc[4][4];
        #pragma unroll
        for (int i = 0; i < 4; i++)
            #pragma unroll
            for (int j = 0; j < 4; j++) acc[i][j] = zero4;
        int4 pb = *(const int4*)(B1 + (size_t)brow * 128 + bcg);
        for (int k0 = 0; k0 < 128; k0 += 32) {
            __syncthreads();
            *(int4*)&Bs[brow * 36 + bcg] = pb;
            __syncthreads();
            if (k0 + 32 < 128)
                pb = *(const int4*)(B1 + (size_t)brow * 128 + k0 + 32 + bcg);
            frag_ab af[4], bf[4];
            #pragma unroll
            for (int ms = 0; ms < 4; ms++)
                af[ms] = *(frag_ab*)&aL[(wr + ms * 16 + l15) * 132 + k0 + qd * 8];
            #pragma unroll
            for (int ns = 0; ns < 4; ns++)
                bf[ns] = *(frag_ab*)&Bs[(wc + ns * 16 + l15) * 36 + qd * 8];
            #pragma unroll
            for (int ms = 0; ms < 4; ms++)
                #pragma unroll
                for (int ns = 0; ns < 4; ns++)
                    acc[ms][ns] = __builtin_amdgcn_mfma_f32_16x16x32_bf16(
                        bf[ns], af[ms], acc[ms][ns], 0, 0, 0);
        }
        __syncthreads();   // all reads of hA from previous half complete
        #pragma unroll
        for (int ms = 0; ms < 4; ms++) {
            int m = wr + ms * 16 + l15;
            #pragma unroll
            for (int ns = 0; ns < 4; ns++) {
                int nb = wc + ns * 16 + qd * 4;
                float v[4];
                #pragma unroll
                for (int r = 0; r < 4; r++) {
                    float t = acc[ms][ns][r];
                    v[r] = t * 0.5f * (1.0f + erff(t * 0.70710678118654752f));
                }
                short4 o;
                o.x = f2bf(v[0]); o.y = f2bf(v[1]);
                o.z = f2bf(v[2]); o.w = f2bf(v[3]);
                *(short4*)&hA[m * 132 + nb] = o;
            }
        }
        __syncthreads();   // hA visible to all waves

        // ---- phase 2: xacc += hA @ F2T[:, half*128 .. +128] ----
        int4 pb2 = *(const int4*)(F2T + (size_t)brow * 256 + half * 128 + bcg);
        for (int k0 = 0; k0 < 128; k0 += 32) {
            __syncthreads();
            *(int4*)&Bs[brow * 36 + bcg] = pb2;
            __syncthreads();
            if (k0 + 32 < 128)
                pb2 = *(const int4*)(F2T + (size_t)brow * 256 + half * 128 + k0 + 32 + bcg);
            frag_ab af[4], bf[4];
            #pragma unroll
            for (int ms = 0; ms < 4; ms++)
                af[ms] = *(frag_ab*)&hA[(wr + ms * 16 + l15) * 132 + k0 + qd * 8];
            #pragma unroll
            for (int ns = 0; ns < 4; ns++)
                bf[ns] = *(frag_ab*)&Bs[(wc + ns * 16 + l15) * 36 + qd * 8];
            #pragma unroll
            for (int ms = 0; ms < 4; ms++)
                #pragma unroll
                for (int ns = 0; ns < 4; ns++)
                    xacc[ms][ns] = __builtin_amdgcn_mfma_f32_16x16x32_bf16(
                        bf[ns], af[ms], xacc[ms][ns], 0, 0, 0);
        }
    }
    // epilogue: xacc -> x[b]
    short* xb = x + ((size_t)b << 15);
    #pragma unroll
    for (int ms = 0; ms < 4; ms++) {
        int m = wr + ms * 16 + l15;
        #pragma unroll
        for (int ns = 0; ns < 4; ns++) {
            int nb = wc + ns * 16 + qd * 4;
            short4 o;
            o.x = f2bf(xacc[ms][ns][0]); o.y = f2bf(xacc[ms][ns][1]);
            o.z = f2bf(xacc[ms][ns][2]); o.w = f2bf(xacc[ms][ns][3]);
            *(short4*)&xb[(size_t)m * 128 + nb] = o;
        }
    }
}

// ---------------------------------------------------------------------------
// Big-tile weight GEMM: BM=256, BN=128, BK=32.  512 threads = 8 waves (4x2).
// C = A1@B1 [+ A2@B2] + R.  B pre-transposed bf16 [N][K].
// MIXA: pass-0 A operand is the TOPK-delay weighted gather of A1 (= x base).
template<bool DUAL, bool GELU_EPI, bool MIXA>
__global__ __launch_bounds__(512)
void bgemm_kernel(const short* __restrict__ A1, const short* __restrict__ B1, int K1,
                  const short* __restrict__ A2, const short* __restrict__ B2, int K2,
                  short* C, const short* __restrict__ R, int ldc, int ldr,
                  long long sCsplit,
                  const float* __restrict__ tc, const int* __restrict__ delays) {
    const int m0 = blockIdx.x * 256;
    int n0c;
    if (sCsplit) { C += (size_t)blockIdx.y * sCsplit; n0c = 0; }
    else         { n0c = blockIdx.y * 128; }
    __shared__ short As[256 * 40];   // [m][k] pad 40
    __shared__ short Bs[128 * 40];   // [n][k] pad 40
    int tid = threadIdx.x;
    int lane = tid & 63, wave = tid >> 6;
    int wr = (wave & 3) * 64, wc = (wave >> 2) * 64;
    int l15 = lane & 15, qd = lane >> 4;

    float wj[TOPKn]; int dj[TOPKn];
    if (MIXA) {
        #pragma unroll
        for (int j = 0; j < TOPKn; j++) {
            wj[j] = tc[blockIdx.x * TOPKn + j];
            dj[j] = delays[j];
        }
    }

    frag_cd zero4 = {0.f, 0.f, 0.f, 0.f};
    frag_cd acc[4][4];
    #pragma unroll
    for (int i = 0; i < 4; i++)
        #pragma unroll
        for (int j = 0; j < 4; j++) acc[i][j] = zero4;

    int arow = tid >> 1, acg = (tid & 1) * 16;   // A: 32B/thread
    int brow = tid >> 2, bcg = (tid & 3) * 8;    // B: 16B/thread

    #pragma unroll
    for (int pass = 0; pass < (DUAL ? 2 : 1); pass++) {
        const short* A = pass ? A2 : A1;
        const short* Bb = (pass ? B2 : B1);
        int K = pass ? K2 : K1;
        const bool domix = MIXA && (pass == 0);
        const short* Bt = Bb + (size_t)blockIdx.y * 128 * K;
        const short* xb = A + ((size_t)m0 << 7);   // x[b] base (MIXA pass 0)
        int4 pa0, pa1, pb0;
        {
            if (!domix) {
                const short* ap = A + (size_t)(m0 + arow) * K + acg;
                pa0 = *(const int4*)ap; pa1 = *(const int4*)(ap + 8);
            }
            pb0 = *(const int4*)(Bt + (size_t)brow * K + bcg);
        }
        for (int k0 = 0; k0 < K; k0 += 32) {
            __syncthreads();
            if (domix) {
                #pragma unroll
                for (int c = 0; c < 2; c++) {
                    int col = k0 + acg + c * 8;
                    float m8[8] = {0.f, 0.f, 0.f, 0.f, 0.f, 0.f, 0.f, 0.f};
                    #pragma unroll
                    for (int j = 0; j < TOPKn; j++) {
                        frag_ab v = *(const frag_ab*)(xb + (((arow + dj[j]) & 255) << 7) + col);
                        #pragma unroll
                        for (int i = 0; i < 8; i++) m8[i] += wj[j] * bf2f(v[i]);
                    }
                    frag_ab o;
                    #pragma unroll
                    for (int i = 0; i < 8; i++) o[i] = f2bf(m8[i]);
                    *(frag_ab*)&As[arow * 40 + acg + c * 8] = o;
                }
            } else {
                *(int4*)&As[arow * 40 + acg] = pa0;
                *(int4*)&As[arow * 40 + acg + 8] = pa1;
            }
            *(int4*)&Bs[brow * 40 + bcg] = pb0;
            __syncthreads();
            if (k0 + 32 < K) {
                if (!domix) {
                    const short* ap = A + (size_t)(m0 + arow) * K + k0 + 32 + acg;
                    pa0 = *(const int4*)ap; pa1 = *(const int4*)(ap + 8);
                }
                pb0 = *(const int4*)(Bt + (size_t)brow * K + k0 + 32 + bcg);
            }
            frag_ab af[4], bf[4];
            #pragma unroll
            for (int ms = 0; ms < 4; ms++)
                af[ms] = *(frag_ab*)&As[(wr + ms * 16 + l15) * 40 + qd * 8];
            #pragma unroll
            for (int ns = 0; ns < 4; ns++)
                bf[ns] = *(frag_ab*)&Bs[(wc + ns * 16 + l15) * 40 + qd * 8];
            #pragma unroll
            for (int ms = 0; ms < 4; ms++)
                #pragma unroll
                for (int ns = 0; ns < 4; ns++)
                    acc[ms][ns] = __builtin_amdgcn_mfma_f32_16x16x32_bf16(
                        bf[ns], af[ms], acc[ms][ns], 0, 0, 0);
        }
    }
    #pragma unroll
    for (int ms = 0; ms < 4; ms++) {
        int m = m0 + wr + ms * 16 + l15;
        #pragma unroll
        for (int ns = 0; ns < 4; ns++) {
            int nb = wc + ns * 16 + qd * 4;
            float v[4];
            #pragma unroll
            for (int r = 0; r < 4; r++) v[r] = acc[ms][ns][r];
            if (R) {
                short4 r4 = *(const short4*)&R[(size_t)m * ldr + n0c + nb];
                v[0] += bf2f(r4.x); v[1] += bf2f(r4.y);
                v[2] += bf2f(r4.z); v[3] += bf2f(r4.w);
            }
            if (GELU_EPI) {
                #pragma unroll
                for (int r = 0; r < 4; r++)
                    v[r] = v[r] * 0.5f * (1.0f + erff(v[r] * 0.70710678118654752f));
            }
            short4 o;
            o.x = f2bf(v[0]); o.y = f2bf(v[1]); o.z = f2bf(v[2]); o.w = f2bf(v[3]);
            *(short4*)&C[(size_t)m * ldc + n0c + nb] = o;
        }
    }
}

// ---------------------------------------------------------------------------
// MFMA bf16 fused attention, one WG per (h, b).  512 threads = 8 waves.
// Fixed-max softmax (scores O(0.01)).  S stored DIAGONALLY (SD[tau][keyLocal],
// stride 66 -> conflict-free mv reduction).  Denominator via ones-column in vT.
// NOTE (R4 lesson): ballot-bitmask + ternary pfrag variants inflate FETCH
// 28->88..126 MB (3 independent A/Bs) -- keep the masks[] LDS float path.
// R6: vT kv-axis XOR-swizzled at 16B blocks (fixed the 16-way transpose-write
// bank conflict; verified -6.4 us).
__global__ __launch_bounds__(512, 4) void attn_kernel(short* q,
        const short* __restrict__ kb, const short* __restrict__ vf,
        const int* __restrict__ paths, float* __restrict__ mv2) {
    int h = blockIdx.x, b = blockIdx.y;
    __shared__ short SB[256 * 72];   // phase0: q staging (stride 72); loop: SD (stride 66)
    __shared__ short ks[64 * 72];
    __shared__ short vT[80 * 72];
    __shared__ float masks[256];
    __shared__ float mvpart[512];
    int tid = threadIdx.x;
    int lane = tid & 63, wave = tid >> 6;
    int l15 = lane & 15, qd = lane >> 4;
    if (tid < 256) masks[tid] = (paths[b * 256 + tid] < NUM_TOTALn) ? 0.0f : -10000.0f;
    {
        int e0 = tid * 2;
        #pragma unroll
        for (int i = 0; i < 2; i++) {
            int e = e0 + i;
            int row = 64 + (e >> 6), col = e & 63;
            vT[row * 72 + col] = (row == 64) ? (short)0x3F80 : (short)0;
        }
    }
    short* qg = q + ((size_t)b << 15) + (size_t)h * 64;
    const short* kg = kb + ((size_t)b << 15) + (size_t)h * 64;
    const short* vg = vf + ((size_t)b << 15) + (size_t)h * 64;

    #pragma unroll
    for (int p = 0; p < 4; p++) {
        int chunk = p * 512 + tid;
        int r = chunk >> 3, cb = (chunk & 7) * 8;
        *(frag_ab*)&SB[r * 72 + cb] = *(const frag_ab*)(qg + (size_t)r * 128 + cb);
    }
    __syncthreads();
    int myrow = wave * 32;
    frag_ab aq[2][2];
    #pragma unroll
    for (int mt = 0; mt < 2; mt++)
        #pragma unroll
        for (int hf = 0; hf < 2; hf++)
            aq[mt][hf] = *(frag_ab*)&SB[(myrow + mt * 16 + l15) * 72 + hf * 32 + qd * 8];

    frag_cd zero4 = {0.f, 0.f, 0.f, 0.f};
    frag_cd oacc[2][5];
    #pragma unroll
    for (int mt = 0; mt < 2; mt++)
        #pragma unroll
        for (int et = 0; et < 5; et++) oacc[mt][et] = zero4;
    float macc = 0.0f;
    int tau = tid & 255, half = tid >> 8;

    for (int jt = 0; jt < 4; jt++) {
        __syncthreads();
        {
            int r = tid >> 3, cb = (tid & 7) * 8;
            *(frag_ab*)&ks[r * 72 + cb] =
                *(const frag_ab*)(kg + (size_t)(jt * 64 + r) * 128 + cb);
            frag_ab v8 = *(const frag_ab*)(vg + (size_t)(jt * 64 + r) * 128 + cb);
            // vT swizzled write: e = cb+i, phys block = (r>>3) ^ ((e>>3)&7);
            // e>>3 == cb>>3 (cb multiple of 8, i<8) -> per-thread constant.
            int swz = (((r >> 3) ^ (cb >> 3)) << 3) + (r & 7);
            #pragma unroll
            for (int i = 0; i < 8; i++) vT[(cb + i) * 72 + swz] = v8[i];
        }
        __syncthreads();
        #pragma unroll
        for (int mt = 0; mt < 2; mt++) {
            #pragma unroll
            for (int nt = 0; nt < 4; nt++) {
                frag_ab b0 = *(frag_ab*)&ks[(nt * 16 + l15) * 72 + qd * 8];
                frag_ab b1 = *(frag_ab*)&ks[(nt * 16 + l15) * 72 + 32 + qd * 8];
                frag_cd c = zero4;
                c = __builtin_amdgcn_mfma_f32_16x16x32_bf16(aq[mt][0], b0, c, 0, 0, 0);
                c = __builtin_amdgcn_mfma_f32_16x16x32_bf16(aq[mt][1], b1, c, 0, 0, 0);
                int keyLocal = nt * 16 + l15;
                #pragma unroll
                for (int r = 0; r < 4; r++) {
                    int row = myrow + mt * 16 + qd * 4 + r;
                    int tt = (row - jt * 64 - keyLocal) & 255;
                    SB[tt * 66 + keyLocal] = f2bf(c[r] * 0.125f);
                }
            }
        }
        __syncthreads();
        {
            const int* SD32 = (const int*)&SB[tau * 66 + half * 32];
            #pragma unroll
            for (int i = 0; i < 16; i++) {
                int pk = SD32[i];
                macc += bf2f((short)(pk & 0xFFFF)) + bf2f((short)(pk >> 16));
            }
        }
        #pragma unroll
        for (int mt = 0; mt < 2; mt++) {
            int row = myrow + mt * 16 + l15;
            #pragma unroll
            for (int hf = 0; hf < 2; hf++) {
                int kl0 = hf * 32 + qd * 8;
                frag_ab pfrag;
                #pragma unroll
                for (int j = 0; j < 8; j++) {
                    int kl = kl0 + j;
                    int tt = (row - jt * 64 - kl) & 255;
                    float s = bf2f(SB[tt * 66 + kl]);
                    pfrag[j] = f2bf(__expf(s + masks[jt * 64 + kl]));
                }
                #pragma unroll
                for (int et = 0; et < 5; et++) {
                    // swizzled bv read: e = et*16+l15; phys blk = (hf*4+qd) ^ ((e>>3)&7)
                    int e = et * 16 + l15;
                    int blk = (hf * 4 + qd) ^ ((e >> 3) & 7);
                    frag_ab bv = *(frag_ab*)&vT[e * 72 + (blk << 3)];
                    oacc[mt][et] = __builtin_amdgcn_mfma_f32_16x16x32_bf16(pfrag, bv, oacc[mt][et], 0, 0, 0);
                }
            }
        }
    }
    __syncthreads();
    mvpart[tid] = macc;
    __syncthreads();
    if (tid < 256)
        mv2[(size_t)h * 65536 + b * 256 + tid] =
            (mvpart[tid] + mvpart[tid + 256]) * 0.0625f;
    #pragma unroll
    for (int mt = 0; mt < 2; mt++) {
        #pragma unroll
        for (int r = 0; r < 4; r++) {
            float l = oacc[mt][4][r];
            l = __shfl(l, (lane & 48));
            float inv = 1.0f / l;
            int row = myrow + mt * 16 + qd * 4 + r;
            #pragma unroll
            for (int et = 0; et < 4; et++)
                qg[(size_t)row * 128 + et * 16 + l15] = f2bf(oacc[mt][et][r] * inv);
        }
    }
}

// ---------------------------------------------------------------------------
__global__ __launch_bounds__(256) void gm_reduce_kernel(const float* __restrict__ mv2,
                                                        float* __restrict__ gm) {
    int tau = blockIdx.x;
    int b = threadIdx.x;
    __shared__ float red[256];
    red[b] = mv2[b * 256 + tau] + mv2[65536 + b * 256 + tau];
    __syncthreads();
    for (int s = 128; s > 0; s >>= 1) { if (b < s) red[b] += red[b + s]; __syncthreads(); }
    if (b == 0) gm[tau] = red[0] * (1.0f / 256.0f);
}

// Single block.  5 rounds of wave-shuffle argmax (tie -> smaller index) over
// 256 values (4 waves), then per-b softmax over the selected weights.
__global__ __launch_bounds__(256) void topk_softmax_kernel(const float* __restrict__ gm,
                                                           const float* __restrict__ mv2,
                                                           int* __restrict__ delays,
                                                           float* __restrict__ tc) {
    __shared__ float vsh[4];
    __shared__ int ish[4];
    __shared__ int dsh[TOPKn];
    int tid = threadIdx.x;
    int lane = tid & 63, wave = tid >> 6;
    float v = gm[tid];
    for (int t = 0; t < TOPKn; t++) {
        float mv_ = v; int mi = tid;
        #pragma unroll
        for (int s = 32; s > 0; s >>= 1) {
            float v2 = __shfl_xor(mv_, s); int i2 = __shfl_xor(mi, s);
            if (v2 > mv_ || (v2 == mv_ && i2 < mi)) { mv_ = v2; mi = i2; }
        }
        if (lane == 0) { vsh[wave] = mv_; ish[wave] = mi; }
        __syncthreads();
        if (tid == 0) {
            float bv = vsh[0]; int bi = ish[0];
            #pragma unroll
            for (int w = 1; w < 4; w++)
                if (vsh[w] > bv || (vsh[w] == bv && ish[w] < bi)) { bv = vsh[w]; bi = ish[w]; }
            dsh[t] = bi; delays[t] = bi;
        }
        __syncthreads();
        if (tid == dsh[t]) v = -1e30f;
    }
    __syncthreads();
    int b = tid;
    float w[TOPKn];
    float m = -1e30f;
    #pragma unroll
    for (int j = 0; j < TOPKn; j++) {
        w[j] = mv2[b * 256 + dsh[j]] + mv2[65536 + b * 256 + dsh[j]];
        m = fmaxf(m, w[j]);
    }
    float ssum = 0.0f;
    #pragma unroll
    for (int j = 0; j < TOPKn; j++) { w[j] = expf(w[j] - m); ssum += w[j]; }
    #pragma unroll
    for (int j = 0; j < TOPKn; j++) tc[b * TOPKn + j] = w[j] / ssum;
}

__global__ __launch_bounds__(256) void gather_out_kernel(const short* __restrict__ x,
                                                         const int* __restrict__ lengths,
                                                         float* __restrict__ out) {
    int idx = blockIdx.x * 256 + threadIdx.x;
    int d = idx & 127;
    int b = idx >> 7;
    out[idx] = bf2f(x[((size_t)b << 15) + (size_t)(lengths[b] - 1) * Dn + d]);
}

// ---------------------------------------------------------------------------
extern "C" void kernel_launch(void* const* d_in, const int* in_sizes, int n_in,
                              void* d_out, int out_size, void* d_ws, size_t ws_size,
                              hipStream_t stream) {
    const int* paths    = (const int*)d_in[0];
    const int* lengths  = (const int*)d_in[1];
    const float* ego    = (const float*)d_in[4];
    const float* pos    = (const float*)d_in[5];
    const float* Wq     = (const float*)d_in[6];
    const float* Wk     = (const float*)d_in[7];
    const float* Wv     = (const float*)d_in[8];
    const float* Wp     = (const float*)d_in[9];
    const float* F1     = (const float*)d_in[10];
    const float* F2     = (const float*)d_in[11];
    float* out = (float*)d_out;

    const size_t need = (size_t)5 * BLD * 2 + 131072 * 2 + 131072 * 4
                        + 256 * 4 + 1280 * 4 + 16 * 4 + (size_t)NLn * WT_LAYER * 2;
    if (ws_size < need) {
        beacon_kernel<<<dim3(1), dim3(1), 0, stream>>>(out, (float)(ws_size >> 20));
        return;
    }

    short* x    = (short*)d_ws;
    short* q    = x + (size_t)1 * BLD;   // q~ -> spat
    short* kb   = x + (size_t)2 * BLD;   // k~ -> a
    short* vf   = x + (size_t)3 * BLD;   // v~
    short* Gb   = x + (size_t)5 * BLD;
    float* mv   = (float*)(Gb + 131072);   // mv2: [2][256][256]
    float* gm   = mv + 131072;
    float* tc   = gm + 256;
    int* delays = (int*)(tc + 1280);
    short* Wt   = (short*)(delays + 16);

    build_G_kernel<<<dim3(2, 256), dim3(256), 0, stream>>>(Gb);
    build_x_kernel<<<dim3(BLD / 1024), dim3(256), 0, stream>>>(paths, ego, pos, x);

    // Wt per layer: [0]=Wq^T | [16384]=Wk^T | [32768]=Wv^T | [49152]=0.1*Wp^T
    //               [65536]=F1^T | [98304]=F2^T | [131072]=W2^T=0.9*(Wv@Wp)^T
    wtrans_all_kernel<<<dim3(512, NLn), dim3(256), 0, stream>>>(Wq, Wk, Wv, Wp, F1, F2, Wt);
    // W2T = 9*(0.1Wp^T)@(Wv^T slow-path) for both layers in one batched launch
    mgemm(stream, Wt + 49152, Wt + 32768, Wt + 131072, nullptr,
          128, 128, 128, 128, 128, 128, 0,
          WT_LAYER, WT_LAYER, WT_LAYER, 0, NLn,
          9.0f, 0.0f, false, false);

    for (int k = 0; k < NLn; k++) {
        const short* WtL = Wt + (size_t)k * WT_LAYER;
        // fused: xf = G_k @ x[b] (LDS) -> {q,k,v} projections, one WG per b
        filtproj_kernel<<<dim3(256), dim3(512), 0, stream>>>(
            Gb + (size_t)k * 65536, x, WtL, q);

        attn_kernel<<<dim3(2, 256), dim3(512), 0, stream>>>(q, kb, vf, paths, mv);

        gm_reduce_kernel<<<dim3(256), dim3(256), 0, stream>>>(mv, gm);
        topk_softmax_kernel<<<dim3(1), dim3(256), 0, stream>>>(gm, mv, delays, tc);

        // a = mix(x)@W2' + spat@(0.1Wp') + x  -> kb   (mix fused into A-stage)
        bgemm_kernel<true, false, true><<<dim3(256, 1), dim3(512), 0, stream>>>(
            x, WtL + 131072, 128, q, WtL + 49152, 128, kb, x, 128, 128, 0,
            tc, delays);
        // fused FFN: x = gelu(a @ F1) @ F2, one WG per b (h stays in LDS)
        ffn_kernel<<<dim3(256), dim3(512), 0, stream>>>(kb, WtL, x);
    }

    gather_out_kernel<<<dim3((Bn * Dn) / 256), dim3(256), 0, stream>>>(x, lengths, out);
}

// Round 9
// 345.977 us; speedup vs baseline: 1.4136x; 1.0414x over previous
//
#include <hip/hip_runtime.h>
#include <math.h>

// Problem constants
#define Bn 256
#define Ln 256
#define Dn 128
#define Hn 2
#define En 64
#define NLn 2
#define TOPKn 5
#define NUM_TOTALn 100000
#define BLD (Bn*Ln*Dn)      // 8388608 elements per activation buffer (bf16)
#define WT_LAYER 147456     // bf16 elements of weights per layer (incl W2T)

using frag_ab = __attribute__((ext_vector_type(8))) short;   // 8 bf16
using frag_cd = __attribute__((ext_vector_type(4))) float;   // 4 f32

__device__ inline short f2bf(float f) {
    union { float f; unsigned u; } c; c.f = f;
    unsigned r = (c.u + 0x7FFFu + ((c.u >> 16) & 1u)) >> 16;   // RNE
    return (short)r;
}
__device__ inline float bf2f(short s) {
    union { unsigned u; float f; } c; c.u = ((unsigned)(unsigned short)s) << 16;
    return c.f;
}

// ---------------------------------------------------------------------------
__global__ void beacon_kernel(float* out, float v) { out[0] = v; }

// Circulant band-pass matrices G_k[t][s] = g_k[(t-s)&255], closed-form
// Dirichlet kernel.  k=0: f in [51,128] (incl Nyquist), k=1: f in [0,77]
// (incl DC).
__global__ __launch_bounds__(256) void build_G_kernel(short* __restrict__ G) {
    int k = blockIdx.x, t = blockIdx.y, s = threadIdx.x;
    int d = (t - s) & 255;
    int f1 = (k == 0) ? 51 : 1;
    int f2 = (k == 0) ? 127 : 77;
    float acc;
    if (d == 0) {
        acc = 2.0f * (float)(f2 - f1 + 1);
    } else {
        const float c = 3.14159265358979323846f / 256.0f;
        int ahi = (d * (2 * f2 + 1)) & 511;
        int alo = (d * (2 * f1 - 1)) & 511;
        acc = (sinf(c * (float)ahi) - sinf(c * (float)alo)) / sinf(c * (float)d);
    }
    acc += (k == 0) ? ((d & 1) ? -1.0f : 1.0f)   // Nyquist term cos(pi*d)
                    : 1.0f;                       // DC term
    G[((size_t)k * 256 + t) * 256 + s] = f2bf(acc * (1.0f / 256.0f));
}

// x[b,t,d] = ego[paths[b,t], d] + pos[t, d]  -> bf16
__global__ __launch_bounds__(256) void build_x_kernel(const int* __restrict__ paths,
                                                      const float* __restrict__ ego,
                                                      const float* __restrict__ pos,
                                                      short* __restrict__ x) {
    int base = (blockIdx.x * 256 + threadIdx.x) * 4;
    int d = base & 127;
    int bl = base >> 7;
    int t = bl & 255;
    float4 e = *(const float4*)(ego + (size_t)paths[bl] * Dn + d);
    float4 p = *(const float4*)(pos + t * Dn + d);
    short4 s;
    s.x = f2bf(e.x + p.x); s.y = f2bf(e.y + p.y);
    s.z = f2bf(e.z + p.z); s.w = f2bf(e.w + p.w);
    *(short4*)&x[base] = s;
}

// All 6 weight transposes in ONE kernel.  Per layer z, flat idx in [0,131072):
// [0,16384)=Wq  [16384,32768)=Wk  [32768,49152)=Wv  [49152,65536)=0.1*Wp
// [65536,98304)=F1 (K=128,N=256)  [98304,131072)=F2 (K=256,N=128)
// in f32 [z][K][N] -> out bf16 [z][N][K] * scale
__global__ __launch_bounds__(256) void wtrans_all_kernel(
        const float* __restrict__ Wq, const float* __restrict__ Wk,
        const float* __restrict__ Wv, const float* __restrict__ Wp,
        const float* __restrict__ F1, const float* __restrict__ F2,
        short* __restrict__ Wt) {
    int z = blockIdx.y;
    int idx = blockIdx.x * 256 + threadIdx.x;
    short* WtL = Wt + (size_t)z * WT_LAYER;
    if (idx < 65536) {
        int which = idx >> 14, local = idx & 16383;
        const float* src = (which == 0) ? Wq : (which == 1) ? Wk
                         : (which == 2) ? Wv : Wp;
        float scale = (which == 3) ? 0.1f : 1.0f;
        int n = local & 127, k = local >> 7;
        WtL[(which << 14) + n * 128 + k] = f2bf(scale * src[(size_t)z * 16384 + local]);
    } else if (idx < 98304) {
        int local = idx - 65536;                  // F1: [128][256]
        int n = local & 255, k = local >> 8;
        WtL[65536 + n * 128 + k] = f2bf(F1[(size_t)z * 32768 + local]);
    } else {
        int local = idx - 98304;                  // F2: [256][128]
        int n = local & 127, k = local >> 7;
        WtL[98304 + n * 256 + k] = f2bf(F2[(size_t)z * 32768 + local]);
    }
}

// ---------------------------------------------------------------------------
// General MFMA bf16 GEMM (W2T precompute only now).
// A bf16 [M][K].  BT_FAST: B bf16 [N][K]; else B bf16 [K][N] transpose-staged.
template<bool BT_FAST, bool GELU_EPI>
__global__ __launch_bounds__(256)
void mfma_gemm_kernel(const short* A, const short* Bp, short* C, const short* R,
                      int K, int lda, int ldb, int ldc, int ldr,
                      long long sA, long long sB, long long sC, long long sR,
                      long long sCsplit, float alpha, float beta) {
    int bz = blockIdx.z;
    A += (size_t)bz * sA; C += (size_t)bz * sC;
    if (R) R += (size_t)bz * sR;
    const short* Bt = Bp + (size_t)bz * sB;
    const int m0 = blockIdx.x * 128, n0 = blockIdx.y * 128;
    int n0c = n0;
    if (sCsplit) { C += (size_t)blockIdx.y * sCsplit; n0c = 0; }
    __shared__ short As[128 * 40];
    __shared__ short Bs[128 * 40];
    int tid = threadIdx.x;
    int lane = tid & 63, wave = tid >> 6;
    int wr = (wave >> 1) * 64, wc = (wave & 1) * 64;
    int l15 = lane & 15, qd = lane >> 4;

    frag_cd zero4 = {0.f, 0.f, 0.f, 0.f};
    frag_cd acc[4][4];
    #pragma unroll
    for (int i = 0; i < 4; i++)
        #pragma unroll
        for (int j = 0; j < 4; j++) acc[i][j] = zero4;

    int arow = tid >> 1, acg = (tid & 1) * 16;
    int bnrow = tid >> 1, bcg = (tid & 1) * 16;
    int bkk = tid & 31, bnb = (tid >> 5) * 16;

    int4 pa0, pa1, pb0, pb1;
    {
        const short* ap = A + (size_t)(m0 + arow) * lda + acg;
        pa0 = *(const int4*)ap; pa1 = *(const int4*)(ap + 8);
        if (BT_FAST) {
            const short* bp = Bt + (size_t)(n0 + bnrow) * ldb + bcg;
            pb0 = *(const int4*)bp; pb1 = *(const int4*)(bp + 8);
        } else {
            const short* bp = Bt + (size_t)bkk * ldb + n0 + bnb;
            pb0 = *(const int4*)bp; pb1 = *(const int4*)(bp + 8);
        }
    }

    for (int k0 = 0; k0 < K; k0 += 32) {
        __syncthreads();
        *(int4*)&As[arow * 40 + acg] = pa0;
        *(int4*)&As[arow * 40 + acg + 8] = pa1;
        if (BT_FAST) {
            *(int4*)&Bs[bnrow * 40 + bcg] = pb0;
            *(int4*)&Bs[bnrow * 40 + bcg + 8] = pb1;
        } else {
            short tmp[16];
            *(int4*)&tmp[0] = pb0; *(int4*)&tmp[8] = pb1;
            #pragma unroll
            for (int i = 0; i < 16; i++) Bs[(bnb + i) * 40 + bkk] = tmp[i];
        }
        __syncthreads();
        if (k0 + 32 < K) {
            const short* ap = A + (size_t)(m0 + arow) * lda + k0 + 32 + acg;
            pa0 = *(const int4*)ap; pa1 = *(const int4*)(ap + 8);
            if (BT_FAST) {
                const short* bp = Bt + (size_t)(n0 + bnrow) * ldb + k0 + 32 + bcg;
                pb0 = *(const int4*)bp; pb1 = *(const int4*)(bp + 8);
            } else {
                const short* bp = Bt + (size_t)(k0 + 32 + bkk) * ldb + n0 + bnb;
                pb0 = *(const int4*)bp; pb1 = *(const int4*)(bp + 8);
            }
        }
        frag_ab af[4], bf[4];
        #pragma unroll
        for (int ms = 0; ms < 4; ms++)
            af[ms] = *(frag_ab*)&As[(wr + ms * 16 + l15) * 40 + qd * 8];
        #pragma unroll
        for (int ns = 0; ns < 4; ns++)
            bf[ns] = *(frag_ab*)&Bs[(wc + ns * 16 + l15) * 40 + qd * 8];
        #pragma unroll
        for (int ms = 0; ms < 4; ms++)
            #pragma unroll
            for (int ns = 0; ns < 4; ns++)
                acc[ms][ns] = __builtin_amdgcn_mfma_f32_16x16x32_bf16(
                    bf[ns], af[ms], acc[ms][ns], 0, 0, 0);
    }
    #pragma unroll
    for (int ms = 0; ms < 4; ms++) {
        int m = m0 + wr + ms * 16 + l15;
        #pragma unroll
        for (int ns = 0; ns < 4; ns++) {
            int nb = wc + ns * 16 + qd * 4;
            float v[4];
            #pragma unroll
            for (int r = 0; r < 4; r++) v[r] = alpha * acc[ms][ns][r];
            if (R) {
                short4 r4 = *(const short4*)&R[(size_t)m * ldr + n0 + nb];
                v[0] += beta * bf2f(r4.x); v[1] += beta * bf2f(r4.y);
                v[2] += beta * bf2f(r4.z); v[3] += beta * bf2f(r4.w);
            }
            if (GELU_EPI) {
                #pragma unroll
                for (int r = 0; r < 4; r++)
                    v[r] = v[r] * 0.5f * (1.0f + erff(v[r] * 0.70710678118654752f));
            }
            short4 o;
            o.x = f2bf(v[0]); o.y = f2bf(v[1]); o.z = f2bf(v[2]); o.w = f2bf(v[3]);
            *(short4*)&C[(size_t)m * ldc + n0c + nb] = o;
        }
    }
}

static inline void mgemm(hipStream_t s, const short* A, const short* B, short* C,
                         const short* R, int M, int N, int K,
                         int lda, int ldb, int ldc, int ldr,
                         long long sA, long long sB, long long sC, long long sR,
                         int batch, float alpha, float beta, bool btFast, bool gelu,
                         long long sCsplit = 0) {
    dim3 grid(M / 128, N / 128, batch), block(256);
    if (btFast) {
        if (gelu) mfma_gemm_kernel<true, true ><<<grid, block, 0, s>>>(A, B, C, R, K, lda, ldb, ldc, ldr, sA, sB, sC, sR, sCsplit, alpha, beta);
        else      mfma_gemm_kernel<true, false><<<grid, block, 0, s>>>(A, B, C, R, K, lda, ldb, ldc, ldr, sA, sB, sC, sR, sCsplit, alpha, beta);
    } else {
        if (gelu) mfma_gemm_kernel<false, true ><<<grid, block, 0, s>>>(A, B, C, R, K, lda, ldb, ldc, ldr, sA, sB, sC, sR, sCsplit, alpha, beta);
        else      mfma_gemm_kernel<false, false><<<grid, block, 0, s>>>(A, B, C, R, K, lda, ldb, ldc, ldr, sA, sB, sC, sR, sCsplit, alpha, beta);
    }
}

// ---------------------------------------------------------------------------
// Fused band-filter + QKV projections.  One WG per batch b (grid 256, 1/CU),
// 512 threads = 8 waves (4x2).  (R7 win: -14 us, x5 round-trip eliminated.)
__global__ __launch_bounds__(512)
void filtproj_kernel(const short* __restrict__ G, const short* __restrict__ x,
                     const short* __restrict__ W, short* __restrict__ q) {
    int b = blockIdx.x;
    __shared__ short As[256 * 40];
    __shared__ short Bs[128 * 40];
    __shared__ short xf[256 * 136];
    int tid = threadIdx.x;
    int lane = tid & 63, wave = tid >> 6;
    int wr = (wave & 3) * 64, wc = (wave >> 2) * 64;
    int l15 = lane & 15, qd = lane >> 4;
    const short* xb = x + ((size_t)b << 15);

    frag_cd zero4 = {0.f, 0.f, 0.f, 0.f};
    frag_cd acc[4][4];
    #pragma unroll
    for (int i = 0; i < 4; i++)
        #pragma unroll
        for (int j = 0; j < 4; j++) acc[i][j] = zero4;

    int arow = tid >> 1, acg = (tid & 1) * 16;   // A: 32B/thread (256x32 tile)
    int bkk = tid & 31, bnb = (tid >> 5) * 16;   // B slow-path (tid<256 only)

    // ---- phase 1: xf = G @ x[b] ----
    int4 pa0, pa1, pb0, pb1;
    {
        const short* ap = G + (size_t)arow * 256 + acg;
        pa0 = *(const int4*)ap; pa1 = *(const int4*)(ap + 8);
        if (tid < 256) {
            const short* bp = xb + (size_t)bkk * 128 + bnb;
            pb0 = *(const int4*)bp; pb1 = *(const int4*)(bp + 8);
        }
    }
    for (int k0 = 0; k0 < 256; k0 += 32) {
        __syncthreads();
        *(int4*)&As[arow * 40 + acg] = pa0;
        *(int4*)&As[arow * 40 + acg + 8] = pa1;
        if (tid < 256) {
            short tmp[16];
            *(int4*)&tmp[0] = pb0; *(int4*)&tmp[8] = pb1;
            #pragma unroll
            for (int i = 0; i < 16; i++) Bs[(bnb + i) * 40 + bkk] = tmp[i];
        }
        __syncthreads();
        if (k0 + 32 < 256) {
            const short* ap = G + (size_t)arow * 256 + k0 + 32 + acg;
            pa0 = *(const int4*)ap; pa1 = *(const int4*)(ap + 8);
            if (tid < 256) {
                const short* bp = xb + (size_t)(k0 + 32 + bkk) * 128 + bnb;
                pb0 = *(const int4*)bp; pb1 = *(const int4*)(bp + 8);
            }
        }
        frag_ab af[4], bf[4];
        #pragma unroll
        for (int ms = 0; ms < 4; ms++)
            af[ms] = *(frag_ab*)&As[(wr + ms * 16 + l15) * 40 + qd * 8];
        #pragma unroll
        for (int ns = 0; ns < 4; ns++)
            bf[ns] = *(frag_ab*)&Bs[(wc + ns * 16 + l15) * 40 + qd * 8];
        #pragma unroll
        for (int ms = 0; ms < 4; ms++)
            #pragma unroll
            for (int ns = 0; ns < 4; ns++)
                acc[ms][ns] = __builtin_amdgcn_mfma_f32_16x16x32_bf16(
                    bf[ns], af[ms], acc[ms][ns], 0, 0, 0);
    }
    // epilogue -> LDS xf (same f2bf rounding as the old global store)
    #pragma unroll
    for (int ms = 0; ms < 4; ms++) {
        int m = wr + ms * 16 + l15;
        #pragma unroll
        for (int ns = 0; ns < 4; ns++) {
            int nb = wc + ns * 16 + qd * 4;
            short4 o;
            o.x = f2bf(acc[ms][ns][0]); o.y = f2bf(acc[ms][ns][1]);
            o.z = f2bf(acc[ms][ns][2]); o.w = f2bf(acc[ms][ns][3]);
            *(short4*)&xf[m * 136 + nb] = o;
        }
    }

    // ---- phase 2: C_y[b] = xf @ Wy^T, y = 0..2 ----
    int brow = tid >> 2, bcg = (tid & 3) * 8;    // B: 16B/thread (128x32 tile)
    #pragma unroll 1
    for (int y = 0; y < 3; y++) {
        const short* Bt = W + y * 16384;
        #pragma unroll
        for (int i = 0; i < 4; i++)
            #pragma unroll
            for (int j = 0; j < 4; j++) acc[i][j] = zero4;
        int4 pb = *(const int4*)(Bt + (size_t)brow * 128 + bcg);
        for (int k0 = 0; k0 < 128; k0 += 32) {
            __syncthreads();
            *(int4*)&Bs[brow * 40 + bcg] = pb;
            __syncthreads();
            if (k0 + 32 < 128)
                pb = *(const int4*)(Bt + (size_t)brow * 128 + k0 + 32 + bcg);
            frag_ab af[4], bf[4];
            #pragma unroll
            for (int ms = 0; ms < 4; ms++)
                af[ms] = *(frag_ab*)&xf[(wr + ms * 16 + l15) * 136 + k0 + qd * 8];
            #pragma unroll
            for (int ns = 0; ns < 4; ns++)
                bf[ns] = *(frag_ab*)&Bs[(wc + ns * 16 + l15) * 40 + qd * 8];
            #pragma unroll
            for (int ms = 0; ms < 4; ms++)
                #pragma unroll
                for (int ns = 0; ns < 4; ns++)
                    acc[ms][ns] = __builtin_amdgcn_mfma_f32_16x16x32_bf16(
                        bf[ns], af[ms], acc[ms][ns], 0, 0, 0);
        }
        short* Cy = q + (size_t)y * BLD + ((size_t)b << 15);
        #pragma unroll
        for (int ms = 0; ms < 4; ms++) {
            int m = wr + ms * 16 + l15;
            #pragma unroll
            for (int ns = 0; ns < 4; ns++) {
                int nb = wc + ns * 16 + qd * 4;
                short4 o;
                o.x = f2bf(acc[ms][ns][0]); o.y = f2bf(acc[ms][ns][1]);
                o.z = f2bf(acc[ms][ns][2]); o.w = f2bf(acc[ms][ns][3]);
                *(short4*)&Cy[(size_t)m * 128 + nb] = o;
            }
        }
    }
}

// ---------------------------------------------------------------------------
// Fused a-GEMM + FFN (layer tail).  One WG per batch b (grid 256), 512 thr.
// Phase A: a[b] = mix(x[b])@W2T + spat[b]@(0.1WpT) + x[b]  -> aL (LDS).
//   pass 0: MIXA gather of x[b] as A (bgemm domix pattern), B = W2T.
//   pass 1: A = spat[b] = q[b] staged from global, B = 0.1WpT.
//   epilogue: + residual x[b], f2bf -> aL (identical rounding to the old
//   kb global store).
// Phase B: x[b] = gelu(a[b]@F1)@F2 -- R8 ffn structure, aL already in LDS.
// As staging for phase A aliases hA (hA only written after phase A, behind
// a barrier).  LDS: aL 67.6 + hA 67.6 + Bs 10.2 = 145.4 KB.
// Saves the a (kb) 33 MB/layer round-trip + 1 launch/layer.
__global__ __launch_bounds__(512)
void amix_ffn_kernel(const short* __restrict__ x, const short* __restrict__ q,
                     const short* __restrict__ W,
                     const float* __restrict__ tc, const int* __restrict__ delays,
                     short* __restrict__ xout) {
    int b = blockIdx.x;
    __shared__ short aL[256 * 132];   // a[b] (67.6 KB)
    __shared__ short hA[256 * 132];   // gelu half (67.6 KB); aliases As in phase A
    __shared__ short Bs[128 * 40];    // weight tile (10.2 KB)
    short* As = hA;                   // phase-A staging (256*40 <= 256*132)
    int tid = threadIdx.x;
    int lane = tid & 63, wave = tid >> 6;
    int wr = (wave & 3) * 64, wc = (wave >> 2) * 64;
    int l15 = lane & 15, qd = lane >> 4;
    const short* xb = x + ((size_t)b << 15);

    float wj[TOPKn]; int dj[TOPKn];
    #pragma unroll
    for (int j = 0; j < TOPKn; j++) {
        wj[j] = tc[b * TOPKn + j];
        dj[j] = delays[j];
    }

    frag_cd zero4 = {0.f, 0.f, 0.f, 0.f};
    frag_cd acc[4][4];
    #pragma unroll
    for (int i = 0; i < 4; i++)
        #pragma unroll
        for (int j = 0; j < 4; j++) acc[i][j] = zero4;

    int arow = tid >> 1, acg = (tid & 1) * 16;   // A: 32B/thread
    int brow = tid >> 2, bcg = (tid & 3) * 8;    // B: 16B/thread

    // ---- phase A pass 0: acc = mix(x[b]) @ W2T ----
    {
        const short* Bt = W + 131072;   // W2T [128][128]
        int4 pb0 = *(const int4*)(Bt + (size_t)brow * 128 + bcg);
        for (int k0 = 0; k0 < 128; k0 += 32) {
            __syncthreads();
            #pragma unroll
            for (int c = 0; c < 2; c++) {
                int col = k0 + acg + c * 8;
                float m8[8] = {0.f, 0.f, 0.f, 0.f, 0.f, 0.f, 0.f, 0.f};
                #pragma unroll
                for (int j = 0; j < TOPKn; j++) {
                    frag_ab v = *(const frag_ab*)(xb + (((arow + dj[j]) & 255) << 7) + col);
                    #pragma unroll
                    for (int i = 0; i < 8; i++) m8[i] += wj[j] * bf2f(v[i]);
                }
                frag_ab o;
                #pragma unroll
                for (int i = 0; i < 8; i++) o[i] = f2bf(m8[i]);
                *(frag_ab*)&As[arow * 40 + acg + c * 8] = o;
            }
            *(int4*)&Bs[brow * 40 + bcg] = pb0;
            __syncthreads();
            if (k0 + 32 < 128)
                pb0 = *(const int4*)(Bt + (size_t)brow * 128 + k0 + 32 + bcg);
            frag_ab af[4], bf[4];
            #pragma unroll
            for (int ms = 0; ms < 4; ms++)
                af[ms] = *(frag_ab*)&As[(wr + ms * 16 + l15) * 40 + qd * 8];
            #pragma unroll
            for (int ns = 0; ns < 4; ns++)
                bf[ns] = *(frag_ab*)&Bs[(wc + ns * 16 + l15) * 40 + qd * 8];
            #pragma unroll
            for (int ms = 0; ms < 4; ms++)
                #pragma unroll
                for (int ns = 0; ns < 4; ns++)
                    acc[ms][ns] = __builtin_amdgcn_mfma_f32_16x16x32_bf16(
                        bf[ns], af[ms], acc[ms][ns], 0, 0, 0);
        }
    }
    // ---- phase A pass 1: acc += spat[b] @ (0.1 WpT) ----
    {
        const short* A2 = q + ((size_t)b << 15);
        const short* Bt = W + 49152;    // 0.1*WpT [128][128]
        int4 pa0, pa1, pb0;
        {
            const short* ap = A2 + (size_t)arow * 128 + acg;
            pa0 = *(const int4*)ap; pa1 = *(const int4*)(ap + 8);
            pb0 = *(const int4*)(Bt + (size_t)brow * 128 + bcg);
        }
        for (int k0 = 0; k0 < 128; k0 += 32) {
            __syncthreads();
            *(int4*)&As[arow * 40 + acg] = pa0;
            *(int4*)&As[arow * 40 + acg + 8] = pa1;
            *(int4*)&Bs[brow * 40 + bcg] = pb0;
            __syncthreads();
            if (k0 + 32 < 128) {
                const short* ap = A2 + (size_t)arow * 128 + k0 + 32 + acg;
                pa0 = *(const int4*)ap; pa1 = *(const int4*)(ap + 8);
                pb0 = *(const int4*)(Bt + (size_t)brow * 128 + k0 + 32 + bcg);
            }
            frag_ab af[4], bf[4];
            #pragma unroll
            for (int ms = 0; ms < 4; ms++)
                af[ms] = *(frag_ab*)&As[(wr + ms * 16 + l15) * 40 + qd * 8];
            #pragma unroll
            for (int ns = 0; ns < 4; ns++)
                bf[ns] = *(frag_ab*)&Bs[(wc + ns * 16 + l15) * 40 + qd * 8];
            #pragma unroll
            for (int ms = 0; ms < 4; ms++)
                #pragma unroll
                for (int ns = 0; ns < 4; ns++)
                    acc[ms][ns] = __builtin_amdgcn_mfma_f32_16x16x32_bf16(
                        bf[ns], af[ms], acc[ms][ns], 0, 0, 0);
        }
    }
    // ---- phase A epilogue: + residual x[b] -> aL ----
    __syncthreads();   // done reading As (aliased with hA region)
    #pragma unroll
    for (int ms = 0; ms < 4; ms++) {
        int m = wr + ms * 16 + l15;
        #pragma unroll
        for (int ns = 0; ns < 4; ns++) {
            int nb = wc + ns * 16 + qd * 4;
            short4 r4 = *(const short4*)&xb[(size_t)m * 128 + nb];
            float v[4];
            v[0] = acc[ms][ns][0] + bf2f(r4.x);
            v[1] = acc[ms][ns][1] + bf2f(r4.y);
            v[2] = acc[ms][ns][2] + bf2f(r4.z);
            v[3] = acc[ms][ns][3] + bf2f(r4.w);
            short4 o;
            o.x = f2bf(v[0]); o.y = f2bf(v[1]); o.z = f2bf(v[2]); o.w = f2bf(v[3]);
            *(short4*)&aL[m * 132 + nb] = o;
        }
    }
    __syncthreads();   // aL visible; hA region free

    // ---- phase B: x[b] = gelu(a[b] @ F1) @ F2 (R8 ffn structure) ----
    const short* F1T = W + 65536;     // [256][128]
    const short* F2T = W + 98304;     // [128][256]
    frag_cd xacc[4][4];
    #pragma unroll
    for (int i = 0; i < 4; i++)
        #pragma unroll
        for (int j = 0; j < 4; j++) xacc[i][j] = zero4;

    #pragma unroll 1
    for (int half = 0; half < 2; half++) {
        const short* B1 = F1T + (size_t)(half * 128) * 128;
        frag_cd hacc[4][4];
        #pragma unroll
        for (int i = 0; i < 4; i++)
            #pragma unroll
            for (int j = 0; j < 4; j++) hacc[i][j] = zero4;
        int4 pb = *(const int4*)(B1 + (size_t)brow * 128 + bcg);
        for (int k0 = 0; k0 < 128; k0 += 32) {
            __syncthreads();
            *(int4*)&Bs[brow * 40 + bcg] = pb;
            __syncthreads();
            if (k0 + 32 < 128)
                pb = *(const int4*)(B1 + (size_t)brow * 128 + k0 + 32 + bcg);
            frag_ab af[4], bf[4];
            #pragma unroll
            for (int ms = 0; ms < 4; ms++)
                af[ms] = *(frag_ab*)&aL[(wr + ms * 16 + l15) * 132 + k0 + qd * 8];
            #pragma unroll
            for (int ns = 0; ns < 4; ns++)
                bf[ns] = *(frag_ab*)&Bs[(wc + ns * 16 + l15) * 40 + qd * 8];
            #pragma unroll
            for (int ms = 0; ms < 4; ms++)
                #pragma unroll
                for (int ns = 0; ns < 4; ns++)
                    hacc[ms][ns] = __builtin_amdgcn_mfma_f32_16x16x32_bf16(
                        bf[ns], af[ms], hacc[ms][ns], 0, 0, 0);
        }
        __syncthreads();   // all reads of hA from previous half complete
        #pragma unroll
        for (int ms = 0; ms < 4; ms++) {
            int m = wr + ms * 16 + l15;
            #pragma unroll
            for (int ns = 0; ns < 4; ns++) {
                int nb = wc + ns * 16 + qd * 4;
                float v[4];
                #pragma unroll
                for (int r = 0; r < 4; r++) {
                    float t = hacc[ms][ns][r];
                    v[r] = t * 0.5f * (1.0f + erff(t * 0.70710678118654752f));
                }
                short4 o;
                o.x = f2bf(v[0]); o.y = f2bf(v[1]);
                o.z = f2bf(v[2]); o.w = f2bf(v[3]);
                *(short4*)&hA[m * 132 + nb] = o;
            }
        }
        __syncthreads();   // hA visible to all waves

        int4 pb2 = *(const int4*)(F2T + (size_t)brow * 256 + half * 128 + bcg);
        for (int k0 = 0; k0 < 128; k0 += 32) {
            __syncthreads();
            *(int4*)&Bs[brow * 40 + bcg] = pb2;
            __syncthreads();
            if (k0 + 32 < 128)
                pb2 = *(const int4*)(F2T + (size_t)brow * 256 + half * 128 + k0 + 32 + bcg);
            frag_ab af[4], bf[4];
            #pragma unroll
            for (int ms = 0; ms < 4; ms++)
                af[ms] = *(frag_ab*)&hA[(wr + ms * 16 + l15) * 132 + k0 + qd * 8];
            #pragma unroll
            for (int ns = 0; ns < 4; ns++)
                bf[ns] = *(frag_ab*)&Bs[(wc + ns * 16 + l15) * 40 + qd * 8];
            #pragma unroll
            for (int ms = 0; ms < 4; ms++)
                #pragma unroll
                for (int ns = 0; ns < 4; ns++)
                    xacc[ms][ns] = __builtin_amdgcn_mfma_f32_16x16x32_bf16(
                        bf[ns], af[ms], xacc[ms][ns], 0, 0, 0);
        }
    }
    // epilogue: xacc -> xout[b]
    short* xo = xout + ((size_t)b << 15);
    #pragma unroll
    for (int ms = 0; ms < 4; ms++) {
        int m = wr + ms * 16 + l15;
        #pragma unroll
        for (int ns = 0; ns < 4; ns++) {
            int nb = wc + ns * 16 + qd * 4;
            short4 o;
            o.x = f2bf(xacc[ms][ns][0]); o.y = f2bf(xacc[ms][ns][1]);
            o.z = f2bf(xacc[ms][ns][2]); o.w = f2bf(xacc[ms][ns][3]);
            *(short4*)&xo[(size_t)m * 128 + nb] = o;
        }
    }
}

// ---------------------------------------------------------------------------
// MFMA bf16 fused attention, one WG per (h, b).  512 threads = 8 waves.
// Fixed-max softmax (scores O(0.01)).  S stored DIAGONALLY (SD[tau][keyLocal],
// stride 66 -> conflict-free mv reduction).  Denominator via ones-column in vT.
// NOTE (R4 lesson): ballot-bitmask + ternary pfrag variants inflate FETCH
// 28->88..126 MB (3 independent A/Bs) -- keep the masks[] LDS float path.
// R6: vT kv-axis XOR-swizzled at 16B blocks (fixed the 16-way transpose-write
// bank conflict; verified -6.4 us).
__global__ __launch_bounds__(512, 4) void attn_kernel(short* q,
        const short* __restrict__ kb, const short* __restrict__ vf,
        const int* __restrict__ paths, float* __restrict__ mv2) {
    int h = blockIdx.x, b = blockIdx.y;
    __shared__ short SB[256 * 72];   // phase0: q staging (stride 72); loop: SD (stride 66)
    __shared__ short ks[64 * 72];
    __shared__ short vT[80 * 72];
    __shared__ float masks[256];
    __shared__ float mvpart[512];
    int tid = threadIdx.x;
    int lane = tid & 63, wave = tid >> 6;
    int l15 = lane & 15, qd = lane >> 4;
    if (tid < 256) masks[tid] = (paths[b * 256 + tid] < NUM_TOTALn) ? 0.0f : -10000.0f;
    {
        int e0 = tid * 2;
        #pragma unroll
        for (int i = 0; i < 2; i++) {
            int e = e0 + i;
            int row = 64 + (e >> 6), col = e & 63;
            vT[row * 72 + col] = (row == 64) ? (short)0x3F80 : (short)0;
        }
    }
    short* qg = q + ((size_t)b << 15) + (size_t)h * 64;
    const short* kg = kb + ((size_t)b << 15) + (size_t)h * 64;
    const short* vg = vf + ((size_t)b << 15) + (size_t)h * 64;

    #pragma unroll
    for (int p = 0; p < 4; p++) {
        int chunk = p * 512 + tid;
        int r = chunk >> 3, cb = (chunk & 7) * 8;
        *(frag_ab*)&SB[r * 72 + cb] = *(const frag_ab*)(qg + (size_t)r * 128 + cb);
    }
    __syncthreads();
    int myrow = wave * 32;
    frag_ab aq[2][2];
    #pragma unroll
    for (int mt = 0; mt < 2; mt++)
        #pragma unroll
        for (int hf = 0; hf < 2; hf++)
            aq[mt][hf] = *(frag_ab*)&SB[(myrow + mt * 16 + l15) * 72 + hf * 32 + qd * 8];

    frag_cd zero4 = {0.f, 0.f, 0.f, 0.f};
    frag_cd oacc[2][5];
    #pragma unroll
    for (int mt = 0; mt < 2; mt++)
        #pragma unroll
        for (int et = 0; et < 5; et++) oacc[mt][et] = zero4;
    float macc = 0.0f;
    int tau = tid & 255, half = tid >> 8;

    for (int jt = 0; jt < 4; jt++) {
        __syncthreads();
        {
            int r = tid >> 3, cb = (tid & 7) * 8;
            *(frag_ab*)&ks[r * 72 + cb] =
                *(const frag_ab*)(kg + (size_t)(jt * 64 + r) * 128 + cb);
            frag_ab v8 = *(const frag_ab*)(vg + (size_t)(jt * 64 + r) * 128 + cb);
            // vT swizzled write: e = cb+i, phys block = (r>>3) ^ ((e>>3)&7);
            // e>>3 == cb>>3 (cb multiple of 8, i<8) -> per-thread constant.
            int swz = (((r >> 3) ^ (cb >> 3)) << 3) + (r & 7);
            #pragma unroll
            for (int i = 0; i < 8; i++) vT[(cb + i) * 72 + swz] = v8[i];
        }
        __syncthreads();
        #pragma unroll
        for (int mt = 0; mt < 2; mt++) {
            #pragma unroll
            for (int nt = 0; nt < 4; nt++) {
                frag_ab b0 = *(frag_ab*)&ks[(nt * 16 + l15) * 72 + qd * 8];
                frag_ab b1 = *(frag_ab*)&ks[(nt * 16 + l15) * 72 + 32 + qd * 8];
                frag_cd c = zero4;
                c = __builtin_amdgcn_mfma_f32_16x16x32_bf16(aq[mt][0], b0, c, 0, 0, 0);
                c = __builtin_amdgcn_mfma_f32_16x16x32_bf16(aq[mt][1], b1, c, 0, 0, 0);
                int keyLocal = nt * 16 + l15;
                #pragma unroll
                for (int r = 0; r < 4; r++) {
                    int row = myrow + mt * 16 + qd * 4 + r;
                    int tt = (row - jt * 64 - keyLocal) & 255;
                    SB[tt * 66 + keyLocal] = f2bf(c[r] * 0.125f);
                }
            }
        }
        __syncthreads();
        {
            const int* SD32 = (const int*)&SB[tau * 66 + half * 32];
            #pragma unroll
            for (int i = 0; i < 16; i++) {
                int pk = SD32[i];
                macc += bf2f((short)(pk & 0xFFFF)) + bf2f((short)(pk >> 16));
            }
        }
        #pragma unroll
        for (int mt = 0; mt < 2; mt++) {
            int row = myrow + mt * 16 + l15;
            #pragma unroll
            for (int hf = 0; hf < 2; hf++) {
                int kl0 = hf * 32 + qd * 8;
                frag_ab pfrag;
                #pragma unroll
                for (int j = 0; j < 8; j++) {
                    int kl = kl0 + j;
                    int tt = (row - jt * 64 - kl) & 255;
                    float s = bf2f(SB[tt * 66 + kl]);
                    pfrag[j] = f2bf(__expf(s + masks[jt * 64 + kl]));
                }
                #pragma unroll
                for (int et = 0; et < 5; et++) {
                    // swizzled bv read: e = et*16+l15; phys blk = (hf*4+qd) ^ ((e>>3)&7)
                    int e = et * 16 + l15;
                    int blk = (hf * 4 + qd) ^ ((e >> 3) & 7);
                    frag_ab bv = *(frag_ab*)&vT[e * 72 + (blk << 3)];
                    oacc[mt][et] = __builtin_amdgcn_mfma_f32_16x16x32_bf16(pfrag, bv, oacc[mt][et], 0, 0, 0);
                }
            }
        }
    }
    __syncthreads();
    mvpart[tid] = macc;
    __syncthreads();
    if (tid < 256)
        mv2[(size_t)h * 65536 + b * 256 + tid] =
            (mvpart[tid] + mvpart[tid + 256]) * 0.0625f;
    #pragma unroll
    for (int mt = 0; mt < 2; mt++) {
        #pragma unroll
        for (int r = 0; r < 4; r++) {
            float l = oacc[mt][4][r];
            l = __shfl(l, (lane & 48));
            float inv = 1.0f / l;
            int row = myrow + mt * 16 + qd * 4 + r;
            #pragma unroll
            for (int et = 0; et < 4; et++)
                qg[(size_t)row * 128 + et * 16 + l15] = f2bf(oacc[mt][et][r] * inv);
        }
    }
}

// ---------------------------------------------------------------------------
__global__ __launch_bounds__(256) void gm_reduce_kernel(const float* __restrict__ mv2,
                                                        float* __restrict__ gm) {
    int tau = blockIdx.x;
    int b = threadIdx.x;
    __shared__ float red[256];
    red[b] = mv2[b * 256 + tau] + mv2[65536 + b * 256 + tau];
    __syncthreads();
    for (int s = 128; s > 0; s >>= 1) { if (b < s) red[b] += red[b + s]; __syncthreads(); }
    if (b == 0) gm[tau] = red[0] * (1.0f / 256.0f);
}

// Single block.  5 rounds of wave-shuffle argmax (tie -> smaller index) over
// 256 values (4 waves), then per-b softmax over the selected weights.
__global__ __launch_bounds__(256) void topk_softmax_kernel(const float* __restrict__ gm,
                                                           const float* __restrict__ mv2,
                                                           int* __restrict__ delays,
                                                           float* __restrict__ tc) {
    __shared__ float vsh[4];
    __shared__ int ish[4];
    __shared__ int dsh[TOPKn];
    int tid = threadIdx.x;
    int lane = tid & 63, wave = tid >> 6;
    float v = gm[tid];
    for (int t = 0; t < TOPKn; t++) {
        float mv_ = v; int mi = tid;
        #pragma unroll
        for (int s = 32; s > 0; s >>= 1) {
            float v2 = __shfl_xor(mv_, s); int i2 = __shfl_xor(mi, s);
            if (v2 > mv_ || (v2 == mv_ && i2 < mi)) { mv_ = v2; mi = i2; }
        }
        if (lane == 0) { vsh[wave] = mv_; ish[wave] = mi; }
        __syncthreads();
        if (tid == 0) {
            float bv = vsh[0]; int bi = ish[0];
            #pragma unroll
            for (int w = 1; w < 4; w++)
                if (vsh[w] > bv || (vsh[w] == bv && ish[w] < bi)) { bv = vsh[w]; bi = ish[w]; }
            dsh[t] = bi; delays[t] = bi;
        }
        __syncthreads();
        if (tid == dsh[t]) v = -1e30f;
    }
    __syncthreads();
    int b = tid;
    float w[TOPKn];
    float m = -1e30f;
    #pragma unroll
    for (int j = 0; j < TOPKn; j++) {
        w[j] = mv2[b * 256 + dsh[j]] + mv2[65536 + b * 256 + dsh[j]];
        m = fmaxf(m, w[j]);
    }
    float ssum = 0.0f;
    #pragma unroll
    for (int j = 0; j < TOPKn; j++) { w[j] = expf(w[j] - m); ssum += w[j]; }
    #pragma unroll
    for (int j = 0; j < TOPKn; j++) tc[b * TOPKn + j] = w[j] / ssum;
}

__global__ __launch_bounds__(256) void gather_out_kernel(const short* __restrict__ x,
                                                         const int* __restrict__ lengths,
                                                         float* __restrict__ out) {
    int idx = blockIdx.x * 256 + threadIdx.x;
    int d = idx & 127;
    int b = idx >> 7;
    out[idx] = bf2f(x[((size_t)b << 15) + (size_t)(lengths[b] - 1) * Dn + d]);
}

// ---------------------------------------------------------------------------
extern "C" void kernel_launch(void* const* d_in, const int* in_sizes, int n_in,
                              void* d_out, int out_size, void* d_ws, size_t ws_size,
                              hipStream_t stream) {
    const int* paths    = (const int*)d_in[0];
    const int* lengths  = (const int*)d_in[1];
    const float* ego    = (const float*)d_in[4];
    const float* pos    = (const float*)d_in[5];
    const float* Wq     = (const float*)d_in[6];
    const float* Wk     = (const float*)d_in[7];
    const float* Wv     = (const float*)d_in[8];
    const float* Wp     = (const float*)d_in[9];
    const float* F1     = (const float*)d_in[10];
    const float* F2     = (const float*)d_in[11];
    float* out = (float*)d_out;

    const size_t need = (size_t)5 * BLD * 2 + 131072 * 2 + 131072 * 4
                        + 256 * 4 + 1280 * 4 + 16 * 4 + (size_t)NLn * WT_LAYER * 2;
    if (ws_size < need) {
        beacon_kernel<<<dim3(1), dim3(1), 0, stream>>>(out, (float)(ws_size >> 20));
        return;
    }

    short* x    = (short*)d_ws;
    short* q    = x + (size_t)1 * BLD;   // q~ -> spat
    short* kb   = x + (size_t)2 * BLD;   // k~
    short* vf   = x + (size_t)3 * BLD;   // v~
    short* Gb   = x + (size_t)5 * BLD;
    float* mv   = (float*)(Gb + 131072);   // mv2: [2][256][256]
    float* gm   = mv + 131072;
    float* tc   = gm + 256;
    int* delays = (int*)(tc + 1280);
    short* Wt   = (short*)(delays + 16);

    build_G_kernel<<<dim3(2, 256), dim3(256), 0, stream>>>(Gb);
    build_x_kernel<<<dim3(BLD / 1024), dim3(256), 0, stream>>>(paths, ego, pos, x);

    // Wt per layer: [0]=Wq^T | [16384]=Wk^T | [32768]=Wv^T | [49152]=0.1*Wp^T
    //               [65536]=F1^T | [98304]=F2^T | [131072]=W2^T=0.9*(Wv@Wp)^T
    wtrans_all_kernel<<<dim3(512, NLn), dim3(256), 0, stream>>>(Wq, Wk, Wv, Wp, F1, F2, Wt);
    // W2T = 9*(0.1Wp^T)@(Wv^T slow-path) for both layers in one batched launch
    mgemm(stream, Wt + 49152, Wt + 32768, Wt + 131072, nullptr,
          128, 128, 128, 128, 128, 128, 0,
          WT_LAYER, WT_LAYER, WT_LAYER, 0, NLn,
          9.0f, 0.0f, false, false);

    for (int k = 0; k < NLn; k++) {
        const short* WtL = Wt + (size_t)k * WT_LAYER;
        // fused: xf = G_k @ x[b] (LDS) -> {q,k,v} projections, one WG per b
        filtproj_kernel<<<dim3(256), dim3(512), 0, stream>>>(
            Gb + (size_t)k * 65536, x, WtL, q);

        attn_kernel<<<dim3(2, 256), dim3(512), 0, stream>>>(q, kb, vf, paths, mv);

        gm_reduce_kernel<<<dim3(256), dim3(256), 0, stream>>>(mv, gm);
        topk_softmax_kernel<<<dim3(1), dim3(256), 0, stream>>>(gm, mv, delays, tc);

        // fused layer tail: a = mix(x)@W2' + spat@(0.1Wp') + x (LDS) -> FFN -> x
        amix_ffn_kernel<<<dim3(256), dim3(512), 0, stream>>>(
            x, q, WtL, tc, delays, x);
    }

    gather_out_kernel<<<dim3((Bn * Dn) / 256), dim3(256), 0, stream>>>(x, lengths, out);
}